// Round 8
// baseline (527.477 us; speedup 1.0000x reference)
//
#include <hip/hip_runtime.h>
#include <math.h>

#define N0 20000
#define N1 15000
#define N2 15000
#define NN 50000          // total nodes
#define EE 800000         // edges
#define SLOPE 0.2f
#define ALPHA 0.05f

typedef _Float16 h8 __attribute__((ext_vector_type(8)));
typedef _Float16 h4 __attribute__((ext_vector_type(4)));
typedef float f4v __attribute__((ext_vector_type(4)));

__device__ __forceinline__ float sel4(float4 v, int h) {
    float lo = (h & 1) ? v.y : v.x;
    float hi = (h & 1) ? v.w : v.z;
    return (h & 2) ? hi : lo;
}

// cheap ELU: expm1f is a libm call (~20 instrs); __expf(x)-1 is ~3 VALU, abs err <1e-6 for x<0
__device__ __forceinline__ float elu_fast(float x) {
    return x > 0.f ? x : __expf(x) - 1.f;
}

// ---------------- CSR build ----------------

__global__ void hist_kernel(const int* __restrict__ dst, int* __restrict__ deg, int E_) {
    int e = blockIdx.x * blockDim.x + threadIdx.x;
    if (e < E_) atomicAdd(&deg[dst[e]], 1);
}

__global__ __launch_bounds__(256) void block_sum_kernel(const int* __restrict__ deg,
                                                        int* __restrict__ bsum, int n) {
    int i = blockIdx.x * 256 + threadIdx.x;
    int v = (i < n) ? deg[i] : 0;
    #pragma unroll
    for (int off = 32; off > 0; off >>= 1) v += __shfl_down(v, off);
    __shared__ int sh[4];
    if ((threadIdx.x & 63) == 0) sh[threadIdx.x >> 6] = v;
    __syncthreads();
    if (threadIdx.x == 0) bsum[blockIdx.x] = sh[0] + sh[1] + sh[2] + sh[3];
}

__global__ __launch_bounds__(256) void scan_bsum_kernel(int* __restrict__ bsum, int nb) {
    __shared__ int sh[256];
    int tid = threadIdx.x;
    int v = (tid < nb) ? bsum[tid] : 0;
    sh[tid] = v;
    __syncthreads();
    #pragma unroll
    for (int off = 1; off < 256; off <<= 1) {
        int t = (tid >= off) ? sh[tid - off] : 0;
        __syncthreads();
        sh[tid] += t;
        __syncthreads();
    }
    if (tid < nb) bsum[tid] = sh[tid] - v;   // exclusive
}

__global__ __launch_bounds__(256) void scan_out_kernel(const int* __restrict__ deg,
                                                       const int* __restrict__ boff,
                                                       int* __restrict__ rowstart,
                                                       int* __restrict__ cursor, int n) {
    __shared__ int sh[256];
    int tid = threadIdx.x;
    int i = blockIdx.x * 256 + tid;
    int v = (i < n) ? deg[i] : 0;
    sh[tid] = v;
    __syncthreads();
    #pragma unroll
    for (int off = 1; off < 256; off <<= 1) {
        int t = (tid >= off) ? sh[tid - off] : 0;
        __syncthreads();
        sh[tid] += t;
        __syncthreads();
    }
    int excl = sh[tid] - v + boff[blockIdx.x];
    if (i < n) { rowstart[i] = excl; cursor[i] = excl; }
    if (i == n - 1) rowstart[n] = excl + v;
}

// pack (et<<16)|src into one int per CSR slot
__global__ void scatter_kernel(const int* __restrict__ src, const int* __restrict__ dst,
                               const int* __restrict__ et, int* __restrict__ cursor,
                               int* __restrict__ pk, int E_) {
    int e = blockIdx.x * blockDim.x + threadIdx.x;
    if (e >= E_) return;
    int d = dst[e];
    int p = atomicAdd(&cursor[d], 1);
    pk[p] = (et[e] << 16) | src[e];
}

// ---------------- es tables (all 3 layers, one launch) ----------------

__global__ void es_table_all(const float* __restrict__ etab0, const float* __restrict__ We0,
                             const float* __restrict__ ae0,
                             const float* __restrict__ etab1, const float* __restrict__ We1,
                             const float* __restrict__ ae1,
                             const float* __restrict__ etab2, const float* __restrict__ We2,
                             const float* __restrict__ ae2,
                             float* __restrict__ es) {
    int b = blockIdx.x;
    const float *etab, *We, *ae;
    float* out;
    int H;
    if (b < 32)      { etab = etab0; We = We0; ae = ae0; out = es;      H = 4; }
    else if (b < 64) { b -= 32; etab = etab1; We = We1; ae = ae1; out = es + 32; H = 4; }
    else             { b -= 64; etab = etab2; We = We2; ae = ae2; out = es + 64; H = 1; }
    int t = b / H, h = b % H;
    int j = threadIdx.x;   // 0..63
    const float* w = We + (size_t)(h * 64 + j) * 64;
    const float* e = etab + t * 64;
    float s = 0.f;
    #pragma unroll
    for (int k = 0; k < 64; k += 4) {
        float4 wv = *(const float4*)(w + k);
        float4 ev = *(const float4*)(e + k);
        s += wv.x * ev.x + wv.y * ev.y + wv.z * ev.z + wv.w * ev.w;
    }
    s *= ae[h * 64 + j];
    #pragma unroll
    for (int off = 32; off > 0; off >>= 1) s += __shfl_down(s, off);
    if (j == 0) out[t * H + h] = s;
}

// ---------------- fp32 -> fp16 converts (10 arrays, one launch) ----------------

__global__ void f2h10(const float* s0, _Float16* d0, int n0,
                      const float* s1, _Float16* d1, int n1,
                      const float* s2, _Float16* d2, int n2,
                      const float* s3, _Float16* d3, int n3,
                      const float* s4, _Float16* d4, int n4,
                      const float* s5, _Float16* d5, int n5,
                      const float* s6, _Float16* d6, int n6,
                      const float* s7, _Float16* d7, int n7,
                      const float* s8, _Float16* d8, int n8,
                      const float* s9, _Float16* d9, int n9) {
    int t = blockIdx.x * 256 + threadIdx.x;
    if (t < n0) { d0[t] = (_Float16)s0[t]; return; } t -= n0;
    if (t < n1) { d1[t] = (_Float16)s1[t]; return; } t -= n1;
    if (t < n2) { d2[t] = (_Float16)s2[t]; return; } t -= n2;
    if (t < n3) { d3[t] = (_Float16)s3[t]; return; } t -= n3;
    if (t < n4) { d4[t] = (_Float16)s4[t]; return; } t -= n4;
    if (t < n5) { d5[t] = (_Float16)s5[t]; return; } t -= n5;
    if (t < n6) { d6[t] = (_Float16)s6[t]; return; } t -= n6;
    if (t < n7) { d7[t] = (_Float16)s7[t]; return; } t -= n7;
    if (t < n8) { d8[t] = (_Float16)s8[t]; return; } t -= n8;
    if (t < n9) { d9[t] = (_Float16)s9[t]; }
}

// ---------------- MFMA fp16 GEMM (verified) ----------------

template<int NT>
__global__ __launch_bounds__(256) void gemm_mfma(const _Float16* __restrict__ A,
                                                 const _Float16* __restrict__ B,
                                                 const float* __restrict__ bias,
                                                 float* __restrict__ Cf,
                                                 _Float16* __restrict__ Ch,
                                                 int M, int N, int K) {
    const int wave = threadIdx.x >> 6;
    const int lane = threadIdx.x & 63;
    const int m_base = (blockIdx.x * 4 + wave) * 32;
    const int n_base = blockIdx.y * (NT * 16);
    const int row = lane & 15;
    const int kq = (lane >> 4) * 8;

    f4v acc[2][NT];
    #pragma unroll
    for (int i = 0; i < 2; i++)
        #pragma unroll
        for (int j = 0; j < NT; j++) {
            f4v z = {0.f, 0.f, 0.f, 0.f};
            acc[i][j] = z;
        }

    int r0 = m_base + row;      if (r0 >= M) r0 = M - 1;
    int r1 = m_base + 16 + row; if (r1 >= M) r1 = M - 1;
    const _Float16* a0p = A + (size_t)r0 * K + kq;
    const _Float16* a1p = A + (size_t)r1 * K + kq;
    const _Float16* bp  = B + (size_t)(n_base + row) * K + kq;

    for (int k = 0; k < K; k += 32) {
        h8 a0 = *(const h8*)(a0p + k);
        h8 a1 = *(const h8*)(a1p + k);
        #pragma unroll
        for (int j = 0; j < NT; j++) {
            h8 b = *(const h8*)(bp + (size_t)j * 16 * K + k);
            acc[0][j] = __builtin_amdgcn_mfma_f32_16x16x32_f16(a0, b, acc[0][j], 0, 0, 0);
            acc[1][j] = __builtin_amdgcn_mfma_f32_16x16x32_f16(a1, b, acc[1][j], 0, 0, 0);
        }
    }

    const int col = lane & 15;
    const int rb = (lane >> 4) * 4;
    #pragma unroll
    for (int ms = 0; ms < 2; ms++) {
        #pragma unroll
        for (int j = 0; j < NT; j++) {
            #pragma unroll
            for (int r = 0; r < 4; r++) {
                int m = m_base + ms * 16 + rb + r;
                if (m < M) {
                    int n = n_base + j * 16 + col;
                    float v = acc[ms][j][r];
                    if (bias) v += bias[n];
                    if (Cf) Cf[(size_t)m * N + n] = v;
                    if (Ch) Ch[(size_t)m * N + n] = (_Float16)v;
                }
            }
        }
    }
}

// ---------------- per-node el/er ----------------

__global__ void node_elr_h(const _Float16* __restrict__ feat, const float* __restrict__ al,
                           const float* __restrict__ ar, float* __restrict__ el,
                           float* __restrict__ er, int nN) {
    int t = blockIdx.x * blockDim.x + threadIdx.x;
    if (t >= nN * 4) return;
    int n = t >> 2, h = t & 3;
    const _Float16* f = feat + (size_t)n * 256 + h * 64;
    const float* a = al + h * 64;
    const float* r = ar + h * 64;
    float sl = 0.f, sr = 0.f;
    #pragma unroll
    for (int j = 0; j < 64; j += 8) {
        h8 fv = *(const h8*)(f + j);
        #pragma unroll
        for (int q = 0; q < 8; q++) {
            float x = (float)fv[q];
            sl = fmaf(x, a[j + q], sl);
            sr = fmaf(x, r[j + q], sr);
        }
    }
    el[t] = sl; er[t] = sr;
}

__global__ void node_elr_f2(const float* __restrict__ feat, const float* __restrict__ al,
                            const float* __restrict__ ar, float* __restrict__ el,
                            float* __restrict__ er, int nN) {
    int t = blockIdx.x * blockDim.x + threadIdx.x;
    if (t >= nN) return;
    const float* f = feat + (size_t)t * 32;
    float sl = 0.f, sr = 0.f;
    #pragma unroll
    for (int j = 0; j < 16; j += 4) {
        float4 fv = *(const float4*)(f + j);
        float4 av = *(const float4*)(al + j);
        float4 rv = *(const float4*)(ar + j);
        sl += fv.x * av.x + fv.y * av.y + fv.z * av.z + fv.w * av.w;
        sr += fv.x * rv.x + fv.y * rv.y + fv.z * rv.z + fv.w * rv.w;
    }
    el[t] = sl; er[t] = sr;
}

// ---------------- fused GAT edge stage, H=4 ----------------
// one wave per dst node. Fast path (deg<=64): lane i owns edge i — single gather,
// in-register softmax (butterfly width adapted to deg); LDS holds packed
// {attention(f32), src} int2 per (edge,head) so phase B needs ONE ds_read_b64
// per edge (no ds_bpermute). Phase B: 2 edge-slots x 32 feature-chunks, h8 loads,
// unroll-4. All __shfl under wave-uniform control flow (round-5 lesson).

template<bool WRITE_A, bool HAS_PREV, bool HAS_RES>
__global__ __launch_bounds__(256) void gat_fused4(const int* __restrict__ rowstart,
                                                  const int* __restrict__ pk,
                                                  const float* __restrict__ el,
                                                  const float* __restrict__ er,
                                                  const float* __restrict__ es,
                                                  const _Float16* __restrict__ feat,
                                                  const _Float16* __restrict__ aprev,
                                                  _Float16* __restrict__ awrite,
                                                  const _Float16* __restrict__ resh,
                                                  _Float16* __restrict__ outh, int nN) {
    __shared__ int2 as_lds[4][256];   // [wave][edge*4 + h] = {f32 bits of a, src}
    const int wave = threadIdx.x >> 6;
    const int lane = threadIdx.x & 63;
    int n = blockIdx.x * 4 + wave;
    if (n >= nN) return;
    const int r0 = rowstart[n], r1 = rowstart[n + 1];
    const int deg = r1 - r0;
    float4 er4 = *(const float4*)(er + n * 4);

    if (deg <= 64) {
        // ---- phase A: one edge per lane, in-register softmax ----
        const int idx = r0 + lane;
        const bool act = idx < r1;
        int p = act ? pk[idx] : 0;
        int psrc = p & 0xFFFF;
        float4 v4 = {-INFINITY, -INFINITY, -INFINITY, -INFINITY};
        if (act) {
            float4 e4 = *(const float4*)(el + psrc * 4);
            float4 c4 = *(const float4*)(es + (p >> 16) * 4);
            float v;
            v = e4.x + er4.x + c4.x; v4.x = v > 0.f ? v : SLOPE * v;
            v = e4.y + er4.y + c4.y; v4.y = v > 0.f ? v : SLOPE * v;
            v = e4.z + er4.z + c4.z; v4.z = v > 0.f ? v : SLOPE * v;
            v = e4.w + er4.w + c4.w; v4.w = v > 0.f ? v : SLOPE * v;
        }
        // butterfly width = smallest pow2 >= deg (wave-uniform deg -> uniform branch)
        float4 m4 = v4;
        #pragma unroll
        for (int off = 1; off <= 8; off <<= 1) {
            m4.x = fmaxf(m4.x, __shfl_xor(m4.x, off));
            m4.y = fmaxf(m4.y, __shfl_xor(m4.y, off));
            m4.z = fmaxf(m4.z, __shfl_xor(m4.z, off));
            m4.w = fmaxf(m4.w, __shfl_xor(m4.w, off));
        }
        if (deg > 16) {
            m4.x = fmaxf(m4.x, __shfl_xor(m4.x, 16));
            m4.y = fmaxf(m4.y, __shfl_xor(m4.y, 16));
            m4.z = fmaxf(m4.z, __shfl_xor(m4.z, 16));
            m4.w = fmaxf(m4.w, __shfl_xor(m4.w, 16));
        }
        if (deg > 32) {
            m4.x = fmaxf(m4.x, __shfl_xor(m4.x, 32));
            m4.y = fmaxf(m4.y, __shfl_xor(m4.y, 32));
            m4.z = fmaxf(m4.z, __shfl_xor(m4.z, 32));
            m4.w = fmaxf(m4.w, __shfl_xor(m4.w, 32));
        }
        float4 ex = {0.f, 0.f, 0.f, 0.f};
        if (act) {
            ex.x = __expf(v4.x - m4.x);
            ex.y = __expf(v4.y - m4.y);
            ex.z = __expf(v4.z - m4.z);
            ex.w = __expf(v4.w - m4.w);
        }
        float4 s4 = ex;
        #pragma unroll
        for (int off = 1; off <= 8; off <<= 1) {
            s4.x += __shfl_xor(s4.x, off);
            s4.y += __shfl_xor(s4.y, off);
            s4.z += __shfl_xor(s4.z, off);
            s4.w += __shfl_xor(s4.w, off);
        }
        if (deg > 16) {
            s4.x += __shfl_xor(s4.x, 16);
            s4.y += __shfl_xor(s4.y, 16);
            s4.z += __shfl_xor(s4.z, 16);
            s4.w += __shfl_xor(s4.w, 16);
        }
        if (deg > 32) {
            s4.x += __shfl_xor(s4.x, 32);
            s4.y += __shfl_xor(s4.y, 32);
            s4.z += __shfl_xor(s4.z, 32);
            s4.w += __shfl_xor(s4.w, 32);
        }
        float4 a4;
        a4.x = ex.x / (s4.x + 1e-9f);
        a4.y = ex.y / (s4.y + 1e-9f);
        a4.z = ex.z / (s4.z + 1e-9f);
        a4.w = ex.w / (s4.w + 1e-9f);
        if (HAS_PREV && act) {
            h4 pv = *(const h4*)(aprev + (size_t)idx * 4);
            a4.x = a4.x * (1.f - ALPHA) + ALPHA * (float)pv[0];
            a4.y = a4.y * (1.f - ALPHA) + ALPHA * (float)pv[1];
            a4.z = a4.z * (1.f - ALPHA) + ALPHA * (float)pv[2];
            a4.w = a4.w * (1.f - ALPHA) + ALPHA * (float)pv[3];
        }
        if (WRITE_A && act) {
            h4 aw;
            aw[0] = (_Float16)a4.x; aw[1] = (_Float16)a4.y;
            aw[2] = (_Float16)a4.z; aw[3] = (_Float16)a4.w;
            *(h4*)(awrite + (size_t)idx * 4) = aw;
        }
        {
            int2* dst_lds = &as_lds[wave][lane * 4];
            dst_lds[0] = make_int2(__float_as_int(a4.x), psrc);
            dst_lds[1] = make_int2(__float_as_int(a4.y), psrc);
            dst_lds[2] = make_int2(__float_as_int(a4.z), psrc);
            dst_lds[3] = make_int2(__float_as_int(a4.w), psrc);
        }

        // ---- phase B: 2 edge-slots x 32 feature-chunks, unroll-4; one b64 LDS read/edge ----
        const int half = lane >> 5;
        const int fl = lane & 31;
        const int h = fl >> 3;
        float acc8[8];
        #pragma unroll
        for (int q = 0; q < 8; q++) acc8[q] = 0.f;
        int i = r0;
        for (; i + 7 < r1; i += 8) {
            int j0 = (i - r0) + half;
            int2 e0 = as_lds[wave][(j0 + 0) * 4 + h];
            int2 e1 = as_lds[wave][(j0 + 2) * 4 + h];
            int2 e2 = as_lds[wave][(j0 + 4) * 4 + h];
            int2 e3 = as_lds[wave][(j0 + 6) * 4 + h];
            float a0 = __int_as_float(e0.x), a1 = __int_as_float(e1.x);
            float a2 = __int_as_float(e2.x), a3 = __int_as_float(e3.x);
            h8 f0 = *(const h8*)(feat + (size_t)e0.y * 256 + fl * 8);
            h8 f1 = *(const h8*)(feat + (size_t)e1.y * 256 + fl * 8);
            h8 f2 = *(const h8*)(feat + (size_t)e2.y * 256 + fl * 8);
            h8 f3 = *(const h8*)(feat + (size_t)e3.y * 256 + fl * 8);
            #pragma unroll
            for (int q = 0; q < 8; q++) acc8[q] = fmaf(a0, (float)f0[q], acc8[q]);
            #pragma unroll
            for (int q = 0; q < 8; q++) acc8[q] = fmaf(a1, (float)f1[q], acc8[q]);
            #pragma unroll
            for (int q = 0; q < 8; q++) acc8[q] = fmaf(a2, (float)f2[q], acc8[q]);
            #pragma unroll
            for (int q = 0; q < 8; q++) acc8[q] = fmaf(a3, (float)f3[q], acc8[q]);
        }
        for (; i + 3 < r1; i += 4) {
            int j0 = (i - r0) + half;
            int2 e0 = as_lds[wave][(j0 + 0) * 4 + h];
            int2 e1 = as_lds[wave][(j0 + 2) * 4 + h];
            float a0 = __int_as_float(e0.x), a1 = __int_as_float(e1.x);
            h8 f0 = *(const h8*)(feat + (size_t)e0.y * 256 + fl * 8);
            h8 f1 = *(const h8*)(feat + (size_t)e1.y * 256 + fl * 8);
            #pragma unroll
            for (int q = 0; q < 8; q++) acc8[q] = fmaf(a0, (float)f0[q], acc8[q]);
            #pragma unroll
            for (int q = 0; q < 8; q++) acc8[q] = fmaf(a1, (float)f1[q], acc8[q]);
        }
        for (; i + 1 < r1; i += 2) {
            int j0 = (i - r0) + half;
            int2 e0 = as_lds[wave][j0 * 4 + h];
            float a0 = __int_as_float(e0.x);
            h8 f0 = *(const h8*)(feat + (size_t)e0.y * 256 + fl * 8);
            #pragma unroll
            for (int q = 0; q < 8; q++) acc8[q] = fmaf(a0, (float)f0[q], acc8[q]);
        }
        if (i < r1) {
            int j0 = i - r0;
            int2 e0 = as_lds[wave][j0 * 4 + h];
            float a0 = (half == 0) ? __int_as_float(e0.x) : 0.f;
            h8 f0 = *(const h8*)(feat + (size_t)e0.y * 256 + fl * 8);
            #pragma unroll
            for (int q = 0; q < 8; q++) acc8[q] = fmaf(a0, (float)f0[q], acc8[q]);
        }
        #pragma unroll
        for (int q = 0; q < 8; q++) acc8[q] += __shfl_xor(acc8[q], 32);

        if (half == 0) {
            if (HAS_RES) {
                h8 rv = *(const h8*)(resh + (size_t)n * 256 + fl * 8);
                #pragma unroll
                for (int q = 0; q < 8; q++) acc8[q] += (float)rv[q];
            }
            #pragma unroll
            for (int q = 0; q < 8; q++) acc8[q] = elu_fast(acc8[q]);
            h8 o;
            #pragma unroll
            for (int q = 0; q < 8; q++) o[q] = (_Float16)acc8[q];
            *(h8*)(outh + (size_t)n * 256 + fl * 8) = o;
        }
        return;
    }

    // ---------------- fallback: deg > 64 (two-pass, rare) ----------------
    float4 m4 = {-INFINITY, -INFINITY, -INFINITY, -INFINITY};
    for (int base = r0; base < r1; base += 64) {
        int idx = base + lane;
        if (idx < r1) {
            int p = pk[idx];
            float4 e4 = *(const float4*)(el + (p & 0xFFFF) * 4);
            float4 c4 = *(const float4*)(es + (p >> 16) * 4);
            float v;
            v = e4.x + er4.x + c4.x; v = v > 0.f ? v : SLOPE * v; m4.x = fmaxf(m4.x, v);
            v = e4.y + er4.y + c4.y; v = v > 0.f ? v : SLOPE * v; m4.y = fmaxf(m4.y, v);
            v = e4.z + er4.z + c4.z; v = v > 0.f ? v : SLOPE * v; m4.z = fmaxf(m4.z, v);
            v = e4.w + er4.w + c4.w; v = v > 0.f ? v : SLOPE * v; m4.w = fmaxf(m4.w, v);
        }
    }
    #pragma unroll
    for (int off = 1; off < 64; off <<= 1) {
        m4.x = fmaxf(m4.x, __shfl_xor(m4.x, off));
        m4.y = fmaxf(m4.y, __shfl_xor(m4.y, off));
        m4.z = fmaxf(m4.z, __shfl_xor(m4.z, off));
        m4.w = fmaxf(m4.w, __shfl_xor(m4.w, off));
    }
    float4 s4 = {0.f, 0.f, 0.f, 0.f};
    for (int base = r0; base < r1; base += 64) {
        int idx = base + lane;
        if (idx < r1) {
            int p = pk[idx];
            float4 e4 = *(const float4*)(el + (p & 0xFFFF) * 4);
            float4 c4 = *(const float4*)(es + (p >> 16) * 4);
            float4 exv;
            float v;
            v = e4.x + er4.x + c4.x; v = v > 0.f ? v : SLOPE * v; exv.x = __expf(v - m4.x);
            v = e4.y + er4.y + c4.y; v = v > 0.f ? v : SLOPE * v; exv.y = __expf(v - m4.y);
            v = e4.z + er4.z + c4.z; v = v > 0.f ? v : SLOPE * v; exv.z = __expf(v - m4.z);
            v = e4.w + er4.w + c4.w; v = v > 0.f ? v : SLOPE * v; exv.w = __expf(v - m4.w);
            if (base == r0) {
                int2* dst_lds = &as_lds[wave][lane * 4];
                dst_lds[0] = make_int2(__float_as_int(exv.x), 0);
                dst_lds[1] = make_int2(__float_as_int(exv.y), 0);
                dst_lds[2] = make_int2(__float_as_int(exv.z), 0);
                dst_lds[3] = make_int2(__float_as_int(exv.w), 0);
            }
            s4.x += exv.x; s4.y += exv.y; s4.z += exv.z; s4.w += exv.w;
        }
    }
    #pragma unroll
    for (int off = 1; off < 64; off <<= 1) {
        s4.x += __shfl_xor(s4.x, off);
        s4.y += __shfl_xor(s4.y, off);
        s4.z += __shfl_xor(s4.z, off);
        s4.w += __shfl_xor(s4.w, off);
    }
    float4 inv4;
    inv4.x = 1.f / (s4.x + 1e-9f); inv4.y = 1.f / (s4.y + 1e-9f);
    inv4.z = 1.f / (s4.z + 1e-9f); inv4.w = 1.f / (s4.w + 1e-9f);
    {
        int idx = r0 + lane;   // deg > 64 -> always valid
        float4 a;
        a.x = __int_as_float(as_lds[wave][lane * 4 + 0].x) * inv4.x;
        a.y = __int_as_float(as_lds[wave][lane * 4 + 1].x) * inv4.y;
        a.z = __int_as_float(as_lds[wave][lane * 4 + 2].x) * inv4.z;
        a.w = __int_as_float(as_lds[wave][lane * 4 + 3].x) * inv4.w;
        if (HAS_PREV) {
            h4 pv = *(const h4*)(aprev + (size_t)idx * 4);
            a.x = a.x * (1.f - ALPHA) + ALPHA * (float)pv[0];
            a.y = a.y * (1.f - ALPHA) + ALPHA * (float)pv[1];
            a.z = a.z * (1.f - ALPHA) + ALPHA * (float)pv[2];
            a.w = a.w * (1.f - ALPHA) + ALPHA * (float)pv[3];
        }
        if (WRITE_A) {
            h4 aw;
            aw[0] = (_Float16)a.x; aw[1] = (_Float16)a.y;
            aw[2] = (_Float16)a.z; aw[3] = (_Float16)a.w;
            *(h4*)(awrite + (size_t)idx * 4) = aw;
        }
        as_lds[wave][lane * 4 + 0].x = __float_as_int(a.x);
        as_lds[wave][lane * 4 + 1].x = __float_as_int(a.y);
        as_lds[wave][lane * 4 + 2].x = __float_as_int(a.z);
        as_lds[wave][lane * 4 + 3].x = __float_as_int(a.w);
    }
    if (WRITE_A) {
        for (int base = r0 + 64; base < r1; base += 64) {
            int idx = base + lane;
            if (idx < r1) {
                int p = pk[idx];
                float4 e4 = *(const float4*)(el + (p & 0xFFFF) * 4);
                float4 c4 = *(const float4*)(es + (p >> 16) * 4);
                float4 a;
                float v;
                v = e4.x + er4.x + c4.x; v = v > 0.f ? v : SLOPE * v; a.x = __expf(v - m4.x) * inv4.x;
                v = e4.y + er4.y + c4.y; v = v > 0.f ? v : SLOPE * v; a.y = __expf(v - m4.y) * inv4.y;
                v = e4.z + er4.z + c4.z; v = v > 0.f ? v : SLOPE * v; a.z = __expf(v - m4.z) * inv4.z;
                v = e4.w + er4.w + c4.w; v = v > 0.f ? v : SLOPE * v; a.w = __expf(v - m4.w) * inv4.w;
                if (HAS_PREV) {
                    h4 pv = *(const h4*)(aprev + (size_t)idx * 4);
                    a.x = a.x * (1.f - ALPHA) + ALPHA * (float)pv[0];
                    a.y = a.y * (1.f - ALPHA) + ALPHA * (float)pv[1];
                    a.z = a.z * (1.f - ALPHA) + ALPHA * (float)pv[2];
                    a.w = a.w * (1.f - ALPHA) + ALPHA * (float)pv[3];
                }
                h4 aw;
                aw[0] = (_Float16)a.x; aw[1] = (_Float16)a.y;
                aw[2] = (_Float16)a.z; aw[3] = (_Float16)a.w;
                *(h4*)(awrite + (size_t)idx * 4) = aw;
            }
        }
    }
    const int h = lane >> 4;
    float4 acc = {0.f, 0.f, 0.f, 0.f};
    const int cap = r0 + 64;
    for (int i = r0; i < cap; i++) {
        int p = pk[i];
        float av = __int_as_float(as_lds[wave][(i - r0) * 4 + h].x);
        h4 f = *(const h4*)(feat + (size_t)(p & 0xFFFF) * 256 + lane * 4);
        acc.x = fmaf(av, (float)f[0], acc.x);
        acc.y = fmaf(av, (float)f[1], acc.y);
        acc.z = fmaf(av, (float)f[2], acc.z);
        acc.w = fmaf(av, (float)f[3], acc.w);
    }
    {
        float mh = sel4(m4, h), invh = sel4(inv4, h), erh = sel4(er4, h);
        for (int i = cap; i < r1; i++) {
            int p = pk[i];
            int s = p & 0xFFFF, t = p >> 16;
            float v = el[s * 4 + h] + erh + es[t * 4 + h];
            v = v > 0.f ? v : SLOPE * v;
            float a = __expf(v - mh) * invh;
            if (HAS_PREV) a = a * (1.f - ALPHA) + ALPHA * (float)aprev[(size_t)i * 4 + h];
            h4 f = *(const h4*)(feat + (size_t)s * 256 + lane * 4);
            acc.x = fmaf(a, (float)f[0], acc.x);
            acc.y = fmaf(a, (float)f[1], acc.y);
            acc.z = fmaf(a, (float)f[2], acc.z);
            acc.w = fmaf(a, (float)f[3], acc.w);
        }
    }
    if (HAS_RES) {
        h4 rv = *(const h4*)(resh + (size_t)n * 256 + lane * 4);
        acc.x += (float)rv[0]; acc.y += (float)rv[1];
        acc.z += (float)rv[2]; acc.w += (float)rv[3];
    }
    acc.x = elu_fast(acc.x);
    acc.y = elu_fast(acc.y);
    acc.z = elu_fast(acc.z);
    acc.w = elu_fast(acc.w);
    h4 o;
    o[0] = (_Float16)acc.x; o[1] = (_Float16)acc.y;
    o[2] = (_Float16)acc.z; o[3] = (_Float16)acc.w;
    *(h4*)(outh + (size_t)n * 256 + lane * 4) = o;
}

// ---------------- fused GAT layer 2 (H=1, C=16): one wave per node ----------------

__global__ __launch_bounds__(256) void gat_fused1(const int* __restrict__ rowstart,
                                                  const int* __restrict__ pk,
                                                  const float* __restrict__ el,
                                                  const float* __restrict__ er,
                                                  const float* __restrict__ es,
                                                  const float* __restrict__ cpack,
                                                  float* __restrict__ out, int nN) {
    const int wave = threadIdx.x >> 6;
    const int lane = threadIdx.x & 63;
    int n = blockIdx.x * 4 + wave;
    if (n >= nN) return;
    const int r0 = rowstart[n], r1 = rowstart[n + 1];
    const int deg = r1 - r0;
    const float ern = er[n];

    if (deg <= 64) {
        const int idx = r0 + lane;
        const bool act = idx < r1;
        int p = act ? pk[idx] : 0;
        int psrc = p & 0xFFFF;
        float v = -INFINITY;
        if (act) {
            float t = el[psrc] + ern + es[p >> 16];
            v = t > 0.f ? t : SLOPE * t;
        }
        float m = v;
        #pragma unroll
        for (int off = 1; off <= 8; off <<= 1) m = fmaxf(m, __shfl_xor(m, off));
        if (deg > 16) m = fmaxf(m, __shfl_xor(m, 16));
        if (deg > 32) m = fmaxf(m, __shfl_xor(m, 32));
        float ex = act ? __expf(v - m) : 0.f;
        float s = ex;
        #pragma unroll
        for (int off = 1; off <= 8; off <<= 1) s += __shfl_xor(s, off);
        if (deg > 16) s += __shfl_xor(s, 16);
        if (deg > 32) s += __shfl_xor(s, 32);
        float a = ex / (s + 1e-9f);

        const int eslot = lane >> 4, fl = lane & 15;
        float acc = 0.f;
        int i = r0;
        for (; i + 7 < r1; i += 8) {
            int j0 = (i - r0) + eslot;
            int j1 = j0 + 4;
            int s0 = __shfl(psrc, j0);
            int s1 = __shfl(psrc, j1);
            float a0 = __shfl(a, j0);
            float a1 = __shfl(a, j1);
            float f0 = cpack[(size_t)s0 * 32 + fl];
            float f1 = cpack[(size_t)s1 * 32 + fl];
            acc = fmaf(a0, f0, acc);
            acc = fmaf(a1, f1, acc);
        }
        for (; i + 3 < r1; i += 4) {
            int j = (i - r0) + eslot;
            int sj = __shfl(psrc, j);
            float aj = __shfl(a, j);
            acc = fmaf(aj, cpack[(size_t)sj * 32 + fl], acc);
        }
        int rem = r1 - i;
        if (rem > 0) {   // wave-uniform branch: full exec for the shfls below
            int j = (i - r0) + (eslot < rem ? eslot : rem - 1);
            int sj = __shfl(psrc, j);
            float aj = __shfl(a, j);
            if (eslot >= rem) aj = 0.f;   // masked lanes contribute nothing
            acc = fmaf(aj, cpack[(size_t)sj * 32 + fl], acc);
        }
        acc += __shfl_xor(acc, 16);
        acc += __shfl_xor(acc, 32);
        if (lane < 16) out[(size_t)n * 16 + lane] = acc + cpack[(size_t)n * 32 + 16 + lane];
        return;
    }

    // fallback deg > 64 (rare)
    float m = -INFINITY;
    for (int base = r0; base < r1; base += 64) {
        int idx = base + lane;
        if (idx < r1) {
            int p = pk[idx];
            float v = el[p & 0xFFFF] + ern + es[p >> 16];
            v = v > 0.f ? v : SLOPE * v;
            m = fmaxf(m, v);
        }
    }
    #pragma unroll
    for (int off = 1; off < 64; off <<= 1) m = fmaxf(m, __shfl_xor(m, off));
    float s = 0.f;
    for (int base = r0; base < r1; base += 64) {
        int idx = base + lane;
        if (idx < r1) {
            int p = pk[idx];
            float v = el[p & 0xFFFF] + ern + es[p >> 16];
            v = v > 0.f ? v : SLOPE * v;
            s += __expf(v - m);
        }
    }
    #pragma unroll
    for (int off = 1; off < 64; off <<= 1) s += __shfl_xor(s, off);
    float inv = 1.f / (s + 1e-9f);
    const int eslot = lane >> 4, fl = lane & 15;
    float acc = 0.f;
    for (int i = r0; i < r1; i += 4) {
        int rem = r1 - i;
        if (eslot < rem) {   // no shfl inside: divergence safe
            int j = i + eslot;
            int p = pk[j];
            float v = el[p & 0xFFFF] + ern + es[p >> 16];
            v = v > 0.f ? v : SLOPE * v;
            float a = __expf(v - m) * inv;
            acc = fmaf(a, cpack[(size_t)(p & 0xFFFF) * 32 + fl], acc);
        }
    }
    acc += __shfl_xor(acc, 16);
    acc += __shfl_xor(acc, 32);
    if (lane < 16) out[(size_t)n * 16 + lane] = acc + cpack[(size_t)n * 32 + 16 + lane];
}

// ---------------- host ----------------

extern "C" void kernel_launch(void* const* d_in, const int* in_sizes, int n_in,
                              void* d_out, int out_size, void* d_ws, size_t ws_size,
                              hipStream_t stream) {
    const float* x0 = (const float*)d_in[0];
    const float* x1 = (const float*)d_in[1];
    const float* x2 = (const float*)d_in[2];
    const int* src  = (const int*)d_in[3];
    const int* dst  = (const int*)d_in[4];
    const int* et   = (const int*)d_in[5];
    const float* W0 = (const float*)d_in[6];  const float* b0 = (const float*)d_in[7];
    const float* W1 = (const float*)d_in[8];  const float* b1 = (const float*)d_in[9];
    const float* W2 = (const float*)d_in[10]; const float* b2 = (const float*)d_in[11];
    const float* Wg0 = (const float*)d_in[12]; const float* etab0 = (const float*)d_in[13];
    const float* We0 = (const float*)d_in[14]; const float* al0 = (const float*)d_in[15];
    const float* ar0 = (const float*)d_in[16]; const float* ae0 = (const float*)d_in[17];
    const float* Wg1 = (const float*)d_in[18]; const float* etab1 = (const float*)d_in[19];
    const float* We1 = (const float*)d_in[20]; const float* al1 = (const float*)d_in[21];
    const float* ar1 = (const float*)d_in[22]; const float* ae1 = (const float*)d_in[23];
    const float* Wg2 = (const float*)d_in[24]; const float* etab2 = (const float*)d_in[25];
    const float* We2 = (const float*)d_in[26]; const float* al2 = (const float*)d_in[27];
    const float* ar2 = (const float*)d_in[28]; const float* ae2 = (const float*)d_in[29];
    const float* resW2 = (const float*)d_in[30];
    float* outp = (float*)d_out;

    char* p = (char*)d_ws;
    auto alloc = [&](size_t bytes) -> void* {
        void* r = (void*)p;
        p += (bytes + 255) & ~(size_t)255;
        return r;
    };
    _Float16* x0h   = (_Float16*)alloc((size_t)N0 * 128 * 2);
    _Float16* x1h   = (_Float16*)alloc((size_t)N1 * 64 * 2);
    _Float16* x2h   = (_Float16*)alloc((size_t)N2 * 32 * 2);
    _Float16* W0h   = (_Float16*)alloc(64 * 128 * 2);
    _Float16* W1h   = (_Float16*)alloc(64 * 64 * 2);
    _Float16* W2h   = (_Float16*)alloc(64 * 32 * 2);
    _Float16* Wg0h  = (_Float16*)alloc(256 * 64 * 2);
    _Float16* Wg1h  = (_Float16*)alloc(256 * 256 * 2);
    _Float16* wpkh  = (_Float16*)alloc(32 * 256 * 2);
    _Float16* h0h   = (_Float16*)alloc((size_t)NN * 64 * 2);
    _Float16* feath = (_Float16*)alloc((size_t)NN * 256 * 2);
    _Float16* bufAh = (_Float16*)alloc((size_t)NN * 256 * 2);
    _Float16* bufBh = (_Float16*)alloc((size_t)NN * 256 * 2);
    _Float16* a0h   = (_Float16*)alloc((size_t)EE * 4 * 2);
    float* el    = (float*)alloc((size_t)NN * 4 * 4);
    float* er    = (float*)alloc((size_t)NN * 4 * 4);
    float* es    = (float*)alloc(96 * 4);
    float* cpack = (float*)alloc((size_t)NN * 32 * 4);
    int* rowstart = (int*)alloc((size_t)(NN + 1) * 4);
    int* deg      = (int*)alloc((size_t)NN * 4);
    int* cursor   = (int*)alloc((size_t)NN * 4);
    int* bsum     = (int*)alloc(256 * 4);
    int* pk       = (int*)alloc((size_t)EE * 4);

    const int EB = (EE + 255) / 256;        // 3125
    const int NB = (NN + 255) / 256;        // 196
    const int NHB = (NN * 4 + 255) / 256;   // 782
    const int MB128 = (NN + 127) / 128;     // 391
    const int WB = (NN + 3) / 4;            // 12500

    // CSR build
    hipMemsetAsync(deg, 0, (size_t)NN * 4, stream);
    hist_kernel<<<EB, 256, 0, stream>>>(dst, deg, EE);
    block_sum_kernel<<<NB, 256, 0, stream>>>(deg, bsum, NN);
    scan_bsum_kernel<<<1, 256, 0, stream>>>(bsum, NB);
    scan_out_kernel<<<NB, 256, 0, stream>>>(deg, bsum, rowstart, cursor, NN);
    scatter_kernel<<<EB, 256, 0, stream>>>(src, dst, et, cursor, pk, EE);

    // es tables + weight/feature converts
    es_table_all<<<72, 64, 0, stream>>>(etab0, We0, ae0, etab1, We1, ae1, etab2, We2, ae2, es);
    {
        int n0c = N0 * 128, n1c = N1 * 64, n2c = N2 * 32;
        int total = n0c + n1c + n2c + 8192 + 4096 + 2048 + 16384 + 65536 + 4096 + 4096;
        f2h10<<<(total + 255) / 256, 256, 0, stream>>>(
            x0, x0h, n0c, x1, x1h, n1c, x2, x2h, n2c,
            W0, W0h, 8192, W1, W1h, 4096, W2, W2h, 2048,
            Wg0, Wg0h, 16384, Wg1, Wg1h, 65536,
            Wg2, wpkh, 4096, resW2, wpkh + 4096, 4096);
    }

    // input projections -> h0h [N,64] fp16
    gemm_mfma<4><<<dim3((N0 + 127) / 128, 1), 256, 0, stream>>>(x0h, W0h, b0, nullptr, h0h, N0, 64, 128);
    gemm_mfma<4><<<dim3((N1 + 127) / 128, 1), 256, 0, stream>>>(x1h, W1h, b1, nullptr, h0h + (size_t)N0 * 64, N1, 64, 64);
    gemm_mfma<4><<<dim3((N2 + 127) / 128, 1), 256, 0, stream>>>(x2h, W2h, b2, nullptr, h0h + (size_t)(N0 + N1) * 64, N2, 64, 32);

    // ---- GAT layer 0 ----
    gemm_mfma<8><<<dim3(MB128, 2), 256, 0, stream>>>(h0h, Wg0h, nullptr, nullptr, feath, NN, 256, 64);
    node_elr_h<<<NHB, 256, 0, stream>>>(feath, al0, ar0, el, er, NN);
    gat_fused4<true, false, false><<<WB, 256, 0, stream>>>(
        rowstart, pk, el, er, es + 0, feath, nullptr, a0h, nullptr, bufAh, NN);

    // ---- GAT layer 1 ----
    gemm_mfma<8><<<dim3(MB128, 2), 256, 0, stream>>>(bufAh, Wg1h, nullptr, nullptr, feath, NN, 256, 256);
    node_elr_h<<<NHB, 256, 0, stream>>>(feath, al1, ar1, el, er, NN);
    gat_fused4<false, true, true><<<WB, 256, 0, stream>>>(
        rowstart, pk, el, er, es + 32, feath, a0h, nullptr, bufAh, bufBh, NN);

    // ---- GAT layer 2 (H=1, C=16, linear residual, no act) ----
    gemm_mfma<2><<<dim3(MB128, 1), 256, 0, stream>>>(bufBh, wpkh, nullptr, cpack, nullptr, NN, 32, 256);
    node_elr_f2<<<NB, 256, 0, stream>>>(cpack, al2, ar2, el, er, NN);
    gat_fused1<<<WB, 256, 0, stream>>>(rowstart, pk, el, er, es + 64, cpack, outp, NN);
}

// Round 9
// 480.138 us; speedup vs baseline: 1.0986x; 1.0986x over previous
//
#include <hip/hip_runtime.h>
#include <math.h>

#define N0 20000
#define N1 15000
#define N2 15000
#define NN 50000          // total nodes
#define EE 800000         // edges
#define SLOPE 0.2f
#define ALPHA 0.05f

typedef _Float16 h8 __attribute__((ext_vector_type(8)));
typedef _Float16 h4 __attribute__((ext_vector_type(4)));
typedef float f4v __attribute__((ext_vector_type(4)));

__device__ __forceinline__ float sel4(float4 v, int h) {
    float lo = (h & 1) ? v.y : v.x;
    float hi = (h & 1) ? v.w : v.z;
    return (h & 2) ? hi : lo;
}

__device__ __forceinline__ float elu_fast(float x) {
    return x > 0.f ? x : __expf(x) - 1.f;
}

// ---------------- CSR build ----------------

__global__ void hist_kernel(const int* __restrict__ dst, int* __restrict__ deg, int E_) {
    int e = blockIdx.x * blockDim.x + threadIdx.x;
    if (e < E_) atomicAdd(&deg[dst[e]], 1);
}

__global__ __launch_bounds__(256) void block_sum_kernel(const int* __restrict__ deg,
                                                        int* __restrict__ bsum, int n) {
    int i = blockIdx.x * 256 + threadIdx.x;
    int v = (i < n) ? deg[i] : 0;
    #pragma unroll
    for (int off = 32; off > 0; off >>= 1) v += __shfl_down(v, off);
    __shared__ int sh[4];
    if ((threadIdx.x & 63) == 0) sh[threadIdx.x >> 6] = v;
    __syncthreads();
    if (threadIdx.x == 0) bsum[blockIdx.x] = sh[0] + sh[1] + sh[2] + sh[3];
}

__global__ __launch_bounds__(256) void scan_bsum_kernel(int* __restrict__ bsum, int nb) {
    __shared__ int sh[256];
    int tid = threadIdx.x;
    int v = (tid < nb) ? bsum[tid] : 0;
    sh[tid] = v;
    __syncthreads();
    #pragma unroll
    for (int off = 1; off < 256; off <<= 1) {
        int t = (tid >= off) ? sh[tid - off] : 0;
        __syncthreads();
        sh[tid] += t;
        __syncthreads();
    }
    if (tid < nb) bsum[tid] = sh[tid] - v;   // exclusive
}

__global__ __launch_bounds__(256) void scan_out_kernel(const int* __restrict__ deg,
                                                       const int* __restrict__ boff,
                                                       int* __restrict__ rowstart,
                                                       int* __restrict__ cursor, int n) {
    __shared__ int sh[256];
    int tid = threadIdx.x;
    int i = blockIdx.x * 256 + tid;
    int v = (i < n) ? deg[i] : 0;
    sh[tid] = v;
    __syncthreads();
    #pragma unroll
    for (int off = 1; off < 256; off <<= 1) {
        int t = (tid >= off) ? sh[tid - off] : 0;
        __syncthreads();
        sh[tid] += t;
        __syncthreads();
    }
    int excl = sh[tid] - v + boff[blockIdx.x];
    if (i < n) { rowstart[i] = excl; cursor[i] = excl; }
    if (i == n - 1) rowstart[n] = excl + v;
}

__global__ void scatter_kernel(const int* __restrict__ src, const int* __restrict__ dst,
                               const int* __restrict__ et, int* __restrict__ cursor,
                               int* __restrict__ pk, int E_) {
    int e = blockIdx.x * blockDim.x + threadIdx.x;
    if (e >= E_) return;
    int d = dst[e];
    int p = atomicAdd(&cursor[d], 1);
    pk[p] = (et[e] << 16) | src[e];
}

// ---------------- es tables (all 3 layers, one launch) ----------------

__global__ void es_table_all(const float* __restrict__ etab0, const float* __restrict__ We0,
                             const float* __restrict__ ae0,
                             const float* __restrict__ etab1, const float* __restrict__ We1,
                             const float* __restrict__ ae1,
                             const float* __restrict__ etab2, const float* __restrict__ We2,
                             const float* __restrict__ ae2,
                             float* __restrict__ es) {
    int b = blockIdx.x;
    const float *etab, *We, *ae;
    float* out;
    int H;
    if (b < 32)      { etab = etab0; We = We0; ae = ae0; out = es;      H = 4; }
    else if (b < 64) { b -= 32; etab = etab1; We = We1; ae = ae1; out = es + 32; H = 4; }
    else             { b -= 64; etab = etab2; We = We2; ae = ae2; out = es + 64; H = 1; }
    int t = b / H, h = b % H;
    int j = threadIdx.x;   // 0..63
    const float* w = We + (size_t)(h * 64 + j) * 64;
    const float* e = etab + t * 64;
    float s = 0.f;
    #pragma unroll
    for (int k = 0; k < 64; k += 4) {
        float4 wv = *(const float4*)(w + k);
        float4 ev = *(const float4*)(e + k);
        s += wv.x * ev.x + wv.y * ev.y + wv.z * ev.z + wv.w * ev.w;
    }
    s *= ae[h * 64 + j];
    #pragma unroll
    for (int off = 32; off > 0; off >>= 1) s += __shfl_down(s, off);
    if (j == 0) out[t * H + h] = s;
}

// ---------------- fp32 -> fp16 converts ----------------

__global__ void f2h10(const float* s0, _Float16* d0, int n0,
                      const float* s1, _Float16* d1, int n1,
                      const float* s2, _Float16* d2, int n2,
                      const float* s3, _Float16* d3, int n3,
                      const float* s4, _Float16* d4, int n4,
                      const float* s5, _Float16* d5, int n5,
                      const float* s6, _Float16* d6, int n6,
                      const float* s7, _Float16* d7, int n7,
                      const float* s8, _Float16* d8, int n8,
                      const float* s9, _Float16* d9, int n9) {
    int t = blockIdx.x * 256 + threadIdx.x;
    if (t < n0) { d0[t] = (_Float16)s0[t]; return; } t -= n0;
    if (t < n1) { d1[t] = (_Float16)s1[t]; return; } t -= n1;
    if (t < n2) { d2[t] = (_Float16)s2[t]; return; } t -= n2;
    if (t < n3) { d3[t] = (_Float16)s3[t]; return; } t -= n3;
    if (t < n4) { d4[t] = (_Float16)s4[t]; return; } t -= n4;
    if (t < n5) { d5[t] = (_Float16)s5[t]; return; } t -= n5;
    if (t < n6) { d6[t] = (_Float16)s6[t]; return; } t -= n6;
    if (t < n7) { d7[t] = (_Float16)s7[t]; return; } t -= n7;
    if (t < n8) { d8[t] = (_Float16)s8[t]; return; } t -= n8;
    if (t < n9) { d9[t] = (_Float16)s9[t]; }
}

// ---------------- MFMA fp16 GEMM body (verified fragment mapping) ----------------
// ELR: 0 = none; 1 = fused el/er epilogue for H=4/D=64 layers (each y-block covers
// 2 heads: hb = n_base>>6); 2 = fused el/er for layer 2 (H=1, D=16 = j==0 tile).
// el/er are computed from fp32 accumulators via 16-lane quad butterflies
// (exec is full throughout the epilogue — no shfl under divergence).

template<int NT, int ELR>
__device__ __forceinline__ void gemm_body(int bx, int by,
                                          const _Float16* __restrict__ A,
                                          const _Float16* __restrict__ B,
                                          const float* __restrict__ bias,
                                          float* __restrict__ Cf,
                                          _Float16* __restrict__ Ch,
                                          float* __restrict__ el,
                                          float* __restrict__ er,
                                          const float* __restrict__ al,
                                          const float* __restrict__ ar,
                                          int M, int N, int K) {
    const int wave = threadIdx.x >> 6;
    const int lane = threadIdx.x & 63;
    const int m_base = (bx * 4 + wave) * 32;
    const int n_base = by * (NT * 16);
    const int row = lane & 15;
    const int kq = (lane >> 4) * 8;

    f4v acc[2][NT];
    #pragma unroll
    for (int i = 0; i < 2; i++)
        #pragma unroll
        for (int j = 0; j < NT; j++) {
            f4v z = {0.f, 0.f, 0.f, 0.f};
            acc[i][j] = z;
        }

    int ra = m_base + row;      if (ra >= M) ra = M - 1;
    int rb2 = m_base + 16 + row; if (rb2 >= M) rb2 = M - 1;
    const _Float16* a0p = A + (size_t)ra * K + kq;
    const _Float16* a1p = A + (size_t)rb2 * K + kq;
    const _Float16* bp  = B + (size_t)(n_base + row) * K + kq;

    for (int k = 0; k < K; k += 32) {
        h8 a0 = *(const h8*)(a0p + k);
        h8 a1 = *(const h8*)(a1p + k);
        #pragma unroll
        for (int j = 0; j < NT; j++) {
            h8 b = *(const h8*)(bp + (size_t)j * 16 * K + k);
            acc[0][j] = __builtin_amdgcn_mfma_f32_16x16x32_f16(a0, b, acc[0][j], 0, 0, 0);
            acc[1][j] = __builtin_amdgcn_mfma_f32_16x16x32_f16(a1, b, acc[1][j], 0, 0, 0);
        }
    }

    const int col = lane & 15;
    const int rb = (lane >> 4) * 4;

    // ---- fused el/er epilogue ----
    if (ELR == 1) {
        float alw[NT], arw[NT];
        #pragma unroll
        for (int j = 0; j < NT; j++) {
            int cg = n_base + j * 16 + col;
            int hg = cg >> 6, d = cg & 63;
            alw[j] = al[hg * 64 + d];
            arw[j] = ar[hg * 64 + d];
        }
        const int hb = n_base >> 6;
        #pragma unroll
        for (int ms = 0; ms < 2; ms++) {
            #pragma unroll
            for (int r = 0; r < 4; r++) {
                float e0 = 0.f, e1 = 0.f, f0 = 0.f, f1 = 0.f;
                #pragma unroll
                for (int j = 0; j < NT; j++) {
                    float av = acc[ms][j][r];
                    if (j < NT / 2) { e0 = fmaf(av, alw[j], e0); f0 = fmaf(av, arw[j], f0); }
                    else            { e1 = fmaf(av, alw[j], e1); f1 = fmaf(av, arw[j], f1); }
                }
                #pragma unroll
                for (int off = 1; off <= 8; off <<= 1) {
                    e0 += __shfl_xor(e0, off);
                    e1 += __shfl_xor(e1, off);
                    f0 += __shfl_xor(f0, off);
                    f1 += __shfl_xor(f1, off);
                }
                int m = m_base + ms * 16 + rb + r;
                if (col == 0 && m < M) {
                    el[m * 4 + hb]     = e0;
                    el[m * 4 + hb + 1] = e1;
                    er[m * 4 + hb]     = f0;
                    er[m * 4 + hb + 1] = f1;
                }
            }
        }
    }
    if (ELR == 2) {
        float alw = al[col], arw = ar[col];
        #pragma unroll
        for (int ms = 0; ms < 2; ms++) {
            #pragma unroll
            for (int r = 0; r < 4; r++) {
                float e = acc[ms][0][r] * alw;
                float f = acc[ms][0][r] * arw;
                #pragma unroll
                for (int off = 1; off <= 8; off <<= 1) {
                    e += __shfl_xor(e, off);
                    f += __shfl_xor(f, off);
                }
                int m = m_base + ms * 16 + rb + r;
                if (col == 0 && m < M) { el[m] = e; er[m] = f; }
            }
        }
    }

    #pragma unroll
    for (int ms = 0; ms < 2; ms++) {
        #pragma unroll
        for (int j = 0; j < NT; j++) {
            #pragma unroll
            for (int r = 0; r < 4; r++) {
                int m = m_base + ms * 16 + rb + r;
                if (m < M) {
                    int n = n_base + j * 16 + col;
                    float v = acc[ms][j][r];
                    if (bias) v += bias[n];
                    if (Cf) Cf[(size_t)m * N + n] = v;
                    if (Ch) Ch[(size_t)m * N + n] = (_Float16)v;
                }
            }
        }
    }
}

template<int NT, int ELR>
__global__ __launch_bounds__(256) void gemm_mfma(const _Float16* __restrict__ A,
                                                 const _Float16* __restrict__ B,
                                                 const float* __restrict__ bias,
                                                 float* __restrict__ Cf,
                                                 _Float16* __restrict__ Ch,
                                                 float* __restrict__ el,
                                                 float* __restrict__ er,
                                                 const float* __restrict__ al,
                                                 const float* __restrict__ ar,
                                                 int M, int N, int K) {
    gemm_body<NT, ELR>(blockIdx.x, blockIdx.y, A, B, bias, Cf, Ch, el, er, al, ar, M, N, K);
}

// 3 input projections in one dispatch (block-uniform routing)
__global__ __launch_bounds__(256) void proj3(const _Float16* __restrict__ x0h, const _Float16* __restrict__ W0h, const float* __restrict__ b0,
                                             const _Float16* __restrict__ x1h, const _Float16* __restrict__ W1h, const float* __restrict__ b1,
                                             const _Float16* __restrict__ x2h, const _Float16* __restrict__ W2h, const float* __restrict__ b2,
                                             _Float16* __restrict__ h0h, int nb0, int nb1) {
    int b = blockIdx.x;
    if (b < nb0) {
        gemm_body<4, 0>(b, 0, x0h, W0h, b0, nullptr, h0h,
                        nullptr, nullptr, nullptr, nullptr, N0, 64, 128);
    } else if (b < nb0 + nb1) {
        gemm_body<4, 0>(b - nb0, 0, x1h, W1h, b1, nullptr, h0h + (size_t)N0 * 64,
                        nullptr, nullptr, nullptr, nullptr, N1, 64, 64);
    } else {
        gemm_body<4, 0>(b - nb0 - nb1, 0, x2h, W2h, b2, nullptr, h0h + (size_t)(N0 + N1) * 64,
                        nullptr, nullptr, nullptr, nullptr, N2, 64, 32);
    }
}

// ---------------- fused GAT edge stage, H=4 ----------------
// one wave per dst node; LDS layout [wave][h][66] (pad 2) -> conflict-free writes
// (lane-stride 8B = 2-way, free) and bank-spread phase-B reads.
// All __shfl under wave-uniform control flow (round-5 lesson).

template<bool WRITE_A, bool HAS_PREV, bool HAS_RES>
__global__ __launch_bounds__(256) void gat_fused4(const int* __restrict__ rowstart,
                                                  const int* __restrict__ pk,
                                                  const float* __restrict__ el,
                                                  const float* __restrict__ er,
                                                  const float* __restrict__ es,
                                                  const _Float16* __restrict__ feat,
                                                  const _Float16* __restrict__ aprev,
                                                  _Float16* __restrict__ awrite,
                                                  const _Float16* __restrict__ resh,
                                                  _Float16* __restrict__ outh, int nN) {
    __shared__ int2 as_lds[4][4][66];   // [wave][h][edge] = {f32 bits of a, src}
    const int wave = threadIdx.x >> 6;
    const int lane = threadIdx.x & 63;
    int n = blockIdx.x * 4 + wave;
    if (n >= nN) return;
    const int r0 = rowstart[n], r1 = rowstart[n + 1];
    const int deg = r1 - r0;
    float4 er4 = *(const float4*)(er + n * 4);

    if (deg <= 64) {
        // ---- phase A: one edge per lane, in-register softmax ----
        const int idx = r0 + lane;
        const bool act = idx < r1;
        int p = act ? pk[idx] : 0;
        int psrc = p & 0xFFFF;
        float4 v4 = {-INFINITY, -INFINITY, -INFINITY, -INFINITY};
        if (act) {
            float4 e4 = *(const float4*)(el + psrc * 4);
            float4 c4 = *(const float4*)(es + (p >> 16) * 4);
            float v;
            v = e4.x + er4.x + c4.x; v4.x = v > 0.f ? v : SLOPE * v;
            v = e4.y + er4.y + c4.y; v4.y = v > 0.f ? v : SLOPE * v;
            v = e4.z + er4.z + c4.z; v4.z = v > 0.f ? v : SLOPE * v;
            v = e4.w + er4.w + c4.w; v4.w = v > 0.f ? v : SLOPE * v;
        }
        float4 m4 = v4;
        #pragma unroll
        for (int off = 1; off <= 8; off <<= 1) {
            m4.x = fmaxf(m4.x, __shfl_xor(m4.x, off));
            m4.y = fmaxf(m4.y, __shfl_xor(m4.y, off));
            m4.z = fmaxf(m4.z, __shfl_xor(m4.z, off));
            m4.w = fmaxf(m4.w, __shfl_xor(m4.w, off));
        }
        if (deg > 16) {
            m4.x = fmaxf(m4.x, __shfl_xor(m4.x, 16));
            m4.y = fmaxf(m4.y, __shfl_xor(m4.y, 16));
            m4.z = fmaxf(m4.z, __shfl_xor(m4.z, 16));
            m4.w = fmaxf(m4.w, __shfl_xor(m4.w, 16));
        }
        if (deg > 32) {
            m4.x = fmaxf(m4.x, __shfl_xor(m4.x, 32));
            m4.y = fmaxf(m4.y, __shfl_xor(m4.y, 32));
            m4.z = fmaxf(m4.z, __shfl_xor(m4.z, 32));
            m4.w = fmaxf(m4.w, __shfl_xor(m4.w, 32));
        }
        float4 ex = {0.f, 0.f, 0.f, 0.f};
        if (act) {
            ex.x = __expf(v4.x - m4.x);
            ex.y = __expf(v4.y - m4.y);
            ex.z = __expf(v4.z - m4.z);
            ex.w = __expf(v4.w - m4.w);
        }
        float4 s4 = ex;
        #pragma unroll
        for (int off = 1; off <= 8; off <<= 1) {
            s4.x += __shfl_xor(s4.x, off);
            s4.y += __shfl_xor(s4.y, off);
            s4.z += __shfl_xor(s4.z, off);
            s4.w += __shfl_xor(s4.w, off);
        }
        if (deg > 16) {
            s4.x += __shfl_xor(s4.x, 16);
            s4.y += __shfl_xor(s4.y, 16);
            s4.z += __shfl_xor(s4.z, 16);
            s4.w += __shfl_xor(s4.w, 16);
        }
        if (deg > 32) {
            s4.x += __shfl_xor(s4.x, 32);
            s4.y += __shfl_xor(s4.y, 32);
            s4.z += __shfl_xor(s4.z, 32);
            s4.w += __shfl_xor(s4.w, 32);
        }
        float4 a4;
        a4.x = ex.x / (s4.x + 1e-9f);
        a4.y = ex.y / (s4.y + 1e-9f);
        a4.z = ex.z / (s4.z + 1e-9f);
        a4.w = ex.w / (s4.w + 1e-9f);
        if (HAS_PREV && act) {
            h4 pv = *(const h4*)(aprev + (size_t)idx * 4);
            a4.x = a4.x * (1.f - ALPHA) + ALPHA * (float)pv[0];
            a4.y = a4.y * (1.f - ALPHA) + ALPHA * (float)pv[1];
            a4.z = a4.z * (1.f - ALPHA) + ALPHA * (float)pv[2];
            a4.w = a4.w * (1.f - ALPHA) + ALPHA * (float)pv[3];
        }
        if (WRITE_A && act) {
            h4 aw;
            aw[0] = (_Float16)a4.x; aw[1] = (_Float16)a4.y;
            aw[2] = (_Float16)a4.z; aw[3] = (_Float16)a4.w;
            *(h4*)(awrite + (size_t)idx * 4) = aw;
        }
        as_lds[wave][0][lane] = make_int2(__float_as_int(a4.x), psrc);
        as_lds[wave][1][lane] = make_int2(__float_as_int(a4.y), psrc);
        as_lds[wave][2][lane] = make_int2(__float_as_int(a4.z), psrc);
        as_lds[wave][3][lane] = make_int2(__float_as_int(a4.w), psrc);

        // ---- phase B: 2 edge-slots x 32 feature-chunks, unroll-4 ----
        const int half = lane >> 5;
        const int fl = lane & 31;
        const int h = fl >> 3;
        float acc8[8];
        #pragma unroll
        for (int q = 0; q < 8; q++) acc8[q] = 0.f;
        int i = r0;
        for (; i + 7 < r1; i += 8) {
            int j0 = (i - r0) + half;
            int2 e0 = as_lds[wave][h][j0 + 0];
            int2 e1 = as_lds[wave][h][j0 + 2];
            int2 e2 = as_lds[wave][h][j0 + 4];
            int2 e3 = as_lds[wave][h][j0 + 6];
            float a0 = __int_as_float(e0.x), a1 = __int_as_float(e1.x);
            float a2 = __int_as_float(e2.x), a3 = __int_as_float(e3.x);
            h8 f0 = *(const h8*)(feat + (size_t)e0.y * 256 + fl * 8);
            h8 f1 = *(const h8*)(feat + (size_t)e1.y * 256 + fl * 8);
            h8 f2 = *(const h8*)(feat + (size_t)e2.y * 256 + fl * 8);
            h8 f3 = *(const h8*)(feat + (size_t)e3.y * 256 + fl * 8);
            #pragma unroll
            for (int q = 0; q < 8; q++) acc8[q] = fmaf(a0, (float)f0[q], acc8[q]);
            #pragma unroll
            for (int q = 0; q < 8; q++) acc8[q] = fmaf(a1, (float)f1[q], acc8[q]);
            #pragma unroll
            for (int q = 0; q < 8; q++) acc8[q] = fmaf(a2, (float)f2[q], acc8[q]);
            #pragma unroll
            for (int q = 0; q < 8; q++) acc8[q] = fmaf(a3, (float)f3[q], acc8[q]);
        }
        for (; i + 3 < r1; i += 4) {
            int j0 = (i - r0) + half;
            int2 e0 = as_lds[wave][h][j0 + 0];
            int2 e1 = as_lds[wave][h][j0 + 2];
            float a0 = __int_as_float(e0.x), a1 = __int_as_float(e1.x);
            h8 f0 = *(const h8*)(feat + (size_t)e0.y * 256 + fl * 8);
            h8 f1 = *(const h8*)(feat + (size_t)e1.y * 256 + fl * 8);
            #pragma unroll
            for (int q = 0; q < 8; q++) acc8[q] = fmaf(a0, (float)f0[q], acc8[q]);
            #pragma unroll
            for (int q = 0; q < 8; q++) acc8[q] = fmaf(a1, (float)f1[q], acc8[q]);
        }
        for (; i + 1 < r1; i += 2) {
            int j0 = (i - r0) + half;
            int2 e0 = as_lds[wave][h][j0];
            float a0 = __int_as_float(e0.x);
            h8 f0 = *(const h8*)(feat + (size_t)e0.y * 256 + fl * 8);
            #pragma unroll
            for (int q = 0; q < 8; q++) acc8[q] = fmaf(a0, (float)f0[q], acc8[q]);
        }
        if (i < r1) {
            int j0 = i - r0;
            int2 e0 = as_lds[wave][h][j0];
            float a0 = (half == 0) ? __int_as_float(e0.x) : 0.f;
            h8 f0 = *(const h8*)(feat + (size_t)e0.y * 256 + fl * 8);
            #pragma unroll
            for (int q = 0; q < 8; q++) acc8[q] = fmaf(a0, (float)f0[q], acc8[q]);
        }
        #pragma unroll
        for (int q = 0; q < 8; q++) acc8[q] += __shfl_xor(acc8[q], 32);

        if (half == 0) {
            if (HAS_RES) {
                h8 rv = *(const h8*)(resh + (size_t)n * 256 + fl * 8);
                #pragma unroll
                for (int q = 0; q < 8; q++) acc8[q] += (float)rv[q];
            }
            #pragma unroll
            for (int q = 0; q < 8; q++) acc8[q] = elu_fast(acc8[q]);
            h8 o;
            #pragma unroll
            for (int q = 0; q < 8; q++) o[q] = (_Float16)acc8[q];
            *(h8*)(outh + (size_t)n * 256 + fl * 8) = o;
        }
        return;
    }

    // ---------------- fallback: deg > 64 (two-pass, rare) ----------------
    float4 m4 = {-INFINITY, -INFINITY, -INFINITY, -INFINITY};
    for (int base = r0; base < r1; base += 64) {
        int idx = base + lane;
        if (idx < r1) {
            int p = pk[idx];
            float4 e4 = *(const float4*)(el + (p & 0xFFFF) * 4);
            float4 c4 = *(const float4*)(es + (p >> 16) * 4);
            float v;
            v = e4.x + er4.x + c4.x; v = v > 0.f ? v : SLOPE * v; m4.x = fmaxf(m4.x, v);
            v = e4.y + er4.y + c4.y; v = v > 0.f ? v : SLOPE * v; m4.y = fmaxf(m4.y, v);
            v = e4.z + er4.z + c4.z; v = v > 0.f ? v : SLOPE * v; m4.z = fmaxf(m4.z, v);
            v = e4.w + er4.w + c4.w; v = v > 0.f ? v : SLOPE * v; m4.w = fmaxf(m4.w, v);
        }
    }
    #pragma unroll
    for (int off = 1; off < 64; off <<= 1) {
        m4.x = fmaxf(m4.x, __shfl_xor(m4.x, off));
        m4.y = fmaxf(m4.y, __shfl_xor(m4.y, off));
        m4.z = fmaxf(m4.z, __shfl_xor(m4.z, off));
        m4.w = fmaxf(m4.w, __shfl_xor(m4.w, off));
    }
    float4 s4 = {0.f, 0.f, 0.f, 0.f};
    for (int base = r0; base < r1; base += 64) {
        int idx = base + lane;
        if (idx < r1) {
            int p = pk[idx];
            float4 e4 = *(const float4*)(el + (p & 0xFFFF) * 4);
            float4 c4 = *(const float4*)(es + (p >> 16) * 4);
            float4 exv;
            float v;
            v = e4.x + er4.x + c4.x; v = v > 0.f ? v : SLOPE * v; exv.x = __expf(v - m4.x);
            v = e4.y + er4.y + c4.y; v = v > 0.f ? v : SLOPE * v; exv.y = __expf(v - m4.y);
            v = e4.z + er4.z + c4.z; v = v > 0.f ? v : SLOPE * v; exv.z = __expf(v - m4.z);
            v = e4.w + er4.w + c4.w; v = v > 0.f ? v : SLOPE * v; exv.w = __expf(v - m4.w);
            if (base == r0) {
                as_lds[wave][0][lane] = make_int2(__float_as_int(exv.x), p & 0xFFFF);
                as_lds[wave][1][lane] = make_int2(__float_as_int(exv.y), p & 0xFFFF);
                as_lds[wave][2][lane] = make_int2(__float_as_int(exv.z), p & 0xFFFF);
                as_lds[wave][3][lane] = make_int2(__float_as_int(exv.w), p & 0xFFFF);
            }
            s4.x += exv.x; s4.y += exv.y; s4.z += exv.z; s4.w += exv.w;
        }
    }
    #pragma unroll
    for (int off = 1; off < 64; off <<= 1) {
        s4.x += __shfl_xor(s4.x, off);
        s4.y += __shfl_xor(s4.y, off);
        s4.z += __shfl_xor(s4.z, off);
        s4.w += __shfl_xor(s4.w, off);
    }
    float4 inv4;
    inv4.x = 1.f / (s4.x + 1e-9f); inv4.y = 1.f / (s4.y + 1e-9f);
    inv4.z = 1.f / (s4.z + 1e-9f); inv4.w = 1.f / (s4.w + 1e-9f);
    {
        int idx = r0 + lane;   // deg > 64 -> always valid
        float4 a;
        a.x = __int_as_float(as_lds[wave][0][lane].x) * inv4.x;
        a.y = __int_as_float(as_lds[wave][1][lane].x) * inv4.y;
        a.z = __int_as_float(as_lds[wave][2][lane].x) * inv4.z;
        a.w = __int_as_float(as_lds[wave][3][lane].x) * inv4.w;
        if (HAS_PREV) {
            h4 pv = *(const h4*)(aprev + (size_t)idx * 4);
            a.x = a.x * (1.f - ALPHA) + ALPHA * (float)pv[0];
            a.y = a.y * (1.f - ALPHA) + ALPHA * (float)pv[1];
            a.z = a.z * (1.f - ALPHA) + ALPHA * (float)pv[2];
            a.w = a.w * (1.f - ALPHA) + ALPHA * (float)pv[3];
        }
        if (WRITE_A) {
            h4 aw;
            aw[0] = (_Float16)a.x; aw[1] = (_Float16)a.y;
            aw[2] = (_Float16)a.z; aw[3] = (_Float16)a.w;
            *(h4*)(awrite + (size_t)idx * 4) = aw;
        }
        as_lds[wave][0][lane].x = __float_as_int(a.x);
        as_lds[wave][1][lane].x = __float_as_int(a.y);
        as_lds[wave][2][lane].x = __float_as_int(a.z);
        as_lds[wave][3][lane].x = __float_as_int(a.w);
    }
    if (WRITE_A) {
        for (int base = r0 + 64; base < r1; base += 64) {
            int idx = base + lane;
            if (idx < r1) {
                int p = pk[idx];
                float4 e4 = *(const float4*)(el + (p & 0xFFFF) * 4);
                float4 c4 = *(const float4*)(es + (p >> 16) * 4);
                float4 a;
                float v;
                v = e4.x + er4.x + c4.x; v = v > 0.f ? v : SLOPE * v; a.x = __expf(v - m4.x) * inv4.x;
                v = e4.y + er4.y + c4.y; v = v > 0.f ? v : SLOPE * v; a.y = __expf(v - m4.y) * inv4.y;
                v = e4.z + er4.z + c4.z; v = v > 0.f ? v : SLOPE * v; a.z = __expf(v - m4.z) * inv4.z;
                v = e4.w + er4.w + c4.w; v = v > 0.f ? v : SLOPE * v; a.w = __expf(v - m4.w) * inv4.w;
                if (HAS_PREV) {
                    h4 pv = *(const h4*)(aprev + (size_t)idx * 4);
                    a.x = a.x * (1.f - ALPHA) + ALPHA * (float)pv[0];
                    a.y = a.y * (1.f - ALPHA) + ALPHA * (float)pv[1];
                    a.z = a.z * (1.f - ALPHA) + ALPHA * (float)pv[2];
                    a.w = a.w * (1.f - ALPHA) + ALPHA * (float)pv[3];
                }
                h4 aw;
                aw[0] = (_Float16)a.x; aw[1] = (_Float16)a.y;
                aw[2] = (_Float16)a.z; aw[3] = (_Float16)a.w;
                *(h4*)(awrite + (size_t)idx * 4) = aw;
            }
        }
    }
    const int h = lane >> 4;
    float4 acc = {0.f, 0.f, 0.f, 0.f};
    const int cap = r0 + 64;
    for (int i = r0; i < cap; i++) {
        int2 e0 = as_lds[wave][h][i - r0];
        h4 f = *(const h4*)(feat + (size_t)e0.y * 256 + lane * 4);
        float av = __int_as_float(e0.x);
        acc.x = fmaf(av, (float)f[0], acc.x);
        acc.y = fmaf(av, (float)f[1], acc.y);
        acc.z = fmaf(av, (float)f[2], acc.z);
        acc.w = fmaf(av, (float)f[3], acc.w);
    }
    {
        float mh = sel4(m4, h), invh = sel4(inv4, h), erh = sel4(er4, h);
        for (int i = cap; i < r1; i++) {
            int p = pk[i];
            int s = p & 0xFFFF, t = p >> 16;
            float v = el[s * 4 + h] + erh + es[t * 4 + h];
            v = v > 0.f ? v : SLOPE * v;
            float a = __expf(v - mh) * invh;
            if (HAS_PREV) a = a * (1.f - ALPHA) + ALPHA * (float)aprev[(size_t)i * 4 + h];
            h4 f = *(const h4*)(feat + (size_t)s * 256 + lane * 4);
            acc.x = fmaf(a, (float)f[0], acc.x);
            acc.y = fmaf(a, (float)f[1], acc.y);
            acc.z = fmaf(a, (float)f[2], acc.z);
            acc.w = fmaf(a, (float)f[3], acc.w);
        }
    }
    if (HAS_RES) {
        h4 rv = *(const h4*)(resh + (size_t)n * 256 + lane * 4);
        acc.x += (float)rv[0]; acc.y += (float)rv[1];
        acc.z += (float)rv[2]; acc.w += (float)rv[3];
    }
    acc.x = elu_fast(acc.x);
    acc.y = elu_fast(acc.y);
    acc.z = elu_fast(acc.z);
    acc.w = elu_fast(acc.w);
    h4 o;
    o[0] = (_Float16)acc.x; o[1] = (_Float16)acc.y;
    o[2] = (_Float16)acc.z; o[3] = (_Float16)acc.w;
    *(h4*)(outh + (size_t)n * 256 + lane * 4) = o;
}

// ---------------- fused GAT layer 2 (H=1, C=16): one wave per node ----------------

__global__ __launch_bounds__(256) void gat_fused1(const int* __restrict__ rowstart,
                                                  const int* __restrict__ pk,
                                                  const float* __restrict__ el,
                                                  const float* __restrict__ er,
                                                  const float* __restrict__ es,
                                                  const float* __restrict__ cpack,
                                                  float* __restrict__ out, int nN) {
    const int wave = threadIdx.x >> 6;
    const int lane = threadIdx.x & 63;
    int n = blockIdx.x * 4 + wave;
    if (n >= nN) return;
    const int r0 = rowstart[n], r1 = rowstart[n + 1];
    const int deg = r1 - r0;
    const float ern = er[n];

    if (deg <= 64) {
        const int idx = r0 + lane;
        const bool act = idx < r1;
        int p = act ? pk[idx] : 0;
        int psrc = p & 0xFFFF;
        float v = -INFINITY;
        if (act) {
            float t = el[psrc] + ern + es[p >> 16];
            v = t > 0.f ? t : SLOPE * t;
        }
        float m = v;
        #pragma unroll
        for (int off = 1; off <= 8; off <<= 1) m = fmaxf(m, __shfl_xor(m, off));
        if (deg > 16) m = fmaxf(m, __shfl_xor(m, 16));
        if (deg > 32) m = fmaxf(m, __shfl_xor(m, 32));
        float ex = act ? __expf(v - m) : 0.f;
        float s = ex;
        #pragma unroll
        for (int off = 1; off <= 8; off <<= 1) s += __shfl_xor(s, off);
        if (deg > 16) s += __shfl_xor(s, 16);
        if (deg > 32) s += __shfl_xor(s, 32);
        float a = ex / (s + 1e-9f);

        const int eslot = lane >> 4, fl = lane & 15;
        float acc = 0.f;
        int i = r0;
        for (; i + 7 < r1; i += 8) {
            int j0 = (i - r0) + eslot;
            int j1 = j0 + 4;
            int s0 = __shfl(psrc, j0);
            int s1 = __shfl(psrc, j1);
            float a0 = __shfl(a, j0);
            float a1 = __shfl(a, j1);
            float f0 = cpack[(size_t)s0 * 32 + fl];
            float f1 = cpack[(size_t)s1 * 32 + fl];
            acc = fmaf(a0, f0, acc);
            acc = fmaf(a1, f1, acc);
        }
        for (; i + 3 < r1; i += 4) {
            int j = (i - r0) + eslot;
            int sj = __shfl(psrc, j);
            float aj = __shfl(a, j);
            acc = fmaf(aj, cpack[(size_t)sj * 32 + fl], acc);
        }
        int rem = r1 - i;
        if (rem > 0) {   // wave-uniform branch: full exec for the shfls below
            int j = (i - r0) + (eslot < rem ? eslot : rem - 1);
            int sj = __shfl(psrc, j);
            float aj = __shfl(a, j);
            if (eslot >= rem) aj = 0.f;
            acc = fmaf(aj, cpack[(size_t)sj * 32 + fl], acc);
        }
        acc += __shfl_xor(acc, 16);
        acc += __shfl_xor(acc, 32);
        if (lane < 16) out[(size_t)n * 16 + lane] = acc + cpack[(size_t)n * 32 + 16 + lane];
        return;
    }

    // fallback deg > 64 (rare)
    float m = -INFINITY;
    for (int base = r0; base < r1; base += 64) {
        int idx = base + lane;
        if (idx < r1) {
            int p = pk[idx];
            float v = el[p & 0xFFFF] + ern + es[p >> 16];
            v = v > 0.f ? v : SLOPE * v;
            m = fmaxf(m, v);
        }
    }
    #pragma unroll
    for (int off = 1; off < 64; off <<= 1) m = fmaxf(m, __shfl_xor(m, off));
    float s = 0.f;
    for (int base = r0; base < r1; base += 64) {
        int idx = base + lane;
        if (idx < r1) {
            int p = pk[idx];
            float v = el[p & 0xFFFF] + ern + es[p >> 16];
            v = v > 0.f ? v : SLOPE * v;
            s += __expf(v - m);
        }
    }
    #pragma unroll
    for (int off = 1; off < 64; off <<= 1) s += __shfl_xor(s, off);
    float inv = 1.f / (s + 1e-9f);
    const int eslot = lane >> 4, fl = lane & 15;
    float acc = 0.f;
    for (int i = r0; i < r1; i += 4) {
        int rem = r1 - i;
        if (eslot < rem) {
            int j = i + eslot;
            int p = pk[j];
            float v = el[p & 0xFFFF] + ern + es[p >> 16];
            v = v > 0.f ? v : SLOPE * v;
            float a = __expf(v - m) * inv;
            acc = fmaf(a, cpack[(size_t)(p & 0xFFFF) * 32 + fl], acc);
        }
    }
    acc += __shfl_xor(acc, 16);
    acc += __shfl_xor(acc, 32);
    if (lane < 16) out[(size_t)n * 16 + lane] = acc + cpack[(size_t)n * 32 + 16 + lane];
}

// ---------------- host ----------------

extern "C" void kernel_launch(void* const* d_in, const int* in_sizes, int n_in,
                              void* d_out, int out_size, void* d_ws, size_t ws_size,
                              hipStream_t stream) {
    const float* x0 = (const float*)d_in[0];
    const float* x1 = (const float*)d_in[1];
    const float* x2 = (const float*)d_in[2];
    const int* src  = (const int*)d_in[3];
    const int* dst  = (const int*)d_in[4];
    const int* et   = (const int*)d_in[5];
    const float* W0 = (const float*)d_in[6];  const float* b0 = (const float*)d_in[7];
    const float* W1 = (const float*)d_in[8];  const float* b1 = (const float*)d_in[9];
    const float* W2 = (const float*)d_in[10]; const float* b2 = (const float*)d_in[11];
    const float* Wg0 = (const float*)d_in[12]; const float* etab0 = (const float*)d_in[13];
    const float* We0 = (const float*)d_in[14]; const float* al0 = (const float*)d_in[15];
    const float* ar0 = (const float*)d_in[16]; const float* ae0 = (const float*)d_in[17];
    const float* Wg1 = (const float*)d_in[18]; const float* etab1 = (const float*)d_in[19];
    const float* We1 = (const float*)d_in[20]; const float* al1 = (const float*)d_in[21];
    const float* ar1 = (const float*)d_in[22]; const float* ae1 = (const float*)d_in[23];
    const float* Wg2 = (const float*)d_in[24]; const float* etab2 = (const float*)d_in[25];
    const float* We2 = (const float*)d_in[26]; const float* al2 = (const float*)d_in[27];
    const float* ar2 = (const float*)d_in[28]; const float* ae2 = (const float*)d_in[29];
    const float* resW2 = (const float*)d_in[30];
    float* outp = (float*)d_out;

    char* p = (char*)d_ws;
    auto alloc = [&](size_t bytes) -> void* {
        void* r = (void*)p;
        p += (bytes + 255) & ~(size_t)255;
        return r;
    };
    _Float16* x0h   = (_Float16*)alloc((size_t)N0 * 128 * 2);
    _Float16* x1h   = (_Float16*)alloc((size_t)N1 * 64 * 2);
    _Float16* x2h   = (_Float16*)alloc((size_t)N2 * 32 * 2);
    _Float16* W0h   = (_Float16*)alloc(64 * 128 * 2);
    _Float16* W1h   = (_Float16*)alloc(64 * 64 * 2);
    _Float16* W2h   = (_Float16*)alloc(64 * 32 * 2);
    _Float16* Wg0h  = (_Float16*)alloc(256 * 64 * 2);
    _Float16* Wg1h  = (_Float16*)alloc(256 * 256 * 2);
    _Float16* wpkh  = (_Float16*)alloc(32 * 256 * 2);
    _Float16* h0h   = (_Float16*)alloc((size_t)NN * 64 * 2);
    _Float16* feath = (_Float16*)alloc((size_t)NN * 256 * 2);
    _Float16* bufAh = (_Float16*)alloc((size_t)NN * 256 * 2);
    _Float16* bufBh = (_Float16*)alloc((size_t)NN * 256 * 2);
    _Float16* a0h   = (_Float16*)alloc((size_t)EE * 4 * 2);
    float* el    = (float*)alloc((size_t)NN * 4 * 4);
    float* er    = (float*)alloc((size_t)NN * 4 * 4);
    float* es    = (float*)alloc(96 * 4);
    float* cpack = (float*)alloc((size_t)NN * 32 * 4);
    int* rowstart = (int*)alloc((size_t)(NN + 1) * 4);
    int* deg      = (int*)alloc((size_t)NN * 4);
    int* cursor   = (int*)alloc((size_t)NN * 4);
    int* bsum     = (int*)alloc(256 * 4);
    int* pk       = (int*)alloc((size_t)EE * 4);

    const int EB = (EE + 255) / 256;        // 3125
    const int NB = (NN + 255) / 256;        // 196
    const int MB128 = (NN + 127) / 128;     // 391
    const int WB = (NN + 3) / 4;            // 12500
    const int nb0 = (N0 + 127) / 128;       // 157
    const int nb1 = (N1 + 127) / 128;       // 118
    const int nb2 = (N2 + 127) / 128;       // 118

    // CSR build
    hipMemsetAsync(deg, 0, (size_t)NN * 4, stream);
    hist_kernel<<<EB, 256, 0, stream>>>(dst, deg, EE);
    block_sum_kernel<<<NB, 256, 0, stream>>>(deg, bsum, NN);
    scan_bsum_kernel<<<1, 256, 0, stream>>>(bsum, NB);
    scan_out_kernel<<<NB, 256, 0, stream>>>(deg, bsum, rowstart, cursor, NN);
    scatter_kernel<<<EB, 256, 0, stream>>>(src, dst, et, cursor, pk, EE);

    // es tables + weight/feature converts
    es_table_all<<<72, 64, 0, stream>>>(etab0, We0, ae0, etab1, We1, ae1, etab2, We2, ae2, es);
    {
        int n0c = N0 * 128, n1c = N1 * 64, n2c = N2 * 32;
        int total = n0c + n1c + n2c + 8192 + 4096 + 2048 + 16384 + 65536 + 4096 + 4096;
        f2h10<<<(total + 255) / 256, 256, 0, stream>>>(
            x0, x0h, n0c, x1, x1h, n1c, x2, x2h, n2c,
            W0, W0h, 8192, W1, W1h, 4096, W2, W2h, 2048,
            Wg0, Wg0h, 16384, Wg1, Wg1h, 65536,
            Wg2, wpkh, 4096, resW2, wpkh + 4096, 4096);
    }

    // input projections (one dispatch) -> h0h [N,64] fp16
    proj3<<<nb0 + nb1 + nb2, 256, 0, stream>>>(x0h, W0h, b0, x1h, W1h, b1, x2h, W2h, b2,
                                               h0h, nb0, nb1);

    // ---- GAT layer 0 ----
    gemm_mfma<8, 1><<<dim3(MB128, 2), 256, 0, stream>>>(h0h, Wg0h, nullptr, nullptr, feath,
                                                        el, er, al0, ar0, NN, 256, 64);
    gat_fused4<true, false, false><<<WB, 256, 0, stream>>>(
        rowstart, pk, el, er, es + 0, feath, nullptr, a0h, nullptr, bufAh, NN);

    // ---- GAT layer 1 ----
    gemm_mfma<8, 1><<<dim3(MB128, 2), 256, 0, stream>>>(bufAh, Wg1h, nullptr, nullptr, feath,
                                                        el, er, al1, ar1, NN, 256, 256);
    gat_fused4<false, true, true><<<WB, 256, 0, stream>>>(
        rowstart, pk, el, er, es + 32, feath, a0h, nullptr, bufAh, bufBh, NN);

    // ---- GAT layer 2 (H=1, C=16, linear residual, no act) ----
    gemm_mfma<2, 2><<<dim3(MB128, 1), 256, 0, stream>>>(bufBh, wpkh, nullptr, cpack, nullptr,
                                                        el, er, al2, ar2, NN, 32, 256);
    gat_fused1<<<WB, 256, 0, stream>>>(rowstart, pk, el, er, es + 64, cpack, outp, NN);
}

// Round 10
// 474.155 us; speedup vs baseline: 1.1125x; 1.0126x over previous
//
#include <hip/hip_runtime.h>
#include <math.h>

#define N0 20000
#define N1 15000
#define N2 15000
#define NN 50000          // total nodes
#define EE 800000         // edges
#define SLOPE 0.2f
#define ALPHA 0.05f

typedef _Float16 h8 __attribute__((ext_vector_type(8)));
typedef _Float16 h4 __attribute__((ext_vector_type(4)));
typedef float f4v __attribute__((ext_vector_type(4)));

__device__ __forceinline__ float sel4(float4 v, int h) {
    float lo = (h & 1) ? v.y : v.x;
    float hi = (h & 1) ? v.w : v.z;
    return (h & 2) ? hi : lo;
}

__device__ __forceinline__ float elu_fast(float x) {
    return x > 0.f ? x : __expf(x) - 1.f;
}

// ---------------- CSR build ----------------

__global__ void hist_kernel(const int* __restrict__ dst, int* __restrict__ deg, int E_) {
    int e = blockIdx.x * blockDim.x + threadIdx.x;
    if (e < E_) atomicAdd(&deg[dst[e]], 1);
}

__global__ __launch_bounds__(256) void block_sum_kernel(const int* __restrict__ deg,
                                                        int* __restrict__ bsum, int n) {
    int i = blockIdx.x * 256 + threadIdx.x;
    int v = (i < n) ? deg[i] : 0;
    #pragma unroll
    for (int off = 32; off > 0; off >>= 1) v += __shfl_down(v, off);
    __shared__ int sh[4];
    if ((threadIdx.x & 63) == 0) sh[threadIdx.x >> 6] = v;
    __syncthreads();
    if (threadIdx.x == 0) bsum[blockIdx.x] = sh[0] + sh[1] + sh[2] + sh[3];
}

// merged: every block redundantly scans bsum (196 entries) for its offset, then
// scans its own 256-chunk of deg. Removes the single-block scan_bsum dispatch.
__global__ __launch_bounds__(256) void scan_out2(const int* __restrict__ deg,
                                                 const int* __restrict__ bsum,
                                                 int* __restrict__ rowstart,
                                                 int* __restrict__ cursor, int n, int nb) {
    __shared__ int sb[256];
    __shared__ int boff_s;
    int tid = threadIdx.x;
    int v = (tid < nb) ? bsum[tid] : 0;
    sb[tid] = v;
    __syncthreads();
    #pragma unroll
    for (int off = 1; off < 256; off <<= 1) {
        int t = (tid >= off) ? sb[tid - off] : 0;
        __syncthreads();
        sb[tid] += t;
        __syncthreads();
    }
    if (tid == blockIdx.x) boff_s = sb[tid] - v;   // exclusive prefix of this block
    __syncthreads();
    int boff = boff_s;
    int i = blockIdx.x * 256 + tid;
    int d = (i < n) ? deg[i] : 0;
    __syncthreads();
    sb[tid] = d;
    __syncthreads();
    #pragma unroll
    for (int off = 1; off < 256; off <<= 1) {
        int t = (tid >= off) ? sb[tid - off] : 0;
        __syncthreads();
        sb[tid] += t;
        __syncthreads();
    }
    int excl = sb[tid] - d + boff;
    if (i < n) { rowstart[i] = excl; cursor[i] = excl; }
    if (i == n - 1) rowstart[n] = excl + d;
}

__global__ void scatter_kernel(const int* __restrict__ src, const int* __restrict__ dst,
                               const int* __restrict__ et, int* __restrict__ cursor,
                               int* __restrict__ pk, int E_) {
    int e = blockIdx.x * blockDim.x + threadIdx.x;
    if (e >= E_) return;
    int d = dst[e];
    int p = atomicAdd(&cursor[d], 1);
    pk[p] = (et[e] << 16) | src[e];
}

// ---------------- prep: es tables (blocks 0..17, one wave per pair) + fp32->fp16 converts ----------------

__device__ __forceinline__ void es_pair(int p,
                                        const float* __restrict__ etab0, const float* __restrict__ We0, const float* __restrict__ ae0,
                                        const float* __restrict__ etab1, const float* __restrict__ We1, const float* __restrict__ ae1,
                                        const float* __restrict__ etab2, const float* __restrict__ We2, const float* __restrict__ ae2,
                                        float* __restrict__ es) {
    const float *etab, *We, *ae;
    float* out;
    int H;
    if (p < 32)      { etab = etab0; We = We0; ae = ae0; out = es;      H = 4; }
    else if (p < 64) { p -= 32; etab = etab1; We = We1; ae = ae1; out = es + 32; H = 4; }
    else             { p -= 64; etab = etab2; We = We2; ae = ae2; out = es + 64; H = 1; }
    int t = p / H, h = p % H;
    int j = threadIdx.x & 63;
    const float* w = We + (size_t)(h * 64 + j) * 64;
    const float* e = etab + t * 64;
    float s = 0.f;
    #pragma unroll
    for (int k = 0; k < 64; k += 4) {
        float4 wv = *(const float4*)(w + k);
        float4 ev = *(const float4*)(e + k);
        s += wv.x * ev.x + wv.y * ev.y + wv.z * ev.z + wv.w * ev.w;
    }
    s *= ae[h * 64 + j];
    #pragma unroll
    for (int off = 32; off > 0; off >>= 1) s += __shfl_down(s, off);
    if (j == 0) out[t * H + h] = s;
}

__global__ __launch_bounds__(256) void prep_kernel(
        const float* etab0, const float* We0, const float* ae0,
        const float* etab1, const float* We1, const float* ae1,
        const float* etab2, const float* We2, const float* ae2,
        float* es,
        const float* s0, _Float16* d0, int n0,
        const float* s1, _Float16* d1, int n1,
        const float* s2, _Float16* d2, int n2,
        const float* s3, _Float16* d3, int n3,
        const float* s4, _Float16* d4, int n4,
        const float* s5, _Float16* d5, int n5,
        const float* s6, _Float16* d6, int n6,
        const float* s7, _Float16* d7, int n7,
        const float* s8, _Float16* d8, int n8,
        const float* s9, _Float16* d9, int n9) {
    int b = blockIdx.x;
    if (b < 18) {
        int p = b * 4 + (threadIdx.x >> 6);
        if (p < 72) es_pair(p, etab0, We0, ae0, etab1, We1, ae1, etab2, We2, ae2, es);
        return;
    }
    int t = (b - 18) * 256 + threadIdx.x;
    if (t < n0) { d0[t] = (_Float16)s0[t]; return; } t -= n0;
    if (t < n1) { d1[t] = (_Float16)s1[t]; return; } t -= n1;
    if (t < n2) { d2[t] = (_Float16)s2[t]; return; } t -= n2;
    if (t < n3) { d3[t] = (_Float16)s3[t]; return; } t -= n3;
    if (t < n4) { d4[t] = (_Float16)s4[t]; return; } t -= n4;
    if (t < n5) { d5[t] = (_Float16)s5[t]; return; } t -= n5;
    if (t < n6) { d6[t] = (_Float16)s6[t]; return; } t -= n6;
    if (t < n7) { d7[t] = (_Float16)s7[t]; return; } t -= n7;
    if (t < n8) { d8[t] = (_Float16)s8[t]; return; } t -= n8;
    if (t < n9) { d9[t] = (_Float16)s9[t]; }
}

// ---------------- MFMA fp16 GEMM body (verified fragment mapping) ----------------
// ELR: 0 = none; 1 = fused el/er for H=4/D=64 layers (y-block covers 2 heads);
// 2 = fused el/er for layer 2 (H=1, D=16 = j==0 tile). Computed from fp32 acc.

template<int NT, int ELR>
__device__ __forceinline__ void gemm_body(int bx, int by,
                                          const _Float16* __restrict__ A,
                                          const _Float16* __restrict__ B,
                                          const float* __restrict__ bias,
                                          float* __restrict__ Cf,
                                          _Float16* __restrict__ Ch,
                                          float* __restrict__ el,
                                          float* __restrict__ er,
                                          const float* __restrict__ al,
                                          const float* __restrict__ ar,
                                          int M, int N, int K) {
    const int wave = threadIdx.x >> 6;
    const int lane = threadIdx.x & 63;
    const int m_base = (bx * 4 + wave) * 32;
    const int n_base = by * (NT * 16);
    const int row = lane & 15;
    const int kq = (lane >> 4) * 8;

    f4v acc[2][NT];
    #pragma unroll
    for (int i = 0; i < 2; i++)
        #pragma unroll
        for (int j = 0; j < NT; j++) {
            f4v z = {0.f, 0.f, 0.f, 0.f};
            acc[i][j] = z;
        }

    int ra = m_base + row;       if (ra >= M) ra = M - 1;
    int rb2 = m_base + 16 + row; if (rb2 >= M) rb2 = M - 1;
    const _Float16* a0p = A + (size_t)ra * K + kq;
    const _Float16* a1p = A + (size_t)rb2 * K + kq;
    const _Float16* bp  = B + (size_t)(n_base + row) * K + kq;

    for (int k = 0; k < K; k += 32) {
        h8 a0 = *(const h8*)(a0p + k);
        h8 a1 = *(const h8*)(a1p + k);
        #pragma unroll
        for (int j = 0; j < NT; j++) {
            h8 b = *(const h8*)(bp + (size_t)j * 16 * K + k);
            acc[0][j] = __builtin_amdgcn_mfma_f32_16x16x32_f16(a0, b, acc[0][j], 0, 0, 0);
            acc[1][j] = __builtin_amdgcn_mfma_f32_16x16x32_f16(a1, b, acc[1][j], 0, 0, 0);
        }
    }

    const int col = lane & 15;
    const int rb = (lane >> 4) * 4;

    if (ELR == 1) {
        float alw[NT], arw[NT];
        #pragma unroll
        for (int j = 0; j < NT; j++) {
            int cg = n_base + j * 16 + col;
            int hg = cg >> 6, d = cg & 63;
            alw[j] = al[hg * 64 + d];
            arw[j] = ar[hg * 64 + d];
        }
        const int hb = n_base >> 6;
        #pragma unroll
        for (int ms = 0; ms < 2; ms++) {
            #pragma unroll
            for (int r = 0; r < 4; r++) {
                float e0 = 0.f, e1 = 0.f, f0 = 0.f, f1 = 0.f;
                #pragma unroll
                for (int j = 0; j < NT; j++) {
                    float av = acc[ms][j][r];
                    if (j < NT / 2) { e0 = fmaf(av, alw[j], e0); f0 = fmaf(av, arw[j], f0); }
                    else            { e1 = fmaf(av, alw[j], e1); f1 = fmaf(av, arw[j], f1); }
                }
                #pragma unroll
                for (int off = 1; off <= 8; off <<= 1) {
                    e0 += __shfl_xor(e0, off);
                    e1 += __shfl_xor(e1, off);
                    f0 += __shfl_xor(f0, off);
                    f1 += __shfl_xor(f1, off);
                }
                int m = m_base + ms * 16 + rb + r;
                if (col == 0 && m < M) {
                    el[m * 4 + hb]     = e0;
                    el[m * 4 + hb + 1] = e1;
                    er[m * 4 + hb]     = f0;
                    er[m * 4 + hb + 1] = f1;
                }
            }
        }
    }
    if (ELR == 2) {
        float alw = al[col], arw = ar[col];
        #pragma unroll
        for (int ms = 0; ms < 2; ms++) {
            #pragma unroll
            for (int r = 0; r < 4; r++) {
                float e = acc[ms][0][r] * alw;
                float f = acc[ms][0][r] * arw;
                #pragma unroll
                for (int off = 1; off <= 8; off <<= 1) {
                    e += __shfl_xor(e, off);
                    f += __shfl_xor(f, off);
                }
                int m = m_base + ms * 16 + rb + r;
                if (col == 0 && m < M) { el[m] = e; er[m] = f; }
            }
        }
    }

    #pragma unroll
    for (int ms = 0; ms < 2; ms++) {
        #pragma unroll
        for (int j = 0; j < NT; j++) {
            #pragma unroll
            for (int r = 0; r < 4; r++) {
                int m = m_base + ms * 16 + rb + r;
                if (m < M) {
                    int n = n_base + j * 16 + col;
                    float v = acc[ms][j][r];
                    if (bias) v += bias[n];
                    if (Cf) Cf[(size_t)m * N + n] = v;
                    if (Ch) Ch[(size_t)m * N + n] = (_Float16)v;
                }
            }
        }
    }
}

template<int NT, int ELR>
__global__ __launch_bounds__(256) void gemm_mfma(const _Float16* __restrict__ A,
                                                 const _Float16* __restrict__ B,
                                                 const float* __restrict__ bias,
                                                 float* __restrict__ Cf,
                                                 _Float16* __restrict__ Ch,
                                                 float* __restrict__ el,
                                                 float* __restrict__ er,
                                                 const float* __restrict__ al,
                                                 const float* __restrict__ ar,
                                                 int M, int N, int K) {
    gemm_body<NT, ELR>(blockIdx.x, blockIdx.y, A, B, bias, Cf, Ch, el, er, al, ar, M, N, K);
}

// 3 input projections in one dispatch (block-uniform routing)
__global__ __launch_bounds__(256) void proj3(const _Float16* __restrict__ x0h, const _Float16* __restrict__ W0h, const float* __restrict__ b0,
                                             const _Float16* __restrict__ x1h, const _Float16* __restrict__ W1h, const float* __restrict__ b1,
                                             const _Float16* __restrict__ x2h, const _Float16* __restrict__ W2h, const float* __restrict__ b2,
                                             _Float16* __restrict__ h0h, int nb0, int nb1) {
    int b = blockIdx.x;
    if (b < nb0) {
        gemm_body<4, 0>(b, 0, x0h, W0h, b0, nullptr, h0h,
                        nullptr, nullptr, nullptr, nullptr, N0, 64, 128);
    } else if (b < nb0 + nb1) {
        gemm_body<4, 0>(b - nb0, 0, x1h, W1h, b1, nullptr, h0h + (size_t)N0 * 64,
                        nullptr, nullptr, nullptr, nullptr, N1, 64, 64);
    } else {
        gemm_body<4, 0>(b - nb0 - nb1, 0, x2h, W2h, b2, nullptr, h0h + (size_t)(N0 + N1) * 64,
                        nullptr, nullptr, nullptr, nullptr, N2, 64, 32);
    }
}

// ---------------- fused GAT edge stage, H=4 ----------------
// one wave per dst node; LDS [wave][h][66] (pad 2) conflict-free.
// All __shfl under wave-uniform control flow (round-5 lesson).

template<bool WRITE_A, bool HAS_PREV, bool HAS_RES>
__global__ __launch_bounds__(256) void gat_fused4(const int* __restrict__ rowstart,
                                                  const int* __restrict__ pk,
                                                  const float* __restrict__ el,
                                                  const float* __restrict__ er,
                                                  const float* __restrict__ es,
                                                  const _Float16* __restrict__ feat,
                                                  const _Float16* __restrict__ aprev,
                                                  _Float16* __restrict__ awrite,
                                                  const _Float16* __restrict__ resh,
                                                  _Float16* __restrict__ outh, int nN) {
    __shared__ int2 as_lds[4][4][66];   // [wave][h][edge] = {f32 bits of a, src}
    const int wave = threadIdx.x >> 6;
    const int lane = threadIdx.x & 63;
    int n = blockIdx.x * 4 + wave;
    if (n >= nN) return;
    const int r0 = rowstart[n], r1 = rowstart[n + 1];
    const int deg = r1 - r0;
    float4 er4 = *(const float4*)(er + n * 4);

    if (deg <= 64) {
        // ---- phase A: one edge per lane, in-register softmax ----
        const int idx = r0 + lane;
        const bool act = idx < r1;
        int p = act ? pk[idx] : 0;
        int psrc = p & 0xFFFF;
        float4 v4 = {-INFINITY, -INFINITY, -INFINITY, -INFINITY};
        if (act) {
            float4 e4 = *(const float4*)(el + psrc * 4);
            float4 c4 = *(const float4*)(es + (p >> 16) * 4);
            float v;
            v = e4.x + er4.x + c4.x; v4.x = v > 0.f ? v : SLOPE * v;
            v = e4.y + er4.y + c4.y; v4.y = v > 0.f ? v : SLOPE * v;
            v = e4.z + er4.z + c4.z; v4.z = v > 0.f ? v : SLOPE * v;
            v = e4.w + er4.w + c4.w; v4.w = v > 0.f ? v : SLOPE * v;
        }
        float4 m4 = v4;
        #pragma unroll
        for (int off = 1; off <= 8; off <<= 1) {
            m4.x = fmaxf(m4.x, __shfl_xor(m4.x, off));
            m4.y = fmaxf(m4.y, __shfl_xor(m4.y, off));
            m4.z = fmaxf(m4.z, __shfl_xor(m4.z, off));
            m4.w = fmaxf(m4.w, __shfl_xor(m4.w, off));
        }
        if (deg > 16) {
            m4.x = fmaxf(m4.x, __shfl_xor(m4.x, 16));
            m4.y = fmaxf(m4.y, __shfl_xor(m4.y, 16));
            m4.z = fmaxf(m4.z, __shfl_xor(m4.z, 16));
            m4.w = fmaxf(m4.w, __shfl_xor(m4.w, 16));
        }
        if (deg > 32) {
            m4.x = fmaxf(m4.x, __shfl_xor(m4.x, 32));
            m4.y = fmaxf(m4.y, __shfl_xor(m4.y, 32));
            m4.z = fmaxf(m4.z, __shfl_xor(m4.z, 32));
            m4.w = fmaxf(m4.w, __shfl_xor(m4.w, 32));
        }
        float4 ex = {0.f, 0.f, 0.f, 0.f};
        if (act) {
            ex.x = __expf(v4.x - m4.x);
            ex.y = __expf(v4.y - m4.y);
            ex.z = __expf(v4.z - m4.z);
            ex.w = __expf(v4.w - m4.w);
        }
        float4 s4 = ex;
        #pragma unroll
        for (int off = 1; off <= 8; off <<= 1) {
            s4.x += __shfl_xor(s4.x, off);
            s4.y += __shfl_xor(s4.y, off);
            s4.z += __shfl_xor(s4.z, off);
            s4.w += __shfl_xor(s4.w, off);
        }
        if (deg > 16) {
            s4.x += __shfl_xor(s4.x, 16);
            s4.y += __shfl_xor(s4.y, 16);
            s4.z += __shfl_xor(s4.z, 16);
            s4.w += __shfl_xor(s4.w, 16);
        }
        if (deg > 32) {
            s4.x += __shfl_xor(s4.x, 32);
            s4.y += __shfl_xor(s4.y, 32);
            s4.z += __shfl_xor(s4.z, 32);
            s4.w += __shfl_xor(s4.w, 32);
        }
        float4 a4;
        a4.x = ex.x / (s4.x + 1e-9f);
        a4.y = ex.y / (s4.y + 1e-9f);
        a4.z = ex.z / (s4.z + 1e-9f);
        a4.w = ex.w / (s4.w + 1e-9f);
        if (HAS_PREV && act) {
            h4 pv = *(const h4*)(aprev + (size_t)idx * 4);
            a4.x = a4.x * (1.f - ALPHA) + ALPHA * (float)pv[0];
            a4.y = a4.y * (1.f - ALPHA) + ALPHA * (float)pv[1];
            a4.z = a4.z * (1.f - ALPHA) + ALPHA * (float)pv[2];
            a4.w = a4.w * (1.f - ALPHA) + ALPHA * (float)pv[3];
        }
        if (WRITE_A && act) {
            h4 aw;
            aw[0] = (_Float16)a4.x; aw[1] = (_Float16)a4.y;
            aw[2] = (_Float16)a4.z; aw[3] = (_Float16)a4.w;
            *(h4*)(awrite + (size_t)idx * 4) = aw;
        }
        as_lds[wave][0][lane] = make_int2(__float_as_int(a4.x), psrc);
        as_lds[wave][1][lane] = make_int2(__float_as_int(a4.y), psrc);
        as_lds[wave][2][lane] = make_int2(__float_as_int(a4.z), psrc);
        as_lds[wave][3][lane] = make_int2(__float_as_int(a4.w), psrc);

        // ---- phase B: 2 edge-slots x 32 feature-chunks, unroll-4 ----
        const int half = lane >> 5;
        const int fl = lane & 31;
        const int h = fl >> 3;
        float acc8[8];
        #pragma unroll
        for (int q = 0; q < 8; q++) acc8[q] = 0.f;
        int i = r0;
        for (; i + 7 < r1; i += 8) {
            int j0 = (i - r0) + half;
            int2 e0 = as_lds[wave][h][j0 + 0];
            int2 e1 = as_lds[wave][h][j0 + 2];
            int2 e2 = as_lds[wave][h][j0 + 4];
            int2 e3 = as_lds[wave][h][j0 + 6];
            float a0 = __int_as_float(e0.x), a1 = __int_as_float(e1.x);
            float a2 = __int_as_float(e2.x), a3 = __int_as_float(e3.x);
            h8 f0 = *(const h8*)(feat + (size_t)e0.y * 256 + fl * 8);
            h8 f1 = *(const h8*)(feat + (size_t)e1.y * 256 + fl * 8);
            h8 f2 = *(const h8*)(feat + (size_t)e2.y * 256 + fl * 8);
            h8 f3 = *(const h8*)(feat + (size_t)e3.y * 256 + fl * 8);
            #pragma unroll
            for (int q = 0; q < 8; q++) acc8[q] = fmaf(a0, (float)f0[q], acc8[q]);
            #pragma unroll
            for (int q = 0; q < 8; q++) acc8[q] = fmaf(a1, (float)f1[q], acc8[q]);
            #pragma unroll
            for (int q = 0; q < 8; q++) acc8[q] = fmaf(a2, (float)f2[q], acc8[q]);
            #pragma unroll
            for (int q = 0; q < 8; q++) acc8[q] = fmaf(a3, (float)f3[q], acc8[q]);
        }
        for (; i + 3 < r1; i += 4) {
            int j0 = (i - r0) + half;
            int2 e0 = as_lds[wave][h][j0 + 0];
            int2 e1 = as_lds[wave][h][j0 + 2];
            float a0 = __int_as_float(e0.x), a1 = __int_as_float(e1.x);
            h8 f0 = *(const h8*)(feat + (size_t)e0.y * 256 + fl * 8);
            h8 f1 = *(const h8*)(feat + (size_t)e1.y * 256 + fl * 8);
            #pragma unroll
            for (int q = 0; q < 8; q++) acc8[q] = fmaf(a0, (float)f0[q], acc8[q]);
            #pragma unroll
            for (int q = 0; q < 8; q++) acc8[q] = fmaf(a1, (float)f1[q], acc8[q]);
        }
        for (; i + 1 < r1; i += 2) {
            int j0 = (i - r0) + half;
            int2 e0 = as_lds[wave][h][j0];
            float a0 = __int_as_float(e0.x);
            h8 f0 = *(const h8*)(feat + (size_t)e0.y * 256 + fl * 8);
            #pragma unroll
            for (int q = 0; q < 8; q++) acc8[q] = fmaf(a0, (float)f0[q], acc8[q]);
        }
        if (i < r1) {
            int j0 = i - r0;
            int2 e0 = as_lds[wave][h][j0];
            float a0 = (half == 0) ? __int_as_float(e0.x) : 0.f;
            h8 f0 = *(const h8*)(feat + (size_t)e0.y * 256 + fl * 8);
            #pragma unroll
            for (int q = 0; q < 8; q++) acc8[q] = fmaf(a0, (float)f0[q], acc8[q]);
        }
        #pragma unroll
        for (int q = 0; q < 8; q++) acc8[q] += __shfl_xor(acc8[q], 32);

        if (half == 0) {
            if (HAS_RES) {
                h8 rv = *(const h8*)(resh + (size_t)n * 256 + fl * 8);
                #pragma unroll
                for (int q = 0; q < 8; q++) acc8[q] += (float)rv[q];
            }
            #pragma unroll
            for (int q = 0; q < 8; q++) acc8[q] = elu_fast(acc8[q]);
            h8 o;
            #pragma unroll
            for (int q = 0; q < 8; q++) o[q] = (_Float16)acc8[q];
            *(h8*)(outh + (size_t)n * 256 + fl * 8) = o;
        }
        return;
    }

    // ---------------- fallback: deg > 64 (two-pass, rare) ----------------
    float4 m4 = {-INFINITY, -INFINITY, -INFINITY, -INFINITY};
    for (int base = r0; base < r1; base += 64) {
        int idx = base + lane;
        if (idx < r1) {
            int p = pk[idx];
            float4 e4 = *(const float4*)(el + (p & 0xFFFF) * 4);
            float4 c4 = *(const float4*)(es + (p >> 16) * 4);
            float v;
            v = e4.x + er4.x + c4.x; v = v > 0.f ? v : SLOPE * v; m4.x = fmaxf(m4.x, v);
            v = e4.y + er4.y + c4.y; v = v > 0.f ? v : SLOPE * v; m4.y = fmaxf(m4.y, v);
            v = e4.z + er4.z + c4.z; v = v > 0.f ? v : SLOPE * v; m4.z = fmaxf(m4.z, v);
            v = e4.w + er4.w + c4.w; v = v > 0.f ? v : SLOPE * v; m4.w = fmaxf(m4.w, v);
        }
    }
    #pragma unroll
    for (int off = 1; off < 64; off <<= 1) {
        m4.x = fmaxf(m4.x, __shfl_xor(m4.x, off));
        m4.y = fmaxf(m4.y, __shfl_xor(m4.y, off));
        m4.z = fmaxf(m4.z, __shfl_xor(m4.z, off));
        m4.w = fmaxf(m4.w, __shfl_xor(m4.w, off));
    }
    float4 s4 = {0.f, 0.f, 0.f, 0.f};
    for (int base = r0; base < r1; base += 64) {
        int idx = base + lane;
        if (idx < r1) {
            int p = pk[idx];
            float4 e4 = *(const float4*)(el + (p & 0xFFFF) * 4);
            float4 c4 = *(const float4*)(es + (p >> 16) * 4);
            float4 exv;
            float v;
            v = e4.x + er4.x + c4.x; v = v > 0.f ? v : SLOPE * v; exv.x = __expf(v - m4.x);
            v = e4.y + er4.y + c4.y; v = v > 0.f ? v : SLOPE * v; exv.y = __expf(v - m4.y);
            v = e4.z + er4.z + c4.z; v = v > 0.f ? v : SLOPE * v; exv.z = __expf(v - m4.z);
            v = e4.w + er4.w + c4.w; v = v > 0.f ? v : SLOPE * v; exv.w = __expf(v - m4.w);
            if (base == r0) {
                as_lds[wave][0][lane] = make_int2(__float_as_int(exv.x), p & 0xFFFF);
                as_lds[wave][1][lane] = make_int2(__float_as_int(exv.y), p & 0xFFFF);
                as_lds[wave][2][lane] = make_int2(__float_as_int(exv.z), p & 0xFFFF);
                as_lds[wave][3][lane] = make_int2(__float_as_int(exv.w), p & 0xFFFF);
            }
            s4.x += exv.x; s4.y += exv.y; s4.z += exv.z; s4.w += exv.w;
        }
    }
    #pragma unroll
    for (int off = 1; off < 64; off <<= 1) {
        s4.x += __shfl_xor(s4.x, off);
        s4.y += __shfl_xor(s4.y, off);
        s4.z += __shfl_xor(s4.z, off);
        s4.w += __shfl_xor(s4.w, off);
    }
    float4 inv4;
    inv4.x = 1.f / (s4.x + 1e-9f); inv4.y = 1.f / (s4.y + 1e-9f);
    inv4.z = 1.f / (s4.z + 1e-9f); inv4.w = 1.f / (s4.w + 1e-9f);
    {
        int idx = r0 + lane;
        float4 a;
        a.x = __int_as_float(as_lds[wave][0][lane].x) * inv4.x;
        a.y = __int_as_float(as_lds[wave][1][lane].x) * inv4.y;
        a.z = __int_as_float(as_lds[wave][2][lane].x) * inv4.z;
        a.w = __int_as_float(as_lds[wave][3][lane].x) * inv4.w;
        if (HAS_PREV) {
            h4 pv = *(const h4*)(aprev + (size_t)idx * 4);
            a.x = a.x * (1.f - ALPHA) + ALPHA * (float)pv[0];
            a.y = a.y * (1.f - ALPHA) + ALPHA * (float)pv[1];
            a.z = a.z * (1.f - ALPHA) + ALPHA * (float)pv[2];
            a.w = a.w * (1.f - ALPHA) + ALPHA * (float)pv[3];
        }
        if (WRITE_A) {
            h4 aw;
            aw[0] = (_Float16)a.x; aw[1] = (_Float16)a.y;
            aw[2] = (_Float16)a.z; aw[3] = (_Float16)a.w;
            *(h4*)(awrite + (size_t)idx * 4) = aw;
        }
        as_lds[wave][0][lane].x = __float_as_int(a.x);
        as_lds[wave][1][lane].x = __float_as_int(a.y);
        as_lds[wave][2][lane].x = __float_as_int(a.z);
        as_lds[wave][3][lane].x = __float_as_int(a.w);
    }
    if (WRITE_A) {
        for (int base = r0 + 64; base < r1; base += 64) {
            int idx = base + lane;
            if (idx < r1) {
                int p = pk[idx];
                float4 e4 = *(const float4*)(el + (p & 0xFFFF) * 4);
                float4 c4 = *(const float4*)(es + (p >> 16) * 4);
                float4 a;
                float v;
                v = e4.x + er4.x + c4.x; v = v > 0.f ? v : SLOPE * v; a.x = __expf(v - m4.x) * inv4.x;
                v = e4.y + er4.y + c4.y; v = v > 0.f ? v : SLOPE * v; a.y = __expf(v - m4.y) * inv4.y;
                v = e4.z + er4.z + c4.z; v = v > 0.f ? v : SLOPE * v; a.z = __expf(v - m4.z) * inv4.z;
                v = e4.w + er4.w + c4.w; v = v > 0.f ? v : SLOPE * v; a.w = __expf(v - m4.w) * inv4.w;
                if (HAS_PREV) {
                    h4 pv = *(const h4*)(aprev + (size_t)idx * 4);
                    a.x = a.x * (1.f - ALPHA) + ALPHA * (float)pv[0];
                    a.y = a.y * (1.f - ALPHA) + ALPHA * (float)pv[1];
                    a.z = a.z * (1.f - ALPHA) + ALPHA * (float)pv[2];
                    a.w = a.w * (1.f - ALPHA) + ALPHA * (float)pv[3];
                }
                h4 aw;
                aw[0] = (_Float16)a.x; aw[1] = (_Float16)a.y;
                aw[2] = (_Float16)a.z; aw[3] = (_Float16)a.w;
                *(h4*)(awrite + (size_t)idx * 4) = aw;
            }
        }
    }
    const int h = lane >> 4;
    float4 acc = {0.f, 0.f, 0.f, 0.f};
    const int cap = r0 + 64;
    for (int i = r0; i < cap; i++) {
        int2 e0 = as_lds[wave][h][i - r0];
        h4 f = *(const h4*)(feat + (size_t)e0.y * 256 + lane * 4);
        float av = __int_as_float(e0.x);
        acc.x = fmaf(av, (float)f[0], acc.x);
        acc.y = fmaf(av, (float)f[1], acc.y);
        acc.z = fmaf(av, (float)f[2], acc.z);
        acc.w = fmaf(av, (float)f[3], acc.w);
    }
    {
        float mh = sel4(m4, h), invh = sel4(inv4, h), erh = sel4(er4, h);
        for (int i = cap; i < r1; i++) {
            int p = pk[i];
            int s = p & 0xFFFF, t = p >> 16;
            float v = el[s * 4 + h] + erh + es[t * 4 + h];
            v = v > 0.f ? v : SLOPE * v;
            float a = __expf(v - mh) * invh;
            if (HAS_PREV) a = a * (1.f - ALPHA) + ALPHA * (float)aprev[(size_t)i * 4 + h];
            h4 f = *(const h4*)(feat + (size_t)s * 256 + lane * 4);
            acc.x = fmaf(a, (float)f[0], acc.x);
            acc.y = fmaf(a, (float)f[1], acc.y);
            acc.z = fmaf(a, (float)f[2], acc.z);
            acc.w = fmaf(a, (float)f[3], acc.w);
        }
    }
    if (HAS_RES) {
        h4 rv = *(const h4*)(resh + (size_t)n * 256 + lane * 4);
        acc.x += (float)rv[0]; acc.y += (float)rv[1];
        acc.z += (float)rv[2]; acc.w += (float)rv[3];
    }
    acc.x = elu_fast(acc.x);
    acc.y = elu_fast(acc.y);
    acc.z = elu_fast(acc.z);
    acc.w = elu_fast(acc.w);
    h4 o;
    o[0] = (_Float16)acc.x; o[1] = (_Float16)acc.y;
    o[2] = (_Float16)acc.z; o[3] = (_Float16)acc.w;
    *(h4*)(outh + (size_t)n * 256 + lane * 4) = o;
}

// ---------------- fused GAT layer 2 (H=1, C=16): one wave per node; cpack is fp16 ----------------

__global__ __launch_bounds__(256) void gat_fused1(const int* __restrict__ rowstart,
                                                  const int* __restrict__ pk,
                                                  const float* __restrict__ el,
                                                  const float* __restrict__ er,
                                                  const float* __restrict__ es,
                                                  const _Float16* __restrict__ cpack,
                                                  float* __restrict__ out, int nN) {
    const int wave = threadIdx.x >> 6;
    const int lane = threadIdx.x & 63;
    int n = blockIdx.x * 4 + wave;
    if (n >= nN) return;
    const int r0 = rowstart[n], r1 = rowstart[n + 1];
    const int deg = r1 - r0;
    const float ern = er[n];

    if (deg <= 64) {
        const int idx = r0 + lane;
        const bool act = idx < r1;
        int p = act ? pk[idx] : 0;
        int psrc = p & 0xFFFF;
        float v = -INFINITY;
        if (act) {
            float t = el[psrc] + ern + es[p >> 16];
            v = t > 0.f ? t : SLOPE * t;
        }
        float m = v;
        #pragma unroll
        for (int off = 1; off <= 8; off <<= 1) m = fmaxf(m, __shfl_xor(m, off));
        if (deg > 16) m = fmaxf(m, __shfl_xor(m, 16));
        if (deg > 32) m = fmaxf(m, __shfl_xor(m, 32));
        float ex = act ? __expf(v - m) : 0.f;
        float s = ex;
        #pragma unroll
        for (int off = 1; off <= 8; off <<= 1) s += __shfl_xor(s, off);
        if (deg > 16) s += __shfl_xor(s, 16);
        if (deg > 32) s += __shfl_xor(s, 32);
        float a = ex / (s + 1e-9f);

        const int eslot = lane >> 4, fl = lane & 15;
        float acc = 0.f;
        int i = r0;
        for (; i + 7 < r1; i += 8) {
            int j0 = (i - r0) + eslot;
            int j1 = j0 + 4;
            int s0 = __shfl(psrc, j0);
            int s1 = __shfl(psrc, j1);
            float a0 = __shfl(a, j0);
            float a1 = __shfl(a, j1);
            float f0 = (float)cpack[(size_t)s0 * 32 + fl];
            float f1 = (float)cpack[(size_t)s1 * 32 + fl];
            acc = fmaf(a0, f0, acc);
            acc = fmaf(a1, f1, acc);
        }
        for (; i + 3 < r1; i += 4) {
            int j = (i - r0) + eslot;
            int sj = __shfl(psrc, j);
            float aj = __shfl(a, j);
            acc = fmaf(aj, (float)cpack[(size_t)sj * 32 + fl], acc);
        }
        int rem = r1 - i;
        if (rem > 0) {   // wave-uniform branch: full exec for the shfls below
            int j = (i - r0) + (eslot < rem ? eslot : rem - 1);
            int sj = __shfl(psrc, j);
            float aj = __shfl(a, j);
            if (eslot >= rem) aj = 0.f;
            acc = fmaf(aj, (float)cpack[(size_t)sj * 32 + fl], acc);
        }
        acc += __shfl_xor(acc, 16);
        acc += __shfl_xor(acc, 32);
        if (lane < 16) out[(size_t)n * 16 + lane] = acc + (float)cpack[(size_t)n * 32 + 16 + lane];
        return;
    }

    // fallback deg > 64 (rare)
    float m = -INFINITY;
    for (int base = r0; base < r1; base += 64) {
        int idx = base + lane;
        if (idx < r1) {
            int p = pk[idx];
            float v = el[p & 0xFFFF] + ern + es[p >> 16];
            v = v > 0.f ? v : SLOPE * v;
            m = fmaxf(m, v);
        }
    }
    #pragma unroll
    for (int off = 1; off < 64; off <<= 1) m = fmaxf(m, __shfl_xor(m, off));
    float s = 0.f;
    for (int base = r0; base < r1; base += 64) {
        int idx = base + lane;
        if (idx < r1) {
            int p = pk[idx];
            float v = el[p & 0xFFFF] + ern + es[p >> 16];
            v = v > 0.f ? v : SLOPE * v;
            s += __expf(v - m);
        }
    }
    #pragma unroll
    for (int off = 1; off < 64; off <<= 1) s += __shfl_xor(s, off);
    float inv = 1.f / (s + 1e-9f);
    const int eslot = lane >> 4, fl = lane & 15;
    float acc = 0.f;
    for (int i = r0; i < r1; i += 4) {
        int rem = r1 - i;
        if (eslot < rem) {
            int j = i + eslot;
            int p = pk[j];
            float v = el[p & 0xFFFF] + ern + es[p >> 16];
            v = v > 0.f ? v : SLOPE * v;
            float a = __expf(v - m) * inv;
            acc = fmaf(a, (float)cpack[(size_t)(p & 0xFFFF) * 32 + fl], acc);
        }
    }
    acc += __shfl_xor(acc, 16);
    acc += __shfl_xor(acc, 32);
    if (lane < 16) out[(size_t)n * 16 + lane] = acc + (float)cpack[(size_t)n * 32 + 16 + lane];
}

// ---------------- host ----------------

extern "C" void kernel_launch(void* const* d_in, const int* in_sizes, int n_in,
                              void* d_out, int out_size, void* d_ws, size_t ws_size,
                              hipStream_t stream) {
    const float* x0 = (const float*)d_in[0];
    const float* x1 = (const float*)d_in[1];
    const float* x2 = (const float*)d_in[2];
    const int* src  = (const int*)d_in[3];
    const int* dst  = (const int*)d_in[4];
    const int* et   = (const int*)d_in[5];
    const float* W0 = (const float*)d_in[6];  const float* b0 = (const float*)d_in[7];
    const float* W1 = (const float*)d_in[8];  const float* b1 = (const float*)d_in[9];
    const float* W2 = (const float*)d_in[10]; const float* b2 = (const float*)d_in[11];
    const float* Wg0 = (const float*)d_in[12]; const float* etab0 = (const float*)d_in[13];
    const float* We0 = (const float*)d_in[14]; const float* al0 = (const float*)d_in[15];
    const float* ar0 = (const float*)d_in[16]; const float* ae0 = (const float*)d_in[17];
    const float* Wg1 = (const float*)d_in[18]; const float* etab1 = (const float*)d_in[19];
    const float* We1 = (const float*)d_in[20]; const float* al1 = (const float*)d_in[21];
    const float* ar1 = (const float*)d_in[22]; const float* ae1 = (const float*)d_in[23];
    const float* Wg2 = (const float*)d_in[24]; const float* etab2 = (const float*)d_in[25];
    const float* We2 = (const float*)d_in[26]; const float* al2 = (const float*)d_in[27];
    const float* ar2 = (const float*)d_in[28]; const float* ae2 = (const float*)d_in[29];
    const float* resW2 = (const float*)d_in[30];
    float* outp = (float*)d_out;

    char* p = (char*)d_ws;
    auto alloc = [&](size_t bytes) -> void* {
        void* r = (void*)p;
        p += (bytes + 255) & ~(size_t)255;
        return r;
    };
    _Float16* x0h   = (_Float16*)alloc((size_t)N0 * 128 * 2);
    _Float16* x1h   = (_Float16*)alloc((size_t)N1 * 64 * 2);
    _Float16* x2h   = (_Float16*)alloc((size_t)N2 * 32 * 2);
    _Float16* W0h   = (_Float16*)alloc(64 * 128 * 2);
    _Float16* W1h   = (_Float16*)alloc(64 * 64 * 2);
    _Float16* W2h   = (_Float16*)alloc(64 * 32 * 2);
    _Float16* Wg0h  = (_Float16*)alloc(256 * 64 * 2);
    _Float16* Wg1h  = (_Float16*)alloc(256 * 256 * 2);
    _Float16* wpkh  = (_Float16*)alloc(32 * 256 * 2);
    _Float16* h0h   = (_Float16*)alloc((size_t)NN * 64 * 2);
    _Float16* feath = (_Float16*)alloc((size_t)NN * 256 * 2);
    _Float16* bufAh = (_Float16*)alloc((size_t)NN * 256 * 2);
    _Float16* bufBh = (_Float16*)alloc((size_t)NN * 256 * 2);
    _Float16* a0h   = (_Float16*)alloc((size_t)EE * 4 * 2);
    _Float16* cpackh = (_Float16*)alloc((size_t)NN * 32 * 2);
    float* el    = (float*)alloc((size_t)NN * 4 * 4);
    float* er    = (float*)alloc((size_t)NN * 4 * 4);
    float* es    = (float*)alloc(96 * 4);
    int* rowstart = (int*)alloc((size_t)(NN + 1) * 4);
    int* deg      = (int*)alloc((size_t)NN * 4);
    int* cursor   = (int*)alloc((size_t)NN * 4);
    int* bsum     = (int*)alloc(256 * 4);
    int* pk       = (int*)alloc((size_t)EE * 4);

    const int EB = (EE + 255) / 256;        // 3125
    const int NB = (NN + 255) / 256;        // 196
    const int MB128 = (NN + 127) / 128;     // 391
    const int WB = (NN + 3) / 4;            // 12500
    const int nb0 = (N0 + 127) / 128;       // 157
    const int nb1 = (N1 + 127) / 128;       // 118
    const int nb2 = (N2 + 127) / 128;       // 118

    // CSR build
    hipMemsetAsync(deg, 0, (size_t)NN * 4, stream);
    hist_kernel<<<EB, 256, 0, stream>>>(dst, deg, EE);
    block_sum_kernel<<<NB, 256, 0, stream>>>(deg, bsum, NN);
    scan_out2<<<NB, 256, 0, stream>>>(deg, bsum, rowstart, cursor, NN, NB);
    scatter_kernel<<<EB, 256, 0, stream>>>(src, dst, et, cursor, pk, EE);

    // prep: es tables + converts (one dispatch)
    {
        int n0c = N0 * 128, n1c = N1 * 64, n2c = N2 * 32;
        int total = n0c + n1c + n2c + 8192 + 4096 + 2048 + 16384 + 65536 + 4096 + 4096;
        prep_kernel<<<18 + (total + 255) / 256, 256, 0, stream>>>(
            etab0, We0, ae0, etab1, We1, ae1, etab2, We2, ae2, es,
            x0, x0h, n0c, x1, x1h, n1c, x2, x2h, n2c,
            W0, W0h, 8192, W1, W1h, 4096, W2, W2h, 2048,
            Wg0, Wg0h, 16384, Wg1, Wg1h, 65536,
            Wg2, wpkh, 4096, resW2, wpkh + 4096, 4096);
    }

    // input projections (one dispatch) -> h0h [N,64] fp16
    proj3<<<nb0 + nb1 + nb2, 256, 0, stream>>>(x0h, W0h, b0, x1h, W1h, b1, x2h, W2h, b2,
                                               h0h, nb0, nb1);

    // ---- GAT layer 0 ----
    gemm_mfma<8, 1><<<dim3(MB128, 2), 256, 0, stream>>>(h0h, Wg0h, nullptr, nullptr, feath,
                                                        el, er, al0, ar0, NN, 256, 64);
    gat_fused4<true, false, false><<<WB, 256, 0, stream>>>(
        rowstart, pk, el, er, es + 0, feath, nullptr, a0h, nullptr, bufAh, NN);

    // ---- GAT layer 1 ----
    gemm_mfma<8, 1><<<dim3(MB128, 2), 256, 0, stream>>>(bufAh, Wg1h, nullptr, nullptr, feath,
                                                        el, er, al1, ar1, NN, 256, 256);
    gat_fused4<false, true, true><<<WB, 256, 0, stream>>>(
        rowstart, pk, el, er, es + 32, feath, a0h, nullptr, bufAh, bufBh, NN);

    // ---- GAT layer 2 (H=1, C=16, linear residual, no act) ----
    gemm_mfma<2, 2><<<dim3(MB128, 1), 256, 0, stream>>>(bufBh, wpkh, nullptr, nullptr, cpackh,
                                                        el, er, al2, ar2, NN, 32, 256);
    gat_fused1<<<WB, 256, 0, stream>>>(rowstart, pk, el, er, es + 64, cpackh, outp, NN);
}

// Round 11
// 464.577 us; speedup vs baseline: 1.1354x; 1.0206x over previous
//
#include <hip/hip_runtime.h>
#include <math.h>

#define N0 20000
#define N1 15000
#define N2 15000
#define NN 50000          // total nodes
#define EE 800000         // edges
#define SLOPE 0.2f
#define ALPHA 0.05f

typedef _Float16 h8 __attribute__((ext_vector_type(8)));
typedef _Float16 h4 __attribute__((ext_vector_type(4)));
typedef float f4v __attribute__((ext_vector_type(4)));

__device__ __forceinline__ float sel4(float4 v, int h) {
    float lo = (h & 1) ? v.y : v.x;
    float hi = (h & 1) ? v.w : v.z;
    return (h & 2) ? hi : lo;
}

__device__ __forceinline__ float elu_fast(float x) {
    return x > 0.f ? x : __expf(x) - 1.f;
}

// ---------------- es table pair (one wave per (layer,t,h)) ----------------

__device__ __forceinline__ void es_pair(int p,
                                        const float* __restrict__ etab0, const float* __restrict__ We0, const float* __restrict__ ae0,
                                        const float* __restrict__ etab1, const float* __restrict__ We1, const float* __restrict__ ae1,
                                        const float* __restrict__ etab2, const float* __restrict__ We2, const float* __restrict__ ae2,
                                        float* __restrict__ es) {
    const float *etab, *We, *ae;
    float* out;
    int H;
    if (p < 32)      { etab = etab0; We = We0; ae = ae0; out = es;      H = 4; }
    else if (p < 64) { p -= 32; etab = etab1; We = We1; ae = ae1; out = es + 32; H = 4; }
    else             { p -= 64; etab = etab2; We = We2; ae = ae2; out = es + 64; H = 1; }
    int t = p / H, h = p % H;
    int j = threadIdx.x & 63;
    const float* w = We + (size_t)(h * 64 + j) * 64;
    const float* e = etab + t * 64;
    float s = 0.f;
    #pragma unroll
    for (int k = 0; k < 64; k += 4) {
        float4 wv = *(const float4*)(w + k);
        float4 ev = *(const float4*)(e + k);
        s += wv.x * ev.x + wv.y * ev.y + wv.z * ev.z + wv.w * ev.w;
    }
    s *= ae[h * 64 + j];
    #pragma unroll
    for (int off = 32; off > 0; off >>= 1) s += __shfl_down(s, off);
    if (j == 0) out[t * H + h] = s;
}

__device__ __forceinline__ void cvt4(const float* __restrict__ s, _Float16* __restrict__ d, int t) {
    float4 v = ((const float4*)s)[t];
    h4 o;
    o[0] = (_Float16)v.x; o[1] = (_Float16)v.y;
    o[2] = (_Float16)v.z; o[3] = (_Float16)v.w;
    ((h4*)d)[t] = o;
}

// ---------------- K1: hist (blocks 0..EB-1) || es tables (next 18) || converts ----------------

__global__ __launch_bounds__(256) void k1_hist_prep(
        const int* __restrict__ dst, int* __restrict__ deg,
        const float* etab0, const float* We0, const float* ae0,
        const float* etab1, const float* We1, const float* ae1,
        const float* etab2, const float* We2, const float* ae2,
        float* es,
        const float* s0, _Float16* d0, int n0,
        const float* s1, _Float16* d1, int n1,
        const float* s2, _Float16* d2, int n2,
        const float* s3, _Float16* d3, int n3,
        const float* s4, _Float16* d4, int n4,
        const float* s5, _Float16* d5, int n5,
        const float* s6, _Float16* d6, int n6,
        const float* s7, _Float16* d7, int n7,
        const float* s8, _Float16* d8, int n8,
        const float* s9, _Float16* d9, int n9, int EB) {
    int b = blockIdx.x;
    if (b < EB) {
        int e = b * 256 + threadIdx.x;
        if (e < EE) atomicAdd(&deg[dst[e]], 1);
        return;
    }
    b -= EB;
    if (b < 18) {
        int p = b * 4 + (threadIdx.x >> 6);
        if (p < 72) es_pair(p, etab0, We0, ae0, etab1, We1, ae1, etab2, We2, ae2, es);
        return;
    }
    int t = (b - 18) * 256 + threadIdx.x;   // vector-of-4 index
    if (t < (n0 >> 2)) { cvt4(s0, d0, t); return; } t -= n0 >> 2;
    if (t < (n1 >> 2)) { cvt4(s1, d1, t); return; } t -= n1 >> 2;
    if (t < (n2 >> 2)) { cvt4(s2, d2, t); return; } t -= n2 >> 2;
    if (t < (n3 >> 2)) { cvt4(s3, d3, t); return; } t -= n3 >> 2;
    if (t < (n4 >> 2)) { cvt4(s4, d4, t); return; } t -= n4 >> 2;
    if (t < (n5 >> 2)) { cvt4(s5, d5, t); return; } t -= n5 >> 2;
    if (t < (n6 >> 2)) { cvt4(s6, d6, t); return; } t -= n6 >> 2;
    if (t < (n7 >> 2)) { cvt4(s7, d7, t); return; } t -= n7 >> 2;
    if (t < (n8 >> 2)) { cvt4(s8, d8, t); return; } t -= n8 >> 2;
    if (t < (n9 >> 2)) { cvt4(s9, d9, t); }
}

// ---------------- scan pieces ----------------

__device__ __forceinline__ void block_sum_body(int b, const int* __restrict__ deg,
                                               int* __restrict__ bsum, int n) {
    int i = b * 256 + threadIdx.x;
    int v = (i < n) ? deg[i] : 0;
    #pragma unroll
    for (int off = 32; off > 0; off >>= 1) v += __shfl_down(v, off);
    __shared__ int sh[4];
    if ((threadIdx.x & 63) == 0) sh[threadIdx.x >> 6] = v;
    __syncthreads();
    if (threadIdx.x == 0) bsum[b] = sh[0] + sh[1] + sh[2] + sh[3];
}

__global__ __launch_bounds__(256) void scan_out2(const int* __restrict__ deg,
                                                 const int* __restrict__ bsum,
                                                 int* __restrict__ rowstart,
                                                 int* __restrict__ cursor, int n, int nb) {
    __shared__ int sb[256];
    __shared__ int boff_s;
    int tid = threadIdx.x;
    int v = (tid < nb) ? bsum[tid] : 0;
    sb[tid] = v;
    __syncthreads();
    #pragma unroll
    for (int off = 1; off < 256; off <<= 1) {
        int t = (tid >= off) ? sb[tid - off] : 0;
        __syncthreads();
        sb[tid] += t;
        __syncthreads();
    }
    if (tid == blockIdx.x) boff_s = sb[tid] - v;
    __syncthreads();
    int boff = boff_s;
    int i = blockIdx.x * 256 + tid;
    int d = (i < n) ? deg[i] : 0;
    __syncthreads();
    sb[tid] = d;
    __syncthreads();
    #pragma unroll
    for (int off = 1; off < 256; off <<= 1) {
        int t = (tid >= off) ? sb[tid - off] : 0;
        __syncthreads();
        sb[tid] += t;
        __syncthreads();
    }
    int excl = sb[tid] - d + boff;
    if (i < n) { rowstart[i] = excl; cursor[i] = excl; }
    if (i == n - 1) rowstart[n] = excl + d;
}

// ---------------- MFMA fp16 GEMM body (verified fragment mapping) ----------------
// ELR: 0 none; 1 fused el/er (H=4/D=64, y-block = 2 heads); 2 fused el/er (H=1,D=16).

template<int NT, int ELR>
__device__ __forceinline__ void gemm_body(int bx, int by,
                                          const _Float16* __restrict__ A,
                                          const _Float16* __restrict__ B,
                                          const float* __restrict__ bias,
                                          float* __restrict__ Cf,
                                          _Float16* __restrict__ Ch,
                                          float* __restrict__ el,
                                          float* __restrict__ er,
                                          const float* __restrict__ al,
                                          const float* __restrict__ ar,
                                          int M, int N, int K) {
    const int wave = threadIdx.x >> 6;
    const int lane = threadIdx.x & 63;
    const int m_base = (bx * 4 + wave) * 32;
    const int n_base = by * (NT * 16);
    const int row = lane & 15;
    const int kq = (lane >> 4) * 8;

    f4v acc[2][NT];
    #pragma unroll
    for (int i = 0; i < 2; i++)
        #pragma unroll
        for (int j = 0; j < NT; j++) {
            f4v z = {0.f, 0.f, 0.f, 0.f};
            acc[i][j] = z;
        }

    int ra = m_base + row;       if (ra >= M) ra = M - 1;
    int rb2 = m_base + 16 + row; if (rb2 >= M) rb2 = M - 1;
    const _Float16* a0p = A + (size_t)ra * K + kq;
    const _Float16* a1p = A + (size_t)rb2 * K + kq;
    const _Float16* bp  = B + (size_t)(n_base + row) * K + kq;

    for (int k = 0; k < K; k += 32) {
        h8 a0 = *(const h8*)(a0p + k);
        h8 a1 = *(const h8*)(a1p + k);
        #pragma unroll
        for (int j = 0; j < NT; j++) {
            h8 b = *(const h8*)(bp + (size_t)j * 16 * K + k);
            acc[0][j] = __builtin_amdgcn_mfma_f32_16x16x32_f16(a0, b, acc[0][j], 0, 0, 0);
            acc[1][j] = __builtin_amdgcn_mfma_f32_16x16x32_f16(a1, b, acc[1][j], 0, 0, 0);
        }
    }

    const int col = lane & 15;
    const int rb = (lane >> 4) * 4;

    if (ELR == 1) {
        float alw[NT], arw[NT];
        #pragma unroll
        for (int j = 0; j < NT; j++) {
            int cg = n_base + j * 16 + col;
            int hg = cg >> 6, d = cg & 63;
            alw[j] = al[hg * 64 + d];
            arw[j] = ar[hg * 64 + d];
        }
        const int hb = n_base >> 6;
        #pragma unroll
        for (int ms = 0; ms < 2; ms++) {
            #pragma unroll
            for (int r = 0; r < 4; r++) {
                float e0 = 0.f, e1 = 0.f, f0 = 0.f, f1 = 0.f;
                #pragma unroll
                for (int j = 0; j < NT; j++) {
                    float av = acc[ms][j][r];
                    if (j < NT / 2) { e0 = fmaf(av, alw[j], e0); f0 = fmaf(av, arw[j], f0); }
                    else            { e1 = fmaf(av, alw[j], e1); f1 = fmaf(av, arw[j], f1); }
                }
                #pragma unroll
                for (int off = 1; off <= 8; off <<= 1) {
                    e0 += __shfl_xor(e0, off);
                    e1 += __shfl_xor(e1, off);
                    f0 += __shfl_xor(f0, off);
                    f1 += __shfl_xor(f1, off);
                }
                int m = m_base + ms * 16 + rb + r;
                if (col == 0 && m < M) {
                    el[m * 4 + hb]     = e0;
                    el[m * 4 + hb + 1] = e1;
                    er[m * 4 + hb]     = f0;
                    er[m * 4 + hb + 1] = f1;
                }
            }
        }
    }
    if (ELR == 2) {
        float alw = al[col], arw = ar[col];
        #pragma unroll
        for (int ms = 0; ms < 2; ms++) {
            #pragma unroll
            for (int r = 0; r < 4; r++) {
                float e = acc[ms][0][r] * alw;
                float f = acc[ms][0][r] * arw;
                #pragma unroll
                for (int off = 1; off <= 8; off <<= 1) {
                    e += __shfl_xor(e, off);
                    f += __shfl_xor(f, off);
                }
                int m = m_base + ms * 16 + rb + r;
                if (col == 0 && m < M) { el[m] = e; er[m] = f; }
            }
        }
    }

    #pragma unroll
    for (int ms = 0; ms < 2; ms++) {
        #pragma unroll
        for (int j = 0; j < NT; j++) {
            #pragma unroll
            for (int r = 0; r < 4; r++) {
                int m = m_base + ms * 16 + rb + r;
                if (m < M) {
                    int n = n_base + j * 16 + col;
                    float v = acc[ms][j][r];
                    if (bias) v += bias[n];
                    if (Cf) Cf[(size_t)m * N + n] = v;
                    if (Ch) Ch[(size_t)m * N + n] = (_Float16)v;
                }
            }
        }
    }
}

template<int NT, int ELR>
__global__ __launch_bounds__(256) void gemm_mfma(const _Float16* __restrict__ A,
                                                 const _Float16* __restrict__ B,
                                                 const float* __restrict__ bias,
                                                 float* __restrict__ Cf,
                                                 _Float16* __restrict__ Ch,
                                                 float* __restrict__ el,
                                                 float* __restrict__ er,
                                                 const float* __restrict__ al,
                                                 const float* __restrict__ ar,
                                                 int M, int N, int K) {
    gemm_body<NT, ELR>(blockIdx.x, blockIdx.y, A, B, bias, Cf, Ch, el, er, al, ar, M, N, K);
}

// ---------------- K2: block_sum (blocks 0..NB-1) || proj3 ----------------

__global__ __launch_bounds__(256) void k2_bsum_proj(
        const int* __restrict__ deg, int* __restrict__ bsum, int NBv,
        const _Float16* __restrict__ x0h, const _Float16* __restrict__ W0h, const float* __restrict__ b0,
        const _Float16* __restrict__ x1h, const _Float16* __restrict__ W1h, const float* __restrict__ b1,
        const _Float16* __restrict__ x2h, const _Float16* __restrict__ W2h, const float* __restrict__ b2,
        _Float16* __restrict__ h0h, int nb0, int nb1) {
    int b = blockIdx.x;
    if (b < NBv) { block_sum_body(b, deg, bsum, NN); return; }
    b -= NBv;
    if (b < nb0) {
        gemm_body<4, 0>(b, 0, x0h, W0h, b0, nullptr, h0h,
                        nullptr, nullptr, nullptr, nullptr, N0, 64, 128);
    } else if (b < nb0 + nb1) {
        gemm_body<4, 0>(b - nb0, 0, x1h, W1h, b1, nullptr, h0h + (size_t)N0 * 64,
                        nullptr, nullptr, nullptr, nullptr, N1, 64, 64);
    } else {
        gemm_body<4, 0>(b - nb0 - nb1, 0, x2h, W2h, b2, nullptr, h0h + (size_t)(N0 + N1) * 64,
                        nullptr, nullptr, nullptr, nullptr, N2, 64, 32);
    }
}

// ---------------- K4: scatter (blocks 0..EB-1) || gemm0 + fused el/er ----------------

__global__ __launch_bounds__(256) void k4_scat_gemm0(
        const int* __restrict__ src, const int* __restrict__ dst, const int* __restrict__ et,
        int* __restrict__ cursor, int* __restrict__ pk, int EB,
        const _Float16* __restrict__ h0h, const _Float16* __restrict__ Wg0h,
        _Float16* __restrict__ feath, float* __restrict__ el, float* __restrict__ er,
        const float* __restrict__ al0, const float* __restrict__ ar0, int MB) {
    int b = blockIdx.x;
    if (b < EB) {
        int e = b * 256 + threadIdx.x;
        if (e < EE) {
            int d = dst[e];
            int p = atomicAdd(&cursor[d], 1);
            pk[p] = (et[e] << 16) | src[e];
        }
        return;
    }
    int t = b - EB;
    int bx = t % MB, by = t / MB;
    gemm_body<8, 1>(bx, by, h0h, Wg0h, nullptr, nullptr, feath, el, er, al0, ar0, NN, 256, 64);
}

// ---------------- fused GAT edge stage, H=4 ----------------
// one wave per dst node; LDS [wave][h][66] conflict-free.
// All __shfl under wave-uniform control flow (round-5 lesson).

template<bool WRITE_A, bool HAS_PREV, bool HAS_RES>
__global__ __launch_bounds__(256) void gat_fused4(const int* __restrict__ rowstart,
                                                  const int* __restrict__ pk,
                                                  const float* __restrict__ el,
                                                  const float* __restrict__ er,
                                                  const float* __restrict__ es,
                                                  const _Float16* __restrict__ feat,
                                                  const _Float16* __restrict__ aprev,
                                                  _Float16* __restrict__ awrite,
                                                  const _Float16* __restrict__ resh,
                                                  _Float16* __restrict__ outh, int nN) {
    __shared__ int2 as_lds[4][4][66];   // [wave][h][edge] = {f32 bits of a, src}
    const int wave = threadIdx.x >> 6;
    const int lane = threadIdx.x & 63;
    int n = blockIdx.x * 4 + wave;
    if (n >= nN) return;
    const int r0 = rowstart[n], r1 = rowstart[n + 1];
    const int deg = r1 - r0;
    float4 er4 = *(const float4*)(er + n * 4);

    if (deg <= 64) {
        // ---- phase A: one edge per lane, in-register softmax ----
        const int idx = r0 + lane;
        const bool act = idx < r1;
        int p = act ? pk[idx] : 0;
        int psrc = p & 0xFFFF;
        float4 v4 = {-INFINITY, -INFINITY, -INFINITY, -INFINITY};
        if (act) {
            float4 e4 = *(const float4*)(el + psrc * 4);
            float4 c4 = *(const float4*)(es + (p >> 16) * 4);
            float v;
            v = e4.x + er4.x + c4.x; v4.x = v > 0.f ? v : SLOPE * v;
            v = e4.y + er4.y + c4.y; v4.y = v > 0.f ? v : SLOPE * v;
            v = e4.z + er4.z + c4.z; v4.z = v > 0.f ? v : SLOPE * v;
            v = e4.w + er4.w + c4.w; v4.w = v > 0.f ? v : SLOPE * v;
        }
        float4 m4 = v4;
        #pragma unroll
        for (int off = 1; off <= 8; off <<= 1) {
            m4.x = fmaxf(m4.x, __shfl_xor(m4.x, off));
            m4.y = fmaxf(m4.y, __shfl_xor(m4.y, off));
            m4.z = fmaxf(m4.z, __shfl_xor(m4.z, off));
            m4.w = fmaxf(m4.w, __shfl_xor(m4.w, off));
        }
        if (deg > 16) {
            m4.x = fmaxf(m4.x, __shfl_xor(m4.x, 16));
            m4.y = fmaxf(m4.y, __shfl_xor(m4.y, 16));
            m4.z = fmaxf(m4.z, __shfl_xor(m4.z, 16));
            m4.w = fmaxf(m4.w, __shfl_xor(m4.w, 16));
        }
        if (deg > 32) {
            m4.x = fmaxf(m4.x, __shfl_xor(m4.x, 32));
            m4.y = fmaxf(m4.y, __shfl_xor(m4.y, 32));
            m4.z = fmaxf(m4.z, __shfl_xor(m4.z, 32));
            m4.w = fmaxf(m4.w, __shfl_xor(m4.w, 32));
        }
        float4 ex = {0.f, 0.f, 0.f, 0.f};
        if (act) {
            ex.x = __expf(v4.x - m4.x);
            ex.y = __expf(v4.y - m4.y);
            ex.z = __expf(v4.z - m4.z);
            ex.w = __expf(v4.w - m4.w);
        }
        float4 s4 = ex;
        #pragma unroll
        for (int off = 1; off <= 8; off <<= 1) {
            s4.x += __shfl_xor(s4.x, off);
            s4.y += __shfl_xor(s4.y, off);
            s4.z += __shfl_xor(s4.z, off);
            s4.w += __shfl_xor(s4.w, off);
        }
        if (deg > 16) {
            s4.x += __shfl_xor(s4.x, 16);
            s4.y += __shfl_xor(s4.y, 16);
            s4.z += __shfl_xor(s4.z, 16);
            s4.w += __shfl_xor(s4.w, 16);
        }
        if (deg > 32) {
            s4.x += __shfl_xor(s4.x, 32);
            s4.y += __shfl_xor(s4.y, 32);
            s4.z += __shfl_xor(s4.z, 32);
            s4.w += __shfl_xor(s4.w, 32);
        }
        float4 a4;
        a4.x = ex.x / (s4.x + 1e-9f);
        a4.y = ex.y / (s4.y + 1e-9f);
        a4.z = ex.z / (s4.z + 1e-9f);
        a4.w = ex.w / (s4.w + 1e-9f);
        if (HAS_PREV && act) {
            h4 pv = *(const h4*)(aprev + (size_t)idx * 4);
            a4.x = a4.x * (1.f - ALPHA) + ALPHA * (float)pv[0];
            a4.y = a4.y * (1.f - ALPHA) + ALPHA * (float)pv[1];
            a4.z = a4.z * (1.f - ALPHA) + ALPHA * (float)pv[2];
            a4.w = a4.w * (1.f - ALPHA) + ALPHA * (float)pv[3];
        }
        if (WRITE_A && act) {
            h4 aw;
            aw[0] = (_Float16)a4.x; aw[1] = (_Float16)a4.y;
            aw[2] = (_Float16)a4.z; aw[3] = (_Float16)a4.w;
            *(h4*)(awrite + (size_t)idx * 4) = aw;
        }
        as_lds[wave][0][lane] = make_int2(__float_as_int(a4.x), psrc);
        as_lds[wave][1][lane] = make_int2(__float_as_int(a4.y), psrc);
        as_lds[wave][2][lane] = make_int2(__float_as_int(a4.z), psrc);
        as_lds[wave][3][lane] = make_int2(__float_as_int(a4.w), psrc);

        // ---- phase B: 2 edge-slots x 32 feature-chunks, unroll-4 ----
        const int half = lane >> 5;
        const int fl = lane & 31;
        const int h = fl >> 3;
        float acc8[8];
        #pragma unroll
        for (int q = 0; q < 8; q++) acc8[q] = 0.f;
        int i = r0;
        for (; i + 7 < r1; i += 8) {
            int j0 = (i - r0) + half;
            int2 e0 = as_lds[wave][h][j0 + 0];
            int2 e1 = as_lds[wave][h][j0 + 2];
            int2 e2 = as_lds[wave][h][j0 + 4];
            int2 e3 = as_lds[wave][h][j0 + 6];
            float a0 = __int_as_float(e0.x), a1 = __int_as_float(e1.x);
            float a2 = __int_as_float(e2.x), a3 = __int_as_float(e3.x);
            h8 f0 = *(const h8*)(feat + (size_t)e0.y * 256 + fl * 8);
            h8 f1 = *(const h8*)(feat + (size_t)e1.y * 256 + fl * 8);
            h8 f2 = *(const h8*)(feat + (size_t)e2.y * 256 + fl * 8);
            h8 f3 = *(const h8*)(feat + (size_t)e3.y * 256 + fl * 8);
            #pragma unroll
            for (int q = 0; q < 8; q++) acc8[q] = fmaf(a0, (float)f0[q], acc8[q]);
            #pragma unroll
            for (int q = 0; q < 8; q++) acc8[q] = fmaf(a1, (float)f1[q], acc8[q]);
            #pragma unroll
            for (int q = 0; q < 8; q++) acc8[q] = fmaf(a2, (float)f2[q], acc8[q]);
            #pragma unroll
            for (int q = 0; q < 8; q++) acc8[q] = fmaf(a3, (float)f3[q], acc8[q]);
        }
        for (; i + 3 < r1; i += 4) {
            int j0 = (i - r0) + half;
            int2 e0 = as_lds[wave][h][j0 + 0];
            int2 e1 = as_lds[wave][h][j0 + 2];
            float a0 = __int_as_float(e0.x), a1 = __int_as_float(e1.x);
            h8 f0 = *(const h8*)(feat + (size_t)e0.y * 256 + fl * 8);
            h8 f1 = *(const h8*)(feat + (size_t)e1.y * 256 + fl * 8);
            #pragma unroll
            for (int q = 0; q < 8; q++) acc8[q] = fmaf(a0, (float)f0[q], acc8[q]);
            #pragma unroll
            for (int q = 0; q < 8; q++) acc8[q] = fmaf(a1, (float)f1[q], acc8[q]);
        }
        for (; i + 1 < r1; i += 2) {
            int j0 = (i - r0) + half;
            int2 e0 = as_lds[wave][h][j0];
            float a0 = __int_as_float(e0.x);
            h8 f0 = *(const h8*)(feat + (size_t)e0.y * 256 + fl * 8);
            #pragma unroll
            for (int q = 0; q < 8; q++) acc8[q] = fmaf(a0, (float)f0[q], acc8[q]);
        }
        if (i < r1) {
            int j0 = i - r0;
            int2 e0 = as_lds[wave][h][j0];
            float a0 = (half == 0) ? __int_as_float(e0.x) : 0.f;
            h8 f0 = *(const h8*)(feat + (size_t)e0.y * 256 + fl * 8);
            #pragma unroll
            for (int q = 0; q < 8; q++) acc8[q] = fmaf(a0, (float)f0[q], acc8[q]);
        }
        #pragma unroll
        for (int q = 0; q < 8; q++) acc8[q] += __shfl_xor(acc8[q], 32);

        if (half == 0) {
            if (HAS_RES) {
                h8 rv = *(const h8*)(resh + (size_t)n * 256 + fl * 8);
                #pragma unroll
                for (int q = 0; q < 8; q++) acc8[q] += (float)rv[q];
            }
            #pragma unroll
            for (int q = 0; q < 8; q++) acc8[q] = elu_fast(acc8[q]);
            h8 o;
            #pragma unroll
            for (int q = 0; q < 8; q++) o[q] = (_Float16)acc8[q];
            *(h8*)(outh + (size_t)n * 256 + fl * 8) = o;
        }
        return;
    }

    // ---------------- fallback: deg > 64 (two-pass, rare) ----------------
    float4 m4 = {-INFINITY, -INFINITY, -INFINITY, -INFINITY};
    for (int base = r0; base < r1; base += 64) {
        int idx = base + lane;
        if (idx < r1) {
            int p = pk[idx];
            float4 e4 = *(const float4*)(el + (p & 0xFFFF) * 4);
            float4 c4 = *(const float4*)(es + (p >> 16) * 4);
            float v;
            v = e4.x + er4.x + c4.x; v = v > 0.f ? v : SLOPE * v; m4.x = fmaxf(m4.x, v);
            v = e4.y + er4.y + c4.y; v = v > 0.f ? v : SLOPE * v; m4.y = fmaxf(m4.y, v);
            v = e4.z + er4.z + c4.z; v = v > 0.f ? v : SLOPE * v; m4.z = fmaxf(m4.z, v);
            v = e4.w + er4.w + c4.w; v = v > 0.f ? v : SLOPE * v; m4.w = fmaxf(m4.w, v);
        }
    }
    #pragma unroll
    for (int off = 1; off < 64; off <<= 1) {
        m4.x = fmaxf(m4.x, __shfl_xor(m4.x, off));
        m4.y = fmaxf(m4.y, __shfl_xor(m4.y, off));
        m4.z = fmaxf(m4.z, __shfl_xor(m4.z, off));
        m4.w = fmaxf(m4.w, __shfl_xor(m4.w, off));
    }
    float4 s4 = {0.f, 0.f, 0.f, 0.f};
    for (int base = r0; base < r1; base += 64) {
        int idx = base + lane;
        if (idx < r1) {
            int p = pk[idx];
            float4 e4 = *(const float4*)(el + (p & 0xFFFF) * 4);
            float4 c4 = *(const float4*)(es + (p >> 16) * 4);
            float4 exv;
            float v;
            v = e4.x + er4.x + c4.x; v = v > 0.f ? v : SLOPE * v; exv.x = __expf(v - m4.x);
            v = e4.y + er4.y + c4.y; v = v > 0.f ? v : SLOPE * v; exv.y = __expf(v - m4.y);
            v = e4.z + er4.z + c4.z; v = v > 0.f ? v : SLOPE * v; exv.z = __expf(v - m4.z);
            v = e4.w + er4.w + c4.w; v = v > 0.f ? v : SLOPE * v; exv.w = __expf(v - m4.w);
            if (base == r0) {
                as_lds[wave][0][lane] = make_int2(__float_as_int(exv.x), p & 0xFFFF);
                as_lds[wave][1][lane] = make_int2(__float_as_int(exv.y), p & 0xFFFF);
                as_lds[wave][2][lane] = make_int2(__float_as_int(exv.z), p & 0xFFFF);
                as_lds[wave][3][lane] = make_int2(__float_as_int(exv.w), p & 0xFFFF);
            }
            s4.x += exv.x; s4.y += exv.y; s4.z += exv.z; s4.w += exv.w;
        }
    }
    #pragma unroll
    for (int off = 1; off < 64; off <<= 1) {
        s4.x += __shfl_xor(s4.x, off);
        s4.y += __shfl_xor(s4.y, off);
        s4.z += __shfl_xor(s4.z, off);
        s4.w += __shfl_xor(s4.w, off);
    }
    float4 inv4;
    inv4.x = 1.f / (s4.x + 1e-9f); inv4.y = 1.f / (s4.y + 1e-9f);
    inv4.z = 1.f / (s4.z + 1e-9f); inv4.w = 1.f / (s4.w + 1e-9f);
    {
        int idx = r0 + lane;
        float4 a;
        a.x = __int_as_float(as_lds[wave][0][lane].x) * inv4.x;
        a.y = __int_as_float(as_lds[wave][1][lane].x) * inv4.y;
        a.z = __int_as_float(as_lds[wave][2][lane].x) * inv4.z;
        a.w = __int_as_float(as_lds[wave][3][lane].x) * inv4.w;
        if (HAS_PREV) {
            h4 pv = *(const h4*)(aprev + (size_t)idx * 4);
            a.x = a.x * (1.f - ALPHA) + ALPHA * (float)pv[0];
            a.y = a.y * (1.f - ALPHA) + ALPHA * (float)pv[1];
            a.z = a.z * (1.f - ALPHA) + ALPHA * (float)pv[2];
            a.w = a.w * (1.f - ALPHA) + ALPHA * (float)pv[3];
        }
        if (WRITE_A) {
            h4 aw;
            aw[0] = (_Float16)a.x; aw[1] = (_Float16)a.y;
            aw[2] = (_Float16)a.z; aw[3] = (_Float16)a.w;
            *(h4*)(awrite + (size_t)idx * 4) = aw;
        }
        as_lds[wave][0][lane].x = __float_as_int(a.x);
        as_lds[wave][1][lane].x = __float_as_int(a.y);
        as_lds[wave][2][lane].x = __float_as_int(a.z);
        as_lds[wave][3][lane].x = __float_as_int(a.w);
    }
    if (WRITE_A) {
        for (int base = r0 + 64; base < r1; base += 64) {
            int idx = base + lane;
            if (idx < r1) {
                int p = pk[idx];
                float4 e4 = *(const float4*)(el + (p & 0xFFFF) * 4);
                float4 c4 = *(const float4*)(es + (p >> 16) * 4);
                float4 a;
                float v;
                v = e4.x + er4.x + c4.x; v = v > 0.f ? v : SLOPE * v; a.x = __expf(v - m4.x) * inv4.x;
                v = e4.y + er4.y + c4.y; v = v > 0.f ? v : SLOPE * v; a.y = __expf(v - m4.y) * inv4.y;
                v = e4.z + er4.z + c4.z; v = v > 0.f ? v : SLOPE * v; a.z = __expf(v - m4.z) * inv4.z;
                v = e4.w + er4.w + c4.w; v = v > 0.f ? v : SLOPE * v; a.w = __expf(v - m4.w) * inv4.w;
                if (HAS_PREV) {
                    h4 pv = *(const h4*)(aprev + (size_t)idx * 4);
                    a.x = a.x * (1.f - ALPHA) + ALPHA * (float)pv[0];
                    a.y = a.y * (1.f - ALPHA) + ALPHA * (float)pv[1];
                    a.z = a.z * (1.f - ALPHA) + ALPHA * (float)pv[2];
                    a.w = a.w * (1.f - ALPHA) + ALPHA * (float)pv[3];
                }
                h4 aw;
                aw[0] = (_Float16)a.x; aw[1] = (_Float16)a.y;
                aw[2] = (_Float16)a.z; aw[3] = (_Float16)a.w;
                *(h4*)(awrite + (size_t)idx * 4) = aw;
            }
        }
    }
    const int h = lane >> 4;
    float4 acc = {0.f, 0.f, 0.f, 0.f};
    const int cap = r0 + 64;
    for (int i = r0; i < cap; i++) {
        int2 e0 = as_lds[wave][h][i - r0];
        h4 f = *(const h4*)(feat + (size_t)e0.y * 256 + lane * 4);
        float av = __int_as_float(e0.x);
        acc.x = fmaf(av, (float)f[0], acc.x);
        acc.y = fmaf(av, (float)f[1], acc.y);
        acc.z = fmaf(av, (float)f[2], acc.z);
        acc.w = fmaf(av, (float)f[3], acc.w);
    }
    {
        float mh = sel4(m4, h), invh = sel4(inv4, h), erh = sel4(er4, h);
        for (int i = cap; i < r1; i++) {
            int p = pk[i];
            int s = p & 0xFFFF, t = p >> 16;
            float v = el[s * 4 + h] + erh + es[t * 4 + h];
            v = v > 0.f ? v : SLOPE * v;
            float a = __expf(v - mh) * invh;
            if (HAS_PREV) a = a * (1.f - ALPHA) + ALPHA * (float)aprev[(size_t)i * 4 + h];
            h4 f = *(const h4*)(feat + (size_t)s * 256 + lane * 4);
            acc.x = fmaf(a, (float)f[0], acc.x);
            acc.y = fmaf(a, (float)f[1], acc.y);
            acc.z = fmaf(a, (float)f[2], acc.z);
            acc.w = fmaf(a, (float)f[3], acc.w);
        }
    }
    if (HAS_RES) {
        h4 rv = *(const h4*)(resh + (size_t)n * 256 + lane * 4);
        acc.x += (float)rv[0]; acc.y += (float)rv[1];
        acc.z += (float)rv[2]; acc.w += (float)rv[3];
    }
    acc.x = elu_fast(acc.x);
    acc.y = elu_fast(acc.y);
    acc.z = elu_fast(acc.z);
    acc.w = elu_fast(acc.w);
    h4 o;
    o[0] = (_Float16)acc.x; o[1] = (_Float16)acc.y;
    o[2] = (_Float16)acc.z; o[3] = (_Float16)acc.w;
    *(h4*)(outh + (size_t)n * 256 + lane * 4) = o;
}

// ---------------- fused GAT layer 2 (H=1, C=16): one wave per node; cpack fp16 ----------------

__global__ __launch_bounds__(256) void gat_fused1(const int* __restrict__ rowstart,
                                                  const int* __restrict__ pk,
                                                  const float* __restrict__ el,
                                                  const float* __restrict__ er,
                                                  const float* __restrict__ es,
                                                  const _Float16* __restrict__ cpack,
                                                  float* __restrict__ out, int nN) {
    const int wave = threadIdx.x >> 6;
    const int lane = threadIdx.x & 63;
    int n = blockIdx.x * 4 + wave;
    if (n >= nN) return;
    const int r0 = rowstart[n], r1 = rowstart[n + 1];
    const int deg = r1 - r0;
    const float ern = er[n];

    if (deg <= 64) {
        const int idx = r0 + lane;
        const bool act = idx < r1;
        int p = act ? pk[idx] : 0;
        int psrc = p & 0xFFFF;
        float v = -INFINITY;
        if (act) {
            float t = el[psrc] + ern + es[p >> 16];
            v = t > 0.f ? t : SLOPE * t;
        }
        float m = v;
        #pragma unroll
        for (int off = 1; off <= 8; off <<= 1) m = fmaxf(m, __shfl_xor(m, off));
        if (deg > 16) m = fmaxf(m, __shfl_xor(m, 16));
        if (deg > 32) m = fmaxf(m, __shfl_xor(m, 32));
        float ex = act ? __expf(v - m) : 0.f;
        float s = ex;
        #pragma unroll
        for (int off = 1; off <= 8; off <<= 1) s += __shfl_xor(s, off);
        if (deg > 16) s += __shfl_xor(s, 16);
        if (deg > 32) s += __shfl_xor(s, 32);
        float a = ex / (s + 1e-9f);

        const int eslot = lane >> 4, fl = lane & 15;
        float acc = 0.f;
        int i = r0;
        for (; i + 7 < r1; i += 8) {
            int j0 = (i - r0) + eslot;
            int j1 = j0 + 4;
            int s0 = __shfl(psrc, j0);
            int s1 = __shfl(psrc, j1);
            float a0 = __shfl(a, j0);
            float a1 = __shfl(a, j1);
            float f0 = (float)cpack[(size_t)s0 * 32 + fl];
            float f1 = (float)cpack[(size_t)s1 * 32 + fl];
            acc = fmaf(a0, f0, acc);
            acc = fmaf(a1, f1, acc);
        }
        for (; i + 3 < r1; i += 4) {
            int j = (i - r0) + eslot;
            int sj = __shfl(psrc, j);
            float aj = __shfl(a, j);
            acc = fmaf(aj, (float)cpack[(size_t)sj * 32 + fl], acc);
        }
        int rem = r1 - i;
        if (rem > 0) {   // wave-uniform branch: full exec for the shfls below
            int j = (i - r0) + (eslot < rem ? eslot : rem - 1);
            int sj = __shfl(psrc, j);
            float aj = __shfl(a, j);
            if (eslot >= rem) aj = 0.f;
            acc = fmaf(aj, (float)cpack[(size_t)sj * 32 + fl], acc);
        }
        acc += __shfl_xor(acc, 16);
        acc += __shfl_xor(acc, 32);
        if (lane < 16) out[(size_t)n * 16 + lane] = acc + (float)cpack[(size_t)n * 32 + 16 + lane];
        return;
    }

    // fallback deg > 64 (rare)
    float m = -INFINITY;
    for (int base = r0; base < r1; base += 64) {
        int idx = base + lane;
        if (idx < r1) {
            int p = pk[idx];
            float v = el[p & 0xFFFF] + ern + es[p >> 16];
            v = v > 0.f ? v : SLOPE * v;
            m = fmaxf(m, v);
        }
    }
    #pragma unroll
    for (int off = 1; off < 64; off <<= 1) m = fmaxf(m, __shfl_xor(m, off));
    float s = 0.f;
    for (int base = r0; base < r1; base += 64) {
        int idx = base + lane;
        if (idx < r1) {
            int p = pk[idx];
            float v = el[p & 0xFFFF] + ern + es[p >> 16];
            v = v > 0.f ? v : SLOPE * v;
            s += __expf(v - m);
        }
    }
    #pragma unroll
    for (int off = 1; off < 64; off <<= 1) s += __shfl_xor(s, off);
    float inv = 1.f / (s + 1e-9f);
    const int eslot = lane >> 4, fl = lane & 15;
    float acc = 0.f;
    for (int i = r0; i < r1; i += 4) {
        int rem = r1 - i;
        if (eslot < rem) {
            int j = i + eslot;
            int p = pk[j];
            float v = el[p & 0xFFFF] + ern + es[p >> 16];
            v = v > 0.f ? v : SLOPE * v;
            float a = __expf(v - m) * inv;
            acc = fmaf(a, (float)cpack[(size_t)(p & 0xFFFF) * 32 + fl], acc);
        }
    }
    acc += __shfl_xor(acc, 16);
    acc += __shfl_xor(acc, 32);
    if (lane < 16) out[(size_t)n * 16 + lane] = acc + (float)cpack[(size_t)n * 32 + 16 + lane];
}

// ---------------- host ----------------

extern "C" void kernel_launch(void* const* d_in, const int* in_sizes, int n_in,
                              void* d_out, int out_size, void* d_ws, size_t ws_size,
                              hipStream_t stream) {
    const float* x0 = (const float*)d_in[0];
    const float* x1 = (const float*)d_in[1];
    const float* x2 = (const float*)d_in[2];
    const int* src  = (const int*)d_in[3];
    const int* dst  = (const int*)d_in[4];
    const int* et   = (const int*)d_in[5];
    const float* W0 = (const float*)d_in[6];  const float* b0 = (const float*)d_in[7];
    const float* W1 = (const float*)d_in[8];  const float* b1 = (const float*)d_in[9];
    const float* W2 = (const float*)d_in[10]; const float* b2 = (const float*)d_in[11];
    const float* Wg0 = (const float*)d_in[12]; const float* etab0 = (const float*)d_in[13];
    const float* We0 = (const float*)d_in[14]; const float* al0 = (const float*)d_in[15];
    const float* ar0 = (const float*)d_in[16]; const float* ae0 = (const float*)d_in[17];
    const float* Wg1 = (const float*)d_in[18]; const float* etab1 = (const float*)d_in[19];
    const float* We1 = (const float*)d_in[20]; const float* al1 = (const float*)d_in[21];
    const float* ar1 = (const float*)d_in[22]; const float* ae1 = (const float*)d_in[23];
    const float* Wg2 = (const float*)d_in[24]; const float* etab2 = (const float*)d_in[25];
    const float* We2 = (const float*)d_in[26]; const float* al2 = (const float*)d_in[27];
    const float* ar2 = (const float*)d_in[28]; const float* ae2 = (const float*)d_in[29];
    const float* resW2 = (const float*)d_in[30];
    float* outp = (float*)d_out;

    char* p = (char*)d_ws;
    auto alloc = [&](size_t bytes) -> void* {
        void* r = (void*)p;
        p += (bytes + 255) & ~(size_t)255;
        return r;
    };
    _Float16* x0h   = (_Float16*)alloc((size_t)N0 * 128 * 2);
    _Float16* x1h   = (_Float16*)alloc((size_t)N1 * 64 * 2);
    _Float16* x2h   = (_Float16*)alloc((size_t)N2 * 32 * 2);
    _Float16* W0h   = (_Float16*)alloc(64 * 128 * 2);
    _Float16* W1h   = (_Float16*)alloc(64 * 64 * 2);
    _Float16* W2h   = (_Float16*)alloc(64 * 32 * 2);
    _Float16* Wg0h  = (_Float16*)alloc(256 * 64 * 2);
    _Float16* Wg1h  = (_Float16*)alloc(256 * 256 * 2);
    _Float16* wpkh  = (_Float16*)alloc(32 * 256 * 2);
    _Float16* h0h   = (_Float16*)alloc((size_t)NN * 64 * 2);
    _Float16* feath = (_Float16*)alloc((size_t)NN * 256 * 2);
    _Float16* bufAh = (_Float16*)alloc((size_t)NN * 256 * 2);
    _Float16* bufBh = (_Float16*)alloc((size_t)NN * 256 * 2);
    _Float16* a0h   = (_Float16*)alloc((size_t)EE * 4 * 2);
    _Float16* cpackh = (_Float16*)alloc((size_t)NN * 32 * 2);
    float* el    = (float*)alloc((size_t)NN * 4 * 4);
    float* er    = (float*)alloc((size_t)NN * 4 * 4);
    float* es    = (float*)alloc(96 * 4);
    int* rowstart = (int*)alloc((size_t)(NN + 1) * 4);
    int* deg      = (int*)alloc((size_t)NN * 4);
    int* cursor   = (int*)alloc((size_t)NN * 4);
    int* bsum     = (int*)alloc(256 * 4);
    int* pk       = (int*)alloc((size_t)EE * 4);

    const int EB = (EE + 255) / 256;        // 3125
    const int NB = (NN + 255) / 256;        // 196
    const int MB128 = (NN + 127) / 128;     // 391
    const int WB = (NN + 3) / 4;            // 12500
    const int nb0 = (N0 + 127) / 128;       // 157
    const int nb1 = (N1 + 127) / 128;       // 118
    const int nb2 = (N2 + 127) / 128;       // 118

    hipMemsetAsync(deg, 0, (size_t)NN * 4, stream);

    // K1: hist || es tables || fp32->fp16 converts (vectorized x4)
    {
        int n0c = N0 * 128, n1c = N1 * 64, n2c = N2 * 32;
        int total4 = (n0c + n1c + n2c + 8192 + 4096 + 2048 + 16384 + 65536 + 4096 + 4096) / 4;
        int cvb = (total4 + 255) / 256;
        k1_hist_prep<<<EB + 18 + cvb, 256, 0, stream>>>(
            dst, deg,
            etab0, We0, ae0, etab1, We1, ae1, etab2, We2, ae2, es,
            x0, x0h, n0c, x1, x1h, n1c, x2, x2h, n2c,
            W0, W0h, 8192, W1, W1h, 4096, W2, W2h, 2048,
            Wg0, Wg0h, 16384, Wg1, Wg1h, 65536,
            Wg2, wpkh, 4096, resW2, wpkh + 4096, 4096, EB);
    }

    // K2: block_sum || input projections
    k2_bsum_proj<<<NB + nb0 + nb1 + nb2, 256, 0, stream>>>(
        deg, bsum, NB, x0h, W0h, b0, x1h, W1h, b1, x2h, W2h, b2, h0h, nb0, nb1);

    // K3: scan (rowstart + cursor)
    scan_out2<<<NB, 256, 0, stream>>>(deg, bsum, rowstart, cursor, NN, NB);

    // K4: scatter || layer-0 GEMM + fused el/er
    k4_scat_gemm0<<<EB + MB128 * 2, 256, 0, stream>>>(
        src, dst, et, cursor, pk, EB,
        h0h, Wg0h, feath, el, er, al0, ar0, MB128);

    // ---- GAT layer 0 edge stage ----
    gat_fused4<true, false, false><<<WB, 256, 0, stream>>>(
        rowstart, pk, el, er, es + 0, feath, nullptr, a0h, nullptr, bufAh, NN);

    // ---- GAT layer 1 ----
    gemm_mfma<8, 1><<<dim3(MB128, 2), 256, 0, stream>>>(bufAh, Wg1h, nullptr, nullptr, feath,
                                                        el, er, al1, ar1, NN, 256, 256);
    gat_fused4<false, true, true><<<WB, 256, 0, stream>>>(
        rowstart, pk, el, er, es + 32, feath, a0h, nullptr, bufAh, bufBh, NN);

    // ---- GAT layer 2 (H=1, C=16, linear residual, no act) ----
    gemm_mfma<2, 2><<<dim3(MB128, 1), 256, 0, stream>>>(bufBh, wpkh, nullptr, nullptr, cpackh,
                                                        el, er, al2, ar2, NN, 32, 256);
    gat_fused1<<<WB, 256, 0, stream>>>(rowstart, pk, el, er, es + 64, cpackh, outp, NN);
}

// Round 12
// 447.864 us; speedup vs baseline: 1.1778x; 1.0373x over previous
//
#include <hip/hip_runtime.h>
#include <math.h>

#define N0 20000
#define N1 15000
#define N2 15000
#define NN 50000          // total nodes
#define EE 800000         // edges
#define SLOPE 0.2f
#define ALPHA 0.05f
#define NODES_PER_G 6250  // NN/8
#define HSLICE 64         // slices per group for partitioned hist/scatter
#define ECHUNK 12500      // EE/HSLICE

typedef _Float16 h8 __attribute__((ext_vector_type(8)));
typedef _Float16 h4 __attribute__((ext_vector_type(4)));
typedef float f4v __attribute__((ext_vector_type(4)));

__device__ __forceinline__ float sel4(float4 v, int h) {
    float lo = (h & 1) ? v.y : v.x;
    float hi = (h & 1) ? v.w : v.z;
    return (h & 2) ? hi : lo;
}

__device__ __forceinline__ float elu_fast(float x) {
    return x > 0.f ? x : __expf(x) - 1.f;
}

// ---------------- es table pair ----------------

__device__ __forceinline__ void es_pair(int p,
                                        const float* __restrict__ etab0, const float* __restrict__ We0, const float* __restrict__ ae0,
                                        const float* __restrict__ etab1, const float* __restrict__ We1, const float* __restrict__ ae1,
                                        const float* __restrict__ etab2, const float* __restrict__ We2, const float* __restrict__ ae2,
                                        float* __restrict__ es) {
    const float *etab, *We, *ae;
    float* out;
    int H;
    if (p < 32)      { etab = etab0; We = We0; ae = ae0; out = es;      H = 4; }
    else if (p < 64) { p -= 32; etab = etab1; We = We1; ae = ae1; out = es + 32; H = 4; }
    else             { p -= 64; etab = etab2; We = We2; ae = ae2; out = es + 64; H = 1; }
    int t = p / H, h = p % H;
    int j = threadIdx.x & 63;
    const float* w = We + (size_t)(h * 64 + j) * 64;
    const float* e = etab + t * 64;
    float s = 0.f;
    #pragma unroll
    for (int k = 0; k < 64; k += 4) {
        float4 wv = *(const float4*)(w + k);
        float4 ev = *(const float4*)(e + k);
        s += wv.x * ev.x + wv.y * ev.y + wv.z * ev.z + wv.w * ev.w;
    }
    s *= ae[h * 64 + j];
    #pragma unroll
    for (int off = 32; off > 0; off >>= 1) s += __shfl_down(s, off);
    if (j == 0) out[t * H + h] = s;
}

__device__ __forceinline__ void cvt4(const float* __restrict__ s, _Float16* __restrict__ d, int t) {
    float4 v = ((const float4*)s)[t];
    h4 o;
    o[0] = (_Float16)v.x; o[1] = (_Float16)v.y;
    o[2] = (_Float16)v.z; o[3] = (_Float16)v.w;
    ((h4*)d)[t] = o;
}

// ---------------- K1: XCD-partitioned hist (512 blocks) || es tables || converts ----------------
// group = b & 7 -> XCD via round-robin dispatch heuristic; each group owns a dst range,
// so deg lines are written by one XCD's blocks only (no cross-XCD line bouncing).

__global__ __launch_bounds__(256) void k1_hist_prep(
        const int* __restrict__ dst, int* __restrict__ deg,
        const float* etab0, const float* We0, const float* ae0,
        const float* etab1, const float* We1, const float* ae1,
        const float* etab2, const float* We2, const float* ae2,
        float* es,
        const float* s0, _Float16* d0, int n0,
        const float* s1, _Float16* d1, int n1,
        const float* s2, _Float16* d2, int n2,
        const float* s3, _Float16* d3, int n3,
        const float* s4, _Float16* d4, int n4,
        const float* s5, _Float16* d5, int n5,
        const float* s6, _Float16* d6, int n6,
        const float* s7, _Float16* d7, int n7,
        const float* s8, _Float16* d8, int n8,
        const float* s9, _Float16* d9, int n9) {
    int b = blockIdx.x;
    if (b < 8 * HSLICE) {
        int g = b & 7, sl = b >> 3;
        int lo = g * NODES_PER_G, hi = lo + NODES_PER_G;
        int e0 = sl * ECHUNK, e1 = e0 + ECHUNK;
        for (int e = e0 + threadIdx.x; e < e1; e += 256) {
            int d = dst[e];
            if (d >= lo && d < hi) atomicAdd(&deg[d], 1);
        }
        return;
    }
    b -= 8 * HSLICE;
    if (b < 18) {
        int p = b * 4 + (threadIdx.x >> 6);
        if (p < 72) es_pair(p, etab0, We0, ae0, etab1, We1, ae1, etab2, We2, ae2, es);
        return;
    }
    int t = (b - 18) * 256 + threadIdx.x;   // vector-of-4 index
    if (t < (n0 >> 2)) { cvt4(s0, d0, t); return; } t -= n0 >> 2;
    if (t < (n1 >> 2)) { cvt4(s1, d1, t); return; } t -= n1 >> 2;
    if (t < (n2 >> 2)) { cvt4(s2, d2, t); return; } t -= n2 >> 2;
    if (t < (n3 >> 2)) { cvt4(s3, d3, t); return; } t -= n3 >> 2;
    if (t < (n4 >> 2)) { cvt4(s4, d4, t); return; } t -= n4 >> 2;
    if (t < (n5 >> 2)) { cvt4(s5, d5, t); return; } t -= n5 >> 2;
    if (t < (n6 >> 2)) { cvt4(s6, d6, t); return; } t -= n6 >> 2;
    if (t < (n7 >> 2)) { cvt4(s7, d7, t); return; } t -= n7 >> 2;
    if (t < (n8 >> 2)) { cvt4(s8, d8, t); return; } t -= n8 >> 2;
    if (t < (n9 >> 2)) { cvt4(s9, d9, t); }
}

// ---------------- scan pieces ----------------

__device__ __forceinline__ void block_sum_body(int b, const int* __restrict__ deg,
                                               int* __restrict__ bsum, int n) {
    int i = b * 256 + threadIdx.x;
    int v = (i < n) ? deg[i] : 0;
    #pragma unroll
    for (int off = 32; off > 0; off >>= 1) v += __shfl_down(v, off);
    __shared__ int sh[4];
    if ((threadIdx.x & 63) == 0) sh[threadIdx.x >> 6] = v;
    __syncthreads();
    if (threadIdx.x == 0) bsum[b] = sh[0] + sh[1] + sh[2] + sh[3];
}

__global__ __launch_bounds__(256) void scan_out2(const int* __restrict__ deg,
                                                 const int* __restrict__ bsum,
                                                 int* __restrict__ rowstart,
                                                 int* __restrict__ cursor, int n, int nb) {
    __shared__ int sb[256];
    __shared__ int boff_s;
    int tid = threadIdx.x;
    int v = (tid < nb) ? bsum[tid] : 0;
    sb[tid] = v;
    __syncthreads();
    #pragma unroll
    for (int off = 1; off < 256; off <<= 1) {
        int t = (tid >= off) ? sb[tid - off] : 0;
        __syncthreads();
        sb[tid] += t;
        __syncthreads();
    }
    if (tid == blockIdx.x) boff_s = sb[tid] - v;
    __syncthreads();
    int boff = boff_s;
    int i = blockIdx.x * 256 + tid;
    int d = (i < n) ? deg[i] : 0;
    __syncthreads();
    sb[tid] = d;
    __syncthreads();
    #pragma unroll
    for (int off = 1; off < 256; off <<= 1) {
        int t = (tid >= off) ? sb[tid - off] : 0;
        __syncthreads();
        sb[tid] += t;
        __syncthreads();
    }
    int excl = sb[tid] - d + boff;
    if (i < n) { rowstart[i] = excl; cursor[i] = excl; }
    if (i == n - 1) rowstart[n] = excl + d;
}

// ---------------- MFMA fp16 GEMM body (verified fragment mapping) ----------------
// ELR: 0 none; 1 fused el/er (H=4/D=64, y-block = 2 heads); 2 fused el/er (H=1,D=16).

template<int NT, int ELR>
__device__ __forceinline__ void gemm_body(int bx, int by,
                                          const _Float16* __restrict__ A,
                                          const _Float16* __restrict__ B,
                                          const float* __restrict__ bias,
                                          float* __restrict__ Cf,
                                          _Float16* __restrict__ Ch,
                                          float* __restrict__ el,
                                          float* __restrict__ er,
                                          const float* __restrict__ al,
                                          const float* __restrict__ ar,
                                          int M, int N, int K) {
    const int wave = threadIdx.x >> 6;
    const int lane = threadIdx.x & 63;
    const int m_base = (bx * 4 + wave) * 32;
    const int n_base = by * (NT * 16);
    const int row = lane & 15;
    const int kq = (lane >> 4) * 8;

    f4v acc[2][NT];
    #pragma unroll
    for (int i = 0; i < 2; i++)
        #pragma unroll
        for (int j = 0; j < NT; j++) {
            f4v z = {0.f, 0.f, 0.f, 0.f};
            acc[i][j] = z;
        }

    int ra = m_base + row;       if (ra >= M) ra = M - 1;
    int rb2 = m_base + 16 + row; if (rb2 >= M) rb2 = M - 1;
    const _Float16* a0p = A + (size_t)ra * K + kq;
    const _Float16* a1p = A + (size_t)rb2 * K + kq;
    const _Float16* bp  = B + (size_t)(n_base + row) * K + kq;

    for (int k = 0; k < K; k += 32) {
        h8 a0 = *(const h8*)(a0p + k);
        h8 a1 = *(const h8*)(a1p + k);
        #pragma unroll
        for (int j = 0; j < NT; j++) {
            h8 b = *(const h8*)(bp + (size_t)j * 16 * K + k);
            acc[0][j] = __builtin_amdgcn_mfma_f32_16x16x32_f16(a0, b, acc[0][j], 0, 0, 0);
            acc[1][j] = __builtin_amdgcn_mfma_f32_16x16x32_f16(a1, b, acc[1][j], 0, 0, 0);
        }
    }

    const int col = lane & 15;
    const int rb = (lane >> 4) * 4;

    if (ELR == 1) {
        float alw[NT], arw[NT];
        #pragma unroll
        for (int j = 0; j < NT; j++) {
            int cg = n_base + j * 16 + col;
            int hg = cg >> 6, d = cg & 63;
            alw[j] = al[hg * 64 + d];
            arw[j] = ar[hg * 64 + d];
        }
        const int hb = n_base >> 6;
        #pragma unroll
        for (int ms = 0; ms < 2; ms++) {
            #pragma unroll
            for (int r = 0; r < 4; r++) {
                float e0 = 0.f, e1 = 0.f, f0 = 0.f, f1 = 0.f;
                #pragma unroll
                for (int j = 0; j < NT; j++) {
                    float av = acc[ms][j][r];
                    if (j < NT / 2) { e0 = fmaf(av, alw[j], e0); f0 = fmaf(av, arw[j], f0); }
                    else            { e1 = fmaf(av, alw[j], e1); f1 = fmaf(av, arw[j], f1); }
                }
                #pragma unroll
                for (int off = 1; off <= 8; off <<= 1) {
                    e0 += __shfl_xor(e0, off);
                    e1 += __shfl_xor(e1, off);
                    f0 += __shfl_xor(f0, off);
                    f1 += __shfl_xor(f1, off);
                }
                int m = m_base + ms * 16 + rb + r;
                if (col == 0 && m < M) {
                    el[m * 4 + hb]     = e0;
                    el[m * 4 + hb + 1] = e1;
                    er[m * 4 + hb]     = f0;
                    er[m * 4 + hb + 1] = f1;
                }
            }
        }
    }
    if (ELR == 2) {
        float alw = al[col], arw = ar[col];
        #pragma unroll
        for (int ms = 0; ms < 2; ms++) {
            #pragma unroll
            for (int r = 0; r < 4; r++) {
                float e = acc[ms][0][r] * alw;
                float f = acc[ms][0][r] * arw;
                #pragma unroll
                for (int off = 1; off <= 8; off <<= 1) {
                    e += __shfl_xor(e, off);
                    f += __shfl_xor(f, off);
                }
                int m = m_base + ms * 16 + rb + r;
                if (col == 0 && m < M) { el[m] = e; er[m] = f; }
            }
        }
    }

    #pragma unroll
    for (int ms = 0; ms < 2; ms++) {
        #pragma unroll
        for (int j = 0; j < NT; j++) {
            #pragma unroll
            for (int r = 0; r < 4; r++) {
                int m = m_base + ms * 16 + rb + r;
                if (m < M) {
                    int n = n_base + j * 16 + col;
                    float v = acc[ms][j][r];
                    if (bias) v += bias[n];
                    if (Cf) Cf[(size_t)m * N + n] = v;
                    if (Ch) Ch[(size_t)m * N + n] = (_Float16)v;
                }
            }
        }
    }
}

template<int NT, int ELR>
__global__ __launch_bounds__(256) void gemm_mfma(const _Float16* __restrict__ A,
                                                 const _Float16* __restrict__ B,
                                                 const float* __restrict__ bias,
                                                 float* __restrict__ Cf,
                                                 _Float16* __restrict__ Ch,
                                                 float* __restrict__ el,
                                                 float* __restrict__ er,
                                                 const float* __restrict__ al,
                                                 const float* __restrict__ ar,
                                                 int M, int N, int K) {
    gemm_body<NT, ELR>(blockIdx.x, blockIdx.y, A, B, bias, Cf, Ch, el, er, al, ar, M, N, K);
}

// ---------------- K2: block_sum (blocks 0..NB-1) || proj3 ----------------

__global__ __launch_bounds__(256) void k2_bsum_proj(
        const int* __restrict__ deg, int* __restrict__ bsum, int NBv,
        const _Float16* __restrict__ x0h, const _Float16* __restrict__ W0h, const float* __restrict__ b0,
        const _Float16* __restrict__ x1h, const _Float16* __restrict__ W1h, const float* __restrict__ b1,
        const _Float16* __restrict__ x2h, const _Float16* __restrict__ W2h, const float* __restrict__ b2,
        _Float16* __restrict__ h0h, int nb0, int nb1) {
    int b = blockIdx.x;
    if (b < NBv) { block_sum_body(b, deg, bsum, NN); return; }
    b -= NBv;
    if (b < nb0) {
        gemm_body<4, 0>(b, 0, x0h, W0h, b0, nullptr, h0h,
                        nullptr, nullptr, nullptr, nullptr, N0, 64, 128);
    } else if (b < nb0 + nb1) {
        gemm_body<4, 0>(b - nb0, 0, x1h, W1h, b1, nullptr, h0h + (size_t)N0 * 64,
                        nullptr, nullptr, nullptr, nullptr, N1, 64, 64);
    } else {
        gemm_body<4, 0>(b - nb0 - nb1, 0, x2h, W2h, b2, nullptr, h0h + (size_t)(N0 + N1) * 64,
                        nullptr, nullptr, nullptr, nullptr, N2, 64, 32);
    }
}

// ---------------- K4: XCD-partitioned scatter (512 blocks) || gemm0 + fused el/er ----------------
// Each group (b&7) scatters only its dst range: pk/cursor lines stay XCD-local.

__global__ __launch_bounds__(256) void k4_scat_gemm0(
        const int* __restrict__ src, const int* __restrict__ dst, const int* __restrict__ et,
        int* __restrict__ cursor, int* __restrict__ pk,
        const _Float16* __restrict__ h0h, const _Float16* __restrict__ Wg0h,
        _Float16* __restrict__ feath, float* __restrict__ el, float* __restrict__ er,
        const float* __restrict__ al0, const float* __restrict__ ar0, int MB) {
    int b = blockIdx.x;
    if (b < 8 * HSLICE) {
        int g = b & 7, sl = b >> 3;
        int lo = g * NODES_PER_G, hi = lo + NODES_PER_G;
        int e0 = sl * ECHUNK, e1 = e0 + ECHUNK;
        for (int e = e0 + threadIdx.x; e < e1; e += 256) {
            int d = dst[e];
            if (d >= lo && d < hi) {
                int p = atomicAdd(&cursor[d], 1);
                pk[p] = (et[e] << 16) | src[e];
            }
        }
        return;
    }
    int t = b - 8 * HSLICE;
    int bx = t % MB, by = t / MB;
    gemm_body<8, 1>(bx, by, h0h, Wg0h, nullptr, nullptr, feath, el, er, al0, ar0, NN, 256, 64);
}

// ---------------- fused GAT edge stage, H=4 ----------------
// one wave per dst node; LDS [wave][h][66] conflict-free.
// All __shfl under wave-uniform control flow (round-5 lesson).

template<bool WRITE_A, bool HAS_PREV, bool HAS_RES>
__global__ __launch_bounds__(256) void gat_fused4(const int* __restrict__ rowstart,
                                                  const int* __restrict__ pk,
                                                  const float* __restrict__ el,
                                                  const float* __restrict__ er,
                                                  const float* __restrict__ es,
                                                  const _Float16* __restrict__ feat,
                                                  const _Float16* __restrict__ aprev,
                                                  _Float16* __restrict__ awrite,
                                                  const _Float16* __restrict__ resh,
                                                  _Float16* __restrict__ outh, int nN) {
    __shared__ int2 as_lds[4][4][66];   // [wave][h][edge] = {f32 bits of a, src}
    const int wave = threadIdx.x >> 6;
    const int lane = threadIdx.x & 63;
    int n = blockIdx.x * 4 + wave;
    if (n >= nN) return;
    const int r0 = rowstart[n], r1 = rowstart[n + 1];
    const int deg = r1 - r0;
    float4 er4 = *(const float4*)(er + n * 4);

    if (deg <= 64) {
        // ---- phase A: one edge per lane, in-register softmax ----
        const int idx = r0 + lane;
        const bool act = idx < r1;
        int p = act ? pk[idx] : 0;
        int psrc = p & 0xFFFF;
        float4 v4 = {-INFINITY, -INFINITY, -INFINITY, -INFINITY};
        if (act) {
            float4 e4 = *(const float4*)(el + psrc * 4);
            float4 c4 = *(const float4*)(es + (p >> 16) * 4);
            float v;
            v = e4.x + er4.x + c4.x; v4.x = v > 0.f ? v : SLOPE * v;
            v = e4.y + er4.y + c4.y; v4.y = v > 0.f ? v : SLOPE * v;
            v = e4.z + er4.z + c4.z; v4.z = v > 0.f ? v : SLOPE * v;
            v = e4.w + er4.w + c4.w; v4.w = v > 0.f ? v : SLOPE * v;
        }
        float4 m4 = v4;
        #pragma unroll
        for (int off = 1; off <= 8; off <<= 1) {
            m4.x = fmaxf(m4.x, __shfl_xor(m4.x, off));
            m4.y = fmaxf(m4.y, __shfl_xor(m4.y, off));
            m4.z = fmaxf(m4.z, __shfl_xor(m4.z, off));
            m4.w = fmaxf(m4.w, __shfl_xor(m4.w, off));
        }
        if (deg > 16) {
            m4.x = fmaxf(m4.x, __shfl_xor(m4.x, 16));
            m4.y = fmaxf(m4.y, __shfl_xor(m4.y, 16));
            m4.z = fmaxf(m4.z, __shfl_xor(m4.z, 16));
            m4.w = fmaxf(m4.w, __shfl_xor(m4.w, 16));
        }
        if (deg > 32) {
            m4.x = fmaxf(m4.x, __shfl_xor(m4.x, 32));
            m4.y = fmaxf(m4.y, __shfl_xor(m4.y, 32));
            m4.z = fmaxf(m4.z, __shfl_xor(m4.z, 32));
            m4.w = fmaxf(m4.w, __shfl_xor(m4.w, 32));
        }
        float4 ex = {0.f, 0.f, 0.f, 0.f};
        if (act) {
            ex.x = __expf(v4.x - m4.x);
            ex.y = __expf(v4.y - m4.y);
            ex.z = __expf(v4.z - m4.z);
            ex.w = __expf(v4.w - m4.w);
        }
        float4 s4 = ex;
        #pragma unroll
        for (int off = 1; off <= 8; off <<= 1) {
            s4.x += __shfl_xor(s4.x, off);
            s4.y += __shfl_xor(s4.y, off);
            s4.z += __shfl_xor(s4.z, off);
            s4.w += __shfl_xor(s4.w, off);
        }
        if (deg > 16) {
            s4.x += __shfl_xor(s4.x, 16);
            s4.y += __shfl_xor(s4.y, 16);
            s4.z += __shfl_xor(s4.z, 16);
            s4.w += __shfl_xor(s4.w, 16);
        }
        if (deg > 32) {
            s4.x += __shfl_xor(s4.x, 32);
            s4.y += __shfl_xor(s4.y, 32);
            s4.z += __shfl_xor(s4.z, 32);
            s4.w += __shfl_xor(s4.w, 32);
        }
        float4 a4;
        a4.x = ex.x / (s4.x + 1e-9f);
        a4.y = ex.y / (s4.y + 1e-9f);
        a4.z = ex.z / (s4.z + 1e-9f);
        a4.w = ex.w / (s4.w + 1e-9f);
        if (HAS_PREV && act) {
            h4 pv = *(const h4*)(aprev + (size_t)idx * 4);
            a4.x = a4.x * (1.f - ALPHA) + ALPHA * (float)pv[0];
            a4.y = a4.y * (1.f - ALPHA) + ALPHA * (float)pv[1];
            a4.z = a4.z * (1.f - ALPHA) + ALPHA * (float)pv[2];
            a4.w = a4.w * (1.f - ALPHA) + ALPHA * (float)pv[3];
        }
        if (WRITE_A && act) {
            h4 aw;
            aw[0] = (_Float16)a4.x; aw[1] = (_Float16)a4.y;
            aw[2] = (_Float16)a4.z; aw[3] = (_Float16)a4.w;
            *(h4*)(awrite + (size_t)idx * 4) = aw;
        }
        as_lds[wave][0][lane] = make_int2(__float_as_int(a4.x), psrc);
        as_lds[wave][1][lane] = make_int2(__float_as_int(a4.y), psrc);
        as_lds[wave][2][lane] = make_int2(__float_as_int(a4.z), psrc);
        as_lds[wave][3][lane] = make_int2(__float_as_int(a4.w), psrc);

        // ---- phase B: 2 edge-slots x 32 feature-chunks, unroll-4 ----
        const int half = lane >> 5;
        const int fl = lane & 31;
        const int h = fl >> 3;
        float acc8[8];
        #pragma unroll
        for (int q = 0; q < 8; q++) acc8[q] = 0.f;
        int i = r0;
        for (; i + 7 < r1; i += 8) {
            int j0 = (i - r0) + half;
            int2 e0 = as_lds[wave][h][j0 + 0];
            int2 e1 = as_lds[wave][h][j0 + 2];
            int2 e2 = as_lds[wave][h][j0 + 4];
            int2 e3 = as_lds[wave][h][j0 + 6];
            float a0 = __int_as_float(e0.x), a1 = __int_as_float(e1.x);
            float a2 = __int_as_float(e2.x), a3 = __int_as_float(e3.x);
            h8 f0 = *(const h8*)(feat + (size_t)e0.y * 256 + fl * 8);
            h8 f1 = *(const h8*)(feat + (size_t)e1.y * 256 + fl * 8);
            h8 f2 = *(const h8*)(feat + (size_t)e2.y * 256 + fl * 8);
            h8 f3 = *(const h8*)(feat + (size_t)e3.y * 256 + fl * 8);
            #pragma unroll
            for (int q = 0; q < 8; q++) acc8[q] = fmaf(a0, (float)f0[q], acc8[q]);
            #pragma unroll
            for (int q = 0; q < 8; q++) acc8[q] = fmaf(a1, (float)f1[q], acc8[q]);
            #pragma unroll
            for (int q = 0; q < 8; q++) acc8[q] = fmaf(a2, (float)f2[q], acc8[q]);
            #pragma unroll
            for (int q = 0; q < 8; q++) acc8[q] = fmaf(a3, (float)f3[q], acc8[q]);
        }
        for (; i + 3 < r1; i += 4) {
            int j0 = (i - r0) + half;
            int2 e0 = as_lds[wave][h][j0 + 0];
            int2 e1 = as_lds[wave][h][j0 + 2];
            float a0 = __int_as_float(e0.x), a1 = __int_as_float(e1.x);
            h8 f0 = *(const h8*)(feat + (size_t)e0.y * 256 + fl * 8);
            h8 f1 = *(const h8*)(feat + (size_t)e1.y * 256 + fl * 8);
            #pragma unroll
            for (int q = 0; q < 8; q++) acc8[q] = fmaf(a0, (float)f0[q], acc8[q]);
            #pragma unroll
            for (int q = 0; q < 8; q++) acc8[q] = fmaf(a1, (float)f1[q], acc8[q]);
        }
        for (; i + 1 < r1; i += 2) {
            int j0 = (i - r0) + half;
            int2 e0 = as_lds[wave][h][j0];
            float a0 = __int_as_float(e0.x);
            h8 f0 = *(const h8*)(feat + (size_t)e0.y * 256 + fl * 8);
            #pragma unroll
            for (int q = 0; q < 8; q++) acc8[q] = fmaf(a0, (float)f0[q], acc8[q]);
        }
        if (i < r1) {
            int j0 = i - r0;
            int2 e0 = as_lds[wave][h][j0];
            float a0 = (half == 0) ? __int_as_float(e0.x) : 0.f;
            h8 f0 = *(const h8*)(feat + (size_t)e0.y * 256 + fl * 8);
            #pragma unroll
            for (int q = 0; q < 8; q++) acc8[q] = fmaf(a0, (float)f0[q], acc8[q]);
        }
        #pragma unroll
        for (int q = 0; q < 8; q++) acc8[q] += __shfl_xor(acc8[q], 32);

        if (half == 0) {
            if (HAS_RES) {
                h8 rv = *(const h8*)(resh + (size_t)n * 256 + fl * 8);
                #pragma unroll
                for (int q = 0; q < 8; q++) acc8[q] += (float)rv[q];
            }
            #pragma unroll
            for (int q = 0; q < 8; q++) acc8[q] = elu_fast(acc8[q]);
            h8 o;
            #pragma unroll
            for (int q = 0; q < 8; q++) o[q] = (_Float16)acc8[q];
            *(h8*)(outh + (size_t)n * 256 + fl * 8) = o;
        }
        return;
    }

    // ---------------- fallback: deg > 64 (two-pass, rare) ----------------
    float4 m4 = {-INFINITY, -INFINITY, -INFINITY, -INFINITY};
    for (int base = r0; base < r1; base += 64) {
        int idx = base + lane;
        if (idx < r1) {
            int p = pk[idx];
            float4 e4 = *(const float4*)(el + (p & 0xFFFF) * 4);
            float4 c4 = *(const float4*)(es + (p >> 16) * 4);
            float v;
            v = e4.x + er4.x + c4.x; v = v > 0.f ? v : SLOPE * v; m4.x = fmaxf(m4.x, v);
            v = e4.y + er4.y + c4.y; v = v > 0.f ? v : SLOPE * v; m4.y = fmaxf(m4.y, v);
            v = e4.z + er4.z + c4.z; v = v > 0.f ? v : SLOPE * v; m4.z = fmaxf(m4.z, v);
            v = e4.w + er4.w + c4.w; v = v > 0.f ? v : SLOPE * v; m4.w = fmaxf(m4.w, v);
        }
    }
    #pragma unroll
    for (int off = 1; off < 64; off <<= 1) {
        m4.x = fmaxf(m4.x, __shfl_xor(m4.x, off));
        m4.y = fmaxf(m4.y, __shfl_xor(m4.y, off));
        m4.z = fmaxf(m4.z, __shfl_xor(m4.z, off));
        m4.w = fmaxf(m4.w, __shfl_xor(m4.w, off));
    }
    float4 s4 = {0.f, 0.f, 0.f, 0.f};
    for (int base = r0; base < r1; base += 64) {
        int idx = base + lane;
        if (idx < r1) {
            int p = pk[idx];
            float4 e4 = *(const float4*)(el + (p & 0xFFFF) * 4);
            float4 c4 = *(const float4*)(es + (p >> 16) * 4);
            float4 exv;
            float v;
            v = e4.x + er4.x + c4.x; v = v > 0.f ? v : SLOPE * v; exv.x = __expf(v - m4.x);
            v = e4.y + er4.y + c4.y; v = v > 0.f ? v : SLOPE * v; exv.y = __expf(v - m4.y);
            v = e4.z + er4.z + c4.z; v = v > 0.f ? v : SLOPE * v; exv.z = __expf(v - m4.z);
            v = e4.w + er4.w + c4.w; v = v > 0.f ? v : SLOPE * v; exv.w = __expf(v - m4.w);
            if (base == r0) {
                as_lds[wave][0][lane] = make_int2(__float_as_int(exv.x), p & 0xFFFF);
                as_lds[wave][1][lane] = make_int2(__float_as_int(exv.y), p & 0xFFFF);
                as_lds[wave][2][lane] = make_int2(__float_as_int(exv.z), p & 0xFFFF);
                as_lds[wave][3][lane] = make_int2(__float_as_int(exv.w), p & 0xFFFF);
            }
            s4.x += exv.x; s4.y += exv.y; s4.z += exv.z; s4.w += exv.w;
        }
    }
    #pragma unroll
    for (int off = 1; off < 64; off <<= 1) {
        s4.x += __shfl_xor(s4.x, off);
        s4.y += __shfl_xor(s4.y, off);
        s4.z += __shfl_xor(s4.z, off);
        s4.w += __shfl_xor(s4.w, off);
    }
    float4 inv4;
    inv4.x = 1.f / (s4.x + 1e-9f); inv4.y = 1.f / (s4.y + 1e-9f);
    inv4.z = 1.f / (s4.z + 1e-9f); inv4.w = 1.f / (s4.w + 1e-9f);
    {
        int idx = r0 + lane;
        float4 a;
        a.x = __int_as_float(as_lds[wave][0][lane].x) * inv4.x;
        a.y = __int_as_float(as_lds[wave][1][lane].x) * inv4.y;
        a.z = __int_as_float(as_lds[wave][2][lane].x) * inv4.z;
        a.w = __int_as_float(as_lds[wave][3][lane].x) * inv4.w;
        if (HAS_PREV) {
            h4 pv = *(const h4*)(aprev + (size_t)idx * 4);
            a.x = a.x * (1.f - ALPHA) + ALPHA * (float)pv[0];
            a.y = a.y * (1.f - ALPHA) + ALPHA * (float)pv[1];
            a.z = a.z * (1.f - ALPHA) + ALPHA * (float)pv[2];
            a.w = a.w * (1.f - ALPHA) + ALPHA * (float)pv[3];
        }
        if (WRITE_A) {
            h4 aw;
            aw[0] = (_Float16)a.x; aw[1] = (_Float16)a.y;
            aw[2] = (_Float16)a.z; aw[3] = (_Float16)a.w;
            *(h4*)(awrite + (size_t)idx * 4) = aw;
        }
        as_lds[wave][0][lane].x = __float_as_int(a.x);
        as_lds[wave][1][lane].x = __float_as_int(a.y);
        as_lds[wave][2][lane].x = __float_as_int(a.z);
        as_lds[wave][3][lane].x = __float_as_int(a.w);
    }
    if (WRITE_A) {
        for (int base = r0 + 64; base < r1; base += 64) {
            int idx = base + lane;
            if (idx < r1) {
                int p = pk[idx];
                float4 e4 = *(const float4*)(el + (p & 0xFFFF) * 4);
                float4 c4 = *(const float4*)(es + (p >> 16) * 4);
                float4 a;
                float v;
                v = e4.x + er4.x + c4.x; v = v > 0.f ? v : SLOPE * v; a.x = __expf(v - m4.x) * inv4.x;
                v = e4.y + er4.y + c4.y; v = v > 0.f ? v : SLOPE * v; a.y = __expf(v - m4.y) * inv4.y;
                v = e4.z + er4.z + c4.z; v = v > 0.f ? v : SLOPE * v; a.z = __expf(v - m4.z) * inv4.z;
                v = e4.w + er4.w + c4.w; v = v > 0.f ? v : SLOPE * v; a.w = __expf(v - m4.w) * inv4.w;
                if (HAS_PREV) {
                    h4 pv = *(const h4*)(aprev + (size_t)idx * 4);
                    a.x = a.x * (1.f - ALPHA) + ALPHA * (float)pv[0];
                    a.y = a.y * (1.f - ALPHA) + ALPHA * (float)pv[1];
                    a.z = a.z * (1.f - ALPHA) + ALPHA * (float)pv[2];
                    a.w = a.w * (1.f - ALPHA) + ALPHA * (float)pv[3];
                }
                h4 aw;
                aw[0] = (_Float16)a.x; aw[1] = (_Float16)a.y;
                aw[2] = (_Float16)a.z; aw[3] = (_Float16)a.w;
                *(h4*)(awrite + (size_t)idx * 4) = aw;
            }
        }
    }
    const int h = lane >> 4;
    float4 acc = {0.f, 0.f, 0.f, 0.f};
    const int cap = r0 + 64;
    for (int i = r0; i < cap; i++) {
        int2 e0 = as_lds[wave][h][i - r0];
        h4 f = *(const h4*)(feat + (size_t)e0.y * 256 + lane * 4);
        float av = __int_as_float(e0.x);
        acc.x = fmaf(av, (float)f[0], acc.x);
        acc.y = fmaf(av, (float)f[1], acc.y);
        acc.z = fmaf(av, (float)f[2], acc.z);
        acc.w = fmaf(av, (float)f[3], acc.w);
    }
    {
        float mh = sel4(m4, h), invh = sel4(inv4, h), erh = sel4(er4, h);
        for (int i = cap; i < r1; i++) {
            int p = pk[i];
            int s = p & 0xFFFF, t = p >> 16;
            float v = el[s * 4 + h] + erh + es[t * 4 + h];
            v = v > 0.f ? v : SLOPE * v;
            float a = __expf(v - mh) * invh;
            if (HAS_PREV) a = a * (1.f - ALPHA) + ALPHA * (float)aprev[(size_t)i * 4 + h];
            h4 f = *(const h4*)(feat + (size_t)s * 256 + lane * 4);
            acc.x = fmaf(a, (float)f[0], acc.x);
            acc.y = fmaf(a, (float)f[1], acc.y);
            acc.z = fmaf(a, (float)f[2], acc.z);
            acc.w = fmaf(a, (float)f[3], acc.w);
        }
    }
    if (HAS_RES) {
        h4 rv = *(const h4*)(resh + (size_t)n * 256 + lane * 4);
        acc.x += (float)rv[0]; acc.y += (float)rv[1];
        acc.z += (float)rv[2]; acc.w += (float)rv[3];
    }
    acc.x = elu_fast(acc.x);
    acc.y = elu_fast(acc.y);
    acc.z = elu_fast(acc.z);
    acc.w = elu_fast(acc.w);
    h4 o;
    o[0] = (_Float16)acc.x; o[1] = (_Float16)acc.y;
    o[2] = (_Float16)acc.z; o[3] = (_Float16)acc.w;
    *(h4*)(outh + (size_t)n * 256 + lane * 4) = o;
}

// ---------------- fused GAT layer 2 (H=1, C=16): one wave per node; cpack fp16 ----------------

__global__ __launch_bounds__(256) void gat_fused1(const int* __restrict__ rowstart,
                                                  const int* __restrict__ pk,
                                                  const float* __restrict__ el,
                                                  const float* __restrict__ er,
                                                  const float* __restrict__ es,
                                                  const _Float16* __restrict__ cpack,
                                                  float* __restrict__ out, int nN) {
    const int wave = threadIdx.x >> 6;
    const int lane = threadIdx.x & 63;
    int n = blockIdx.x * 4 + wave;
    if (n >= nN) return;
    const int r0 = rowstart[n], r1 = rowstart[n + 1];
    const int deg = r1 - r0;
    const float ern = er[n];

    if (deg <= 64) {
        const int idx = r0 + lane;
        const bool act = idx < r1;
        int p = act ? pk[idx] : 0;
        int psrc = p & 0xFFFF;
        float v = -INFINITY;
        if (act) {
            float t = el[psrc] + ern + es[p >> 16];
            v = t > 0.f ? t : SLOPE * t;
        }
        float m = v;
        #pragma unroll
        for (int off = 1; off <= 8; off <<= 1) m = fmaxf(m, __shfl_xor(m, off));
        if (deg > 16) m = fmaxf(m, __shfl_xor(m, 16));
        if (deg > 32) m = fmaxf(m, __shfl_xor(m, 32));
        float ex = act ? __expf(v - m) : 0.f;
        float s = ex;
        #pragma unroll
        for (int off = 1; off <= 8; off <<= 1) s += __shfl_xor(s, off);
        if (deg > 16) s += __shfl_xor(s, 16);
        if (deg > 32) s += __shfl_xor(s, 32);
        float a = ex / (s + 1e-9f);

        const int eslot = lane >> 4, fl = lane & 15;
        float acc = 0.f;
        int i = r0;
        for (; i + 7 < r1; i += 8) {
            int j0 = (i - r0) + eslot;
            int j1 = j0 + 4;
            int s0 = __shfl(psrc, j0);
            int s1 = __shfl(psrc, j1);
            float a0 = __shfl(a, j0);
            float a1 = __shfl(a, j1);
            float f0 = (float)cpack[(size_t)s0 * 32 + fl];
            float f1 = (float)cpack[(size_t)s1 * 32 + fl];
            acc = fmaf(a0, f0, acc);
            acc = fmaf(a1, f1, acc);
        }
        for (; i + 3 < r1; i += 4) {
            int j = (i - r0) + eslot;
            int sj = __shfl(psrc, j);
            float aj = __shfl(a, j);
            acc = fmaf(aj, (float)cpack[(size_t)sj * 32 + fl], acc);
        }
        int rem = r1 - i;
        if (rem > 0) {   // wave-uniform branch: full exec for the shfls below
            int j = (i - r0) + (eslot < rem ? eslot : rem - 1);
            int sj = __shfl(psrc, j);
            float aj = __shfl(a, j);
            if (eslot >= rem) aj = 0.f;
            acc = fmaf(aj, (float)cpack[(size_t)sj * 32 + fl], acc);
        }
        acc += __shfl_xor(acc, 16);
        acc += __shfl_xor(acc, 32);
        if (lane < 16) out[(size_t)n * 16 + lane] = acc + (float)cpack[(size_t)n * 32 + 16 + lane];
        return;
    }

    // fallback deg > 64 (rare)
    float m = -INFINITY;
    for (int base = r0; base < r1; base += 64) {
        int idx = base + lane;
        if (idx < r1) {
            int p = pk[idx];
            float v = el[p & 0xFFFF] + ern + es[p >> 16];
            v = v > 0.f ? v : SLOPE * v;
            m = fmaxf(m, v);
        }
    }
    #pragma unroll
    for (int off = 1; off < 64; off <<= 1) m = fmaxf(m, __shfl_xor(m, off));
    float s = 0.f;
    for (int base = r0; base < r1; base += 64) {
        int idx = base + lane;
        if (idx < r1) {
            int p = pk[idx];
            float v = el[p & 0xFFFF] + ern + es[p >> 16];
            v = v > 0.f ? v : SLOPE * v;
            s += __expf(v - m);
        }
    }
    #pragma unroll
    for (int off = 1; off < 64; off <<= 1) s += __shfl_xor(s, off);
    float inv = 1.f / (s + 1e-9f);
    const int eslot = lane >> 4, fl = lane & 15;
    float acc = 0.f;
    for (int i = r0; i < r1; i += 4) {
        int rem = r1 - i;
        if (eslot < rem) {
            int j = i + eslot;
            int p = pk[j];
            float v = el[p & 0xFFFF] + ern + es[p >> 16];
            v = v > 0.f ? v : SLOPE * v;
            float a = __expf(v - m) * inv;
            acc = fmaf(a, (float)cpack[(size_t)(p & 0xFFFF) * 32 + fl], acc);
        }
    }
    acc += __shfl_xor(acc, 16);
    acc += __shfl_xor(acc, 32);
    if (lane < 16) out[(size_t)n * 16 + lane] = acc + (float)cpack[(size_t)n * 32 + 16 + lane];
}

// ---------------- host ----------------

extern "C" void kernel_launch(void* const* d_in, const int* in_sizes, int n_in,
                              void* d_out, int out_size, void* d_ws, size_t ws_size,
                              hipStream_t stream) {
    const float* x0 = (const float*)d_in[0];
    const float* x1 = (const float*)d_in[1];
    const float* x2 = (const float*)d_in[2];
    const int* src  = (const int*)d_in[3];
    const int* dst  = (const int*)d_in[4];
    const int* et   = (const int*)d_in[5];
    const float* W0 = (const float*)d_in[6];  const float* b0 = (const float*)d_in[7];
    const float* W1 = (const float*)d_in[8];  const float* b1 = (const float*)d_in[9];
    const float* W2 = (const float*)d_in[10]; const float* b2 = (const float*)d_in[11];
    const float* Wg0 = (const float*)d_in[12]; const float* etab0 = (const float*)d_in[13];
    const float* We0 = (const float*)d_in[14]; const float* al0 = (const float*)d_in[15];
    const float* ar0 = (const float*)d_in[16]; const float* ae0 = (const float*)d_in[17];
    const float* Wg1 = (const float*)d_in[18]; const float* etab1 = (const float*)d_in[19];
    const float* We1 = (const float*)d_in[20]; const float* al1 = (const float*)d_in[21];
    const float* ar1 = (const float*)d_in[22]; const float* ae1 = (const float*)d_in[23];
    const float* Wg2 = (const float*)d_in[24]; const float* etab2 = (const float*)d_in[25];
    const float* We2 = (const float*)d_in[26]; const float* al2 = (const float*)d_in[27];
    const float* ar2 = (const float*)d_in[28]; const float* ae2 = (const float*)d_in[29];
    const float* resW2 = (const float*)d_in[30];
    float* outp = (float*)d_out;

    char* p = (char*)d_ws;
    auto alloc = [&](size_t bytes) -> void* {
        void* r = (void*)p;
        p += (bytes + 255) & ~(size_t)255;
        return r;
    };
    _Float16* x0h   = (_Float16*)alloc((size_t)N0 * 128 * 2);
    _Float16* x1h   = (_Float16*)alloc((size_t)N1 * 64 * 2);
    _Float16* x2h   = (_Float16*)alloc((size_t)N2 * 32 * 2);
    _Float16* W0h   = (_Float16*)alloc(64 * 128 * 2);
    _Float16* W1h   = (_Float16*)alloc(64 * 64 * 2);
    _Float16* W2h   = (_Float16*)alloc(64 * 32 * 2);
    _Float16* Wg0h  = (_Float16*)alloc(256 * 64 * 2);
    _Float16* Wg1h  = (_Float16*)alloc(256 * 256 * 2);
    _Float16* wpkh  = (_Float16*)alloc(32 * 256 * 2);
    _Float16* h0h   = (_Float16*)alloc((size_t)NN * 64 * 2);
    _Float16* feath = (_Float16*)alloc((size_t)NN * 256 * 2);
    _Float16* bufAh = (_Float16*)alloc((size_t)NN * 256 * 2);
    _Float16* bufBh = (_Float16*)alloc((size_t)NN * 256 * 2);
    _Float16* a0h   = (_Float16*)alloc((size_t)EE * 4 * 2);
    _Float16* cpackh = (_Float16*)alloc((size_t)NN * 32 * 2);
    float* el    = (float*)alloc((size_t)NN * 4 * 4);
    float* er    = (float*)alloc((size_t)NN * 4 * 4);
    float* es    = (float*)alloc(96 * 4);
    int* rowstart = (int*)alloc((size_t)(NN + 1) * 4);
    int* deg      = (int*)alloc((size_t)NN * 4);
    int* cursor   = (int*)alloc((size_t)NN * 4);
    int* bsum     = (int*)alloc(256 * 4);
    int* pk       = (int*)alloc((size_t)EE * 4);

    const int NB = (NN + 255) / 256;        // 196
    const int MB128 = (NN + 127) / 128;     // 391
    const int WB = (NN + 3) / 4;            // 12500
    const int nb0 = (N0 + 127) / 128;       // 157
    const int nb1 = (N1 + 127) / 128;       // 118
    const int nb2 = (N2 + 127) / 128;       // 118
    const int SB = 8 * HSLICE;              // 512 partitioned hist/scatter blocks

    hipMemsetAsync(deg, 0, (size_t)NN * 4, stream);

    // K1: partitioned hist || es tables || fp32->fp16 converts (vectorized x4)
    {
        int n0c = N0 * 128, n1c = N1 * 64, n2c = N2 * 32;
        int total4 = (n0c + n1c + n2c + 8192 + 4096 + 2048 + 16384 + 65536 + 4096 + 4096) / 4;
        int cvb = (total4 + 255) / 256;
        k1_hist_prep<<<SB + 18 + cvb, 256, 0, stream>>>(
            dst, deg,
            etab0, We0, ae0, etab1, We1, ae1, etab2, We2, ae2, es,
            x0, x0h, n0c, x1, x1h, n1c, x2, x2h, n2c,
            W0, W0h, 8192, W1, W1h, 4096, W2, W2h, 2048,
            Wg0, Wg0h, 16384, Wg1, Wg1h, 65536,
            Wg2, wpkh, 4096, resW2, wpkh + 4096, 4096);
    }

    // K2: block_sum || input projections
    k2_bsum_proj<<<NB + nb0 + nb1 + nb2, 256, 0, stream>>>(
        deg, bsum, NB, x0h, W0h, b0, x1h, W1h, b1, x2h, W2h, b2, h0h, nb0, nb1);

    // K3: scan (rowstart + cursor)
    scan_out2<<<NB, 256, 0, stream>>>(deg, bsum, rowstart, cursor, NN, NB);

    // K4: partitioned scatter || layer-0 GEMM + fused el/er
    k4_scat_gemm0<<<SB + MB128 * 2, 256, 0, stream>>>(
        src, dst, et, cursor, pk,
        h0h, Wg0h, feath, el, er, al0, ar0, MB128);

    // ---- GAT layer 0 edge stage ----
    gat_fused4<true, false, false><<<WB, 256, 0, stream>>>(
        rowstart, pk, el, er, es + 0, feath, nullptr, a0h, nullptr, bufAh, NN);

    // ---- GAT layer 1 ----
    gemm_mfma<8, 1><<<dim3(MB128, 2), 256, 0, stream>>>(bufAh, Wg1h, nullptr, nullptr, feath,
                                                        el, er, al1, ar1, NN, 256, 256);
    gat_fused4<false, true, true><<<WB, 256, 0, stream>>>(
        rowstart, pk, el, er, es + 32, feath, a0h, nullptr, bufAh, bufBh, NN);

    // ---- GAT layer 2 (H=1, C=16, linear residual, no act) ----
    gemm_mfma<2, 2><<<dim3(MB128, 1), 256, 0, stream>>>(bufBh, wpkh, nullptr, nullptr, cpackh,
                                                        el, er, al2, ar2, NN, 32, 256);
    gat_fused1<<<WB, 256, 0, stream>>>(rowstart, pk, el, er, es + 64, cpackh, outp, NN);
}

// Round 13
// 446.994 us; speedup vs baseline: 1.1801x; 1.0019x over previous
//
#include <hip/hip_runtime.h>
#include <math.h>

#define N0 20000
#define N1 15000
#define N2 15000
#define NN 50000          // total nodes
#define EE 800000         // edges
#define SLOPE 0.2f
#define ALPHA 0.05f
#define NODES_PER_G 6250  // NN/8
#define HSLICE 128        // slices per group for partitioned hist/scatter
#define ECHUNK 6250       // EE/HSLICE

typedef _Float16 h8 __attribute__((ext_vector_type(8)));
typedef _Float16 h4 __attribute__((ext_vector_type(4)));
typedef float f4v __attribute__((ext_vector_type(4)));

__device__ __forceinline__ float sel4(float4 v, int h) {
    float lo = (h & 1) ? v.y : v.x;
    float hi = (h & 1) ? v.w : v.z;
    return (h & 2) ? hi : lo;
}

__device__ __forceinline__ float elu_fast(float x) {
    return x > 0.f ? x : __expf(x) - 1.f;
}

// ---------------- es table pair ----------------

__device__ __forceinline__ void es_pair(int p,
                                        const float* __restrict__ etab0, const float* __restrict__ We0, const float* __restrict__ ae0,
                                        const float* __restrict__ etab1, const float* __restrict__ We1, const float* __restrict__ ae1,
                                        const float* __restrict__ etab2, const float* __restrict__ We2, const float* __restrict__ ae2,
                                        float* __restrict__ es) {
    const float *etab, *We, *ae;
    float* out;
    int H;
    if (p < 32)      { etab = etab0; We = We0; ae = ae0; out = es;      H = 4; }
    else if (p < 64) { p -= 32; etab = etab1; We = We1; ae = ae1; out = es + 32; H = 4; }
    else             { p -= 64; etab = etab2; We = We2; ae = ae2; out = es + 64; H = 1; }
    int t = p / H, h = p % H;
    int j = threadIdx.x & 63;
    const float* w = We + (size_t)(h * 64 + j) * 64;
    const float* e = etab + t * 64;
    float s = 0.f;
    #pragma unroll
    for (int k = 0; k < 64; k += 4) {
        float4 wv = *(const float4*)(w + k);
        float4 ev = *(const float4*)(e + k);
        s += wv.x * ev.x + wv.y * ev.y + wv.z * ev.z + wv.w * ev.w;
    }
    s *= ae[h * 64 + j];
    #pragma unroll
    for (int off = 32; off > 0; off >>= 1) s += __shfl_down(s, off);
    if (j == 0) out[t * H + h] = s;
}

__device__ __forceinline__ void cvt4(const float* __restrict__ s, _Float16* __restrict__ d, int t) {
    float4 v = ((const float4*)s)[t];
    h4 o;
    o[0] = (_Float16)v.x; o[1] = (_Float16)v.y;
    o[2] = (_Float16)v.z; o[3] = (_Float16)v.w;
    ((h4*)d)[t] = o;
}

// ---------------- K1: XCD-partitioned hist || es tables || converts ----------------

__global__ __launch_bounds__(256) void k1_hist_prep(
        const int* __restrict__ dst, int* __restrict__ deg,
        const float* etab0, const float* We0, const float* ae0,
        const float* etab1, const float* We1, const float* ae1,
        const float* etab2, const float* We2, const float* ae2,
        float* es,
        const float* s0, _Float16* d0, int n0,
        const float* s1, _Float16* d1, int n1,
        const float* s2, _Float16* d2, int n2,
        const float* s3, _Float16* d3, int n3,
        const float* s4, _Float16* d4, int n4,
        const float* s5, _Float16* d5, int n5,
        const float* s6, _Float16* d6, int n6,
        const float* s7, _Float16* d7, int n7,
        const float* s8, _Float16* d8, int n8,
        const float* s9, _Float16* d9, int n9) {
    int b = blockIdx.x;
    if (b < 8 * HSLICE) {
        int g = b & 7, sl = b >> 3;
        int lo = g * NODES_PER_G, hi = lo + NODES_PER_G;
        int e0 = sl * ECHUNK, e1 = e0 + ECHUNK;
        for (int e = e0 + threadIdx.x; e < e1; e += 256) {
            int d = dst[e];
            if (d >= lo && d < hi) atomicAdd(&deg[d], 1);
        }
        return;
    }
    b -= 8 * HSLICE;
    if (b < 18) {
        int p = b * 4 + (threadIdx.x >> 6);
        if (p < 72) es_pair(p, etab0, We0, ae0, etab1, We1, ae1, etab2, We2, ae2, es);
        return;
    }
    int t = (b - 18) * 256 + threadIdx.x;   // vector-of-4 index
    if (t < (n0 >> 2)) { cvt4(s0, d0, t); return; } t -= n0 >> 2;
    if (t < (n1 >> 2)) { cvt4(s1, d1, t); return; } t -= n1 >> 2;
    if (t < (n2 >> 2)) { cvt4(s2, d2, t); return; } t -= n2 >> 2;
    if (t < (n3 >> 2)) { cvt4(s3, d3, t); return; } t -= n3 >> 2;
    if (t < (n4 >> 2)) { cvt4(s4, d4, t); return; } t -= n4 >> 2;
    if (t < (n5 >> 2)) { cvt4(s5, d5, t); return; } t -= n5 >> 2;
    if (t < (n6 >> 2)) { cvt4(s6, d6, t); return; } t -= n6 >> 2;
    if (t < (n7 >> 2)) { cvt4(s7, d7, t); return; } t -= n7 >> 2;
    if (t < (n8 >> 2)) { cvt4(s8, d8, t); return; } t -= n8 >> 2;
    if (t < (n9 >> 2)) { cvt4(s9, d9, t); }
}

// ---------------- scan pieces ----------------

__device__ __forceinline__ void block_sum_body(int b, const int* __restrict__ deg,
                                               int* __restrict__ bsum, int n) {
    int i = b * 256 + threadIdx.x;
    int v = (i < n) ? deg[i] : 0;
    #pragma unroll
    for (int off = 32; off > 0; off >>= 1) v += __shfl_down(v, off);
    __shared__ int sh[4];
    if ((threadIdx.x & 63) == 0) sh[threadIdx.x >> 6] = v;
    __syncthreads();
    if (threadIdx.x == 0) bsum[b] = sh[0] + sh[1] + sh[2] + sh[3];
}

__global__ __launch_bounds__(256) void scan_out2(const int* __restrict__ deg,
                                                 const int* __restrict__ bsum,
                                                 int* __restrict__ rowstart,
                                                 int* __restrict__ cursor, int n, int nb) {
    __shared__ int sb[256];
    __shared__ int boff_s;
    int tid = threadIdx.x;
    int v = (tid < nb) ? bsum[tid] : 0;
    sb[tid] = v;
    __syncthreads();
    #pragma unroll
    for (int off = 1; off < 256; off <<= 1) {
        int t = (tid >= off) ? sb[tid - off] : 0;
        __syncthreads();
        sb[tid] += t;
        __syncthreads();
    }
    if (tid == blockIdx.x) boff_s = sb[tid] - v;
    __syncthreads();
    int boff = boff_s;
    int i = blockIdx.x * 256 + tid;
    int d = (i < n) ? deg[i] : 0;
    __syncthreads();
    sb[tid] = d;
    __syncthreads();
    #pragma unroll
    for (int off = 1; off < 256; off <<= 1) {
        int t = (tid >= off) ? sb[tid - off] : 0;
        __syncthreads();
        sb[tid] += t;
        __syncthreads();
    }
    int excl = sb[tid] - d + boff;
    if (i < n) { rowstart[i] = excl; cursor[i] = excl; }
    if (i == n - 1) rowstart[n] = excl + d;
}

// ---------------- MFMA fp16 GEMM body (verified fragment mapping) ----------------
// ELR: 0 none; 1 fused el/er (H=4/D=64, y-block = 2 heads); 2 fused el/er (H=1,D=16).

template<int NT, int ELR>
__device__ __forceinline__ void gemm_body(int bx, int by,
                                          const _Float16* __restrict__ A,
                                          const _Float16* __restrict__ B,
                                          const float* __restrict__ bias,
                                          float* __restrict__ Cf,
                                          _Float16* __restrict__ Ch,
                                          float* __restrict__ el,
                                          float* __restrict__ er,
                                          const float* __restrict__ al,
                                          const float* __restrict__ ar,
                                          int M, int N, int K) {
    const int wave = threadIdx.x >> 6;
    const int lane = threadIdx.x & 63;
    const int m_base = (bx * 4 + wave) * 32;
    const int n_base = by * (NT * 16);
    const int row = lane & 15;
    const int kq = (lane >> 4) * 8;

    f4v acc[2][NT];
    #pragma unroll
    for (int i = 0; i < 2; i++)
        #pragma unroll
        for (int j = 0; j < NT; j++) {
            f4v z = {0.f, 0.f, 0.f, 0.f};
            acc[i][j] = z;
        }

    int ra = m_base + row;       if (ra >= M) ra = M - 1;
    int rb2 = m_base + 16 + row; if (rb2 >= M) rb2 = M - 1;
    const _Float16* a0p = A + (size_t)ra * K + kq;
    const _Float16* a1p = A + (size_t)rb2 * K + kq;
    const _Float16* bp  = B + (size_t)(n_base + row) * K + kq;

    for (int k = 0; k < K; k += 32) {
        h8 a0 = *(const h8*)(a0p + k);
        h8 a1 = *(const h8*)(a1p + k);
        #pragma unroll
        for (int j = 0; j < NT; j++) {
            h8 b = *(const h8*)(bp + (size_t)j * 16 * K + k);
            acc[0][j] = __builtin_amdgcn_mfma_f32_16x16x32_f16(a0, b, acc[0][j], 0, 0, 0);
            acc[1][j] = __builtin_amdgcn_mfma_f32_16x16x32_f16(a1, b, acc[1][j], 0, 0, 0);
        }
    }

    const int col = lane & 15;
    const int rb = (lane >> 4) * 4;

    if (ELR == 1) {
        float alw[NT], arw[NT];
        #pragma unroll
        for (int j = 0; j < NT; j++) {
            int cg = n_base + j * 16 + col;
            int hg = cg >> 6, d = cg & 63;
            alw[j] = al[hg * 64 + d];
            arw[j] = ar[hg * 64 + d];
        }
        const int hb = n_base >> 6;
        #pragma unroll
        for (int ms = 0; ms < 2; ms++) {
            #pragma unroll
            for (int r = 0; r < 4; r++) {
                float e0 = 0.f, e1 = 0.f, f0 = 0.f, f1 = 0.f;
                #pragma unroll
                for (int j = 0; j < NT; j++) {
                    float av = acc[ms][j][r];
                    if (j < NT / 2) { e0 = fmaf(av, alw[j], e0); f0 = fmaf(av, arw[j], f0); }
                    else            { e1 = fmaf(av, alw[j], e1); f1 = fmaf(av, arw[j], f1); }
                }
                #pragma unroll
                for (int off = 1; off <= 8; off <<= 1) {
                    e0 += __shfl_xor(e0, off);
                    e1 += __shfl_xor(e1, off);
                    f0 += __shfl_xor(f0, off);
                    f1 += __shfl_xor(f1, off);
                }
                int m = m_base + ms * 16 + rb + r;
                if (col == 0 && m < M) {
                    el[m * 4 + hb]     = e0;
                    el[m * 4 + hb + 1] = e1;
                    er[m * 4 + hb]     = f0;
                    er[m * 4 + hb + 1] = f1;
                }
            }
        }
    }
    if (ELR == 2) {
        float alw = al[col], arw = ar[col];
        #pragma unroll
        for (int ms = 0; ms < 2; ms++) {
            #pragma unroll
            for (int r = 0; r < 4; r++) {
                float e = acc[ms][0][r] * alw;
                float f = acc[ms][0][r] * arw;
                #pragma unroll
                for (int off = 1; off <= 8; off <<= 1) {
                    e += __shfl_xor(e, off);
                    f += __shfl_xor(f, off);
                }
                int m = m_base + ms * 16 + rb + r;
                if (col == 0 && m < M) { el[m] = e; er[m] = f; }
            }
        }
    }

    #pragma unroll
    for (int ms = 0; ms < 2; ms++) {
        #pragma unroll
        for (int j = 0; j < NT; j++) {
            #pragma unroll
            for (int r = 0; r < 4; r++) {
                int m = m_base + ms * 16 + rb + r;
                if (m < M) {
                    int n = n_base + j * 16 + col;
                    float v = acc[ms][j][r];
                    if (bias) v += bias[n];
                    if (Cf) Cf[(size_t)m * N + n] = v;
                    if (Ch) Ch[(size_t)m * N + n] = (_Float16)v;
                }
            }
        }
    }
}

template<int NT, int ELR>
__global__ __launch_bounds__(256) void gemm_mfma(const _Float16* __restrict__ A,
                                                 const _Float16* __restrict__ B,
                                                 const float* __restrict__ bias,
                                                 float* __restrict__ Cf,
                                                 _Float16* __restrict__ Ch,
                                                 float* __restrict__ el,
                                                 float* __restrict__ er,
                                                 const float* __restrict__ al,
                                                 const float* __restrict__ ar,
                                                 int M, int N, int K) {
    gemm_body<NT, ELR>(blockIdx.x, blockIdx.y, A, B, bias, Cf, Ch, el, er, al, ar, M, N, K);
}

// ---------------- K2: block_sum || proj3 ----------------

__global__ __launch_bounds__(256) void k2_bsum_proj(
        const int* __restrict__ deg, int* __restrict__ bsum, int NBv,
        const _Float16* __restrict__ x0h, const _Float16* __restrict__ W0h, const float* __restrict__ b0,
        const _Float16* __restrict__ x1h, const _Float16* __restrict__ W1h, const float* __restrict__ b1,
        const _Float16* __restrict__ x2h, const _Float16* __restrict__ W2h, const float* __restrict__ b2,
        _Float16* __restrict__ h0h, int nb0, int nb1) {
    int b = blockIdx.x;
    if (b < NBv) { block_sum_body(b, deg, bsum, NN); return; }
    b -= NBv;
    if (b < nb0) {
        gemm_body<4, 0>(b, 0, x0h, W0h, b0, nullptr, h0h,
                        nullptr, nullptr, nullptr, nullptr, N0, 64, 128);
    } else if (b < nb0 + nb1) {
        gemm_body<4, 0>(b - nb0, 0, x1h, W1h, b1, nullptr, h0h + (size_t)N0 * 64,
                        nullptr, nullptr, nullptr, nullptr, N1, 64, 64);
    } else {
        gemm_body<4, 0>(b - nb0 - nb1, 0, x2h, W2h, b2, nullptr, h0h + (size_t)(N0 + N1) * 64,
                        nullptr, nullptr, nullptr, nullptr, N2, 64, 32);
    }
}

// ---------------- K4: XCD-partitioned scatter || gemm0 + fused el/er ----------------

__global__ __launch_bounds__(256) void k4_scat_gemm0(
        const int* __restrict__ src, const int* __restrict__ dst, const int* __restrict__ et,
        int* __restrict__ cursor, int* __restrict__ pk,
        const _Float16* __restrict__ h0h, const _Float16* __restrict__ Wg0h,
        _Float16* __restrict__ feath, float* __restrict__ el, float* __restrict__ er,
        const float* __restrict__ al0, const float* __restrict__ ar0, int MB) {
    int b = blockIdx.x;
    if (b < 8 * HSLICE) {
        int g = b & 7, sl = b >> 3;
        int lo = g * NODES_PER_G, hi = lo + NODES_PER_G;
        int e0 = sl * ECHUNK, e1 = e0 + ECHUNK;
        for (int e = e0 + threadIdx.x; e < e1; e += 256) {
            int d = dst[e];
            if (d >= lo && d < hi) {
                int p = atomicAdd(&cursor[d], 1);
                pk[p] = (et[e] << 16) | src[e];
            }
        }
        return;
    }
    int t = b - 8 * HSLICE;
    int bx = t % MB, by = t / MB;
    gemm_body<8, 1>(bx, by, h0h, Wg0h, nullptr, nullptr, feath, el, er, al0, ar0, NN, 256, 64);
}

// ---------------- fused GAT edge stage, H=4 ----------------
// one wave per dst node; LDS [wave][h][66] conflict-free.
// All __shfl under wave-uniform control flow (round-5 lesson).

template<bool WRITE_A, bool HAS_PREV, bool HAS_RES>
__global__ __launch_bounds__(256) void gat_fused4(const int* __restrict__ rowstart,
                                                  const int* __restrict__ pk,
                                                  const float* __restrict__ el,
                                                  const float* __restrict__ er,
                                                  const float* __restrict__ es,
                                                  const _Float16* __restrict__ feat,
                                                  const _Float16* __restrict__ aprev,
                                                  _Float16* __restrict__ awrite,
                                                  const _Float16* __restrict__ resh,
                                                  _Float16* __restrict__ outh, int nN) {
    __shared__ int2 as_lds[4][4][66];   // [wave][h][edge] = {f32 bits of a, src}
    const int wave = threadIdx.x >> 6;
    const int lane = threadIdx.x & 63;
    int n = blockIdx.x * 4 + wave;
    if (n >= nN) return;
    const int r0 = rowstart[n], r1 = rowstart[n + 1];
    const int deg = r1 - r0;
    float4 er4 = *(const float4*)(er + n * 4);

    if (deg <= 64) {
        // ---- phase A: one edge per lane, in-register softmax ----
        const int idx = r0 + lane;
        const bool act = idx < r1;
        int p = act ? pk[idx] : 0;
        int psrc = p & 0xFFFF;
        float4 v4 = {-INFINITY, -INFINITY, -INFINITY, -INFINITY};
        if (act) {
            float4 e4 = *(const float4*)(el + psrc * 4);
            float4 c4 = *(const float4*)(es + (p >> 16) * 4);
            float v;
            v = e4.x + er4.x + c4.x; v4.x = v > 0.f ? v : SLOPE * v;
            v = e4.y + er4.y + c4.y; v4.y = v > 0.f ? v : SLOPE * v;
            v = e4.z + er4.z + c4.z; v4.z = v > 0.f ? v : SLOPE * v;
            v = e4.w + er4.w + c4.w; v4.w = v > 0.f ? v : SLOPE * v;
        }
        float4 m4 = v4;
        #pragma unroll
        for (int off = 1; off <= 8; off <<= 1) {
            m4.x = fmaxf(m4.x, __shfl_xor(m4.x, off));
            m4.y = fmaxf(m4.y, __shfl_xor(m4.y, off));
            m4.z = fmaxf(m4.z, __shfl_xor(m4.z, off));
            m4.w = fmaxf(m4.w, __shfl_xor(m4.w, off));
        }
        if (deg > 16) {
            m4.x = fmaxf(m4.x, __shfl_xor(m4.x, 16));
            m4.y = fmaxf(m4.y, __shfl_xor(m4.y, 16));
            m4.z = fmaxf(m4.z, __shfl_xor(m4.z, 16));
            m4.w = fmaxf(m4.w, __shfl_xor(m4.w, 16));
        }
        if (deg > 32) {
            m4.x = fmaxf(m4.x, __shfl_xor(m4.x, 32));
            m4.y = fmaxf(m4.y, __shfl_xor(m4.y, 32));
            m4.z = fmaxf(m4.z, __shfl_xor(m4.z, 32));
            m4.w = fmaxf(m4.w, __shfl_xor(m4.w, 32));
        }
        float4 ex = {0.f, 0.f, 0.f, 0.f};
        if (act) {
            ex.x = __expf(v4.x - m4.x);
            ex.y = __expf(v4.y - m4.y);
            ex.z = __expf(v4.z - m4.z);
            ex.w = __expf(v4.w - m4.w);
        }
        float4 s4 = ex;
        #pragma unroll
        for (int off = 1; off <= 8; off <<= 1) {
            s4.x += __shfl_xor(s4.x, off);
            s4.y += __shfl_xor(s4.y, off);
            s4.z += __shfl_xor(s4.z, off);
            s4.w += __shfl_xor(s4.w, off);
        }
        if (deg > 16) {
            s4.x += __shfl_xor(s4.x, 16);
            s4.y += __shfl_xor(s4.y, 16);
            s4.z += __shfl_xor(s4.z, 16);
            s4.w += __shfl_xor(s4.w, 16);
        }
        if (deg > 32) {
            s4.x += __shfl_xor(s4.x, 32);
            s4.y += __shfl_xor(s4.y, 32);
            s4.z += __shfl_xor(s4.z, 32);
            s4.w += __shfl_xor(s4.w, 32);
        }
        float4 a4;
        a4.x = ex.x / (s4.x + 1e-9f);
        a4.y = ex.y / (s4.y + 1e-9f);
        a4.z = ex.z / (s4.z + 1e-9f);
        a4.w = ex.w / (s4.w + 1e-9f);
        if (HAS_PREV && act) {
            h4 pv = *(const h4*)(aprev + (size_t)idx * 4);
            a4.x = a4.x * (1.f - ALPHA) + ALPHA * (float)pv[0];
            a4.y = a4.y * (1.f - ALPHA) + ALPHA * (float)pv[1];
            a4.z = a4.z * (1.f - ALPHA) + ALPHA * (float)pv[2];
            a4.w = a4.w * (1.f - ALPHA) + ALPHA * (float)pv[3];
        }
        if (WRITE_A && act) {
            h4 aw;
            aw[0] = (_Float16)a4.x; aw[1] = (_Float16)a4.y;
            aw[2] = (_Float16)a4.z; aw[3] = (_Float16)a4.w;
            *(h4*)(awrite + (size_t)idx * 4) = aw;
        }
        as_lds[wave][0][lane] = make_int2(__float_as_int(a4.x), psrc);
        as_lds[wave][1][lane] = make_int2(__float_as_int(a4.y), psrc);
        as_lds[wave][2][lane] = make_int2(__float_as_int(a4.z), psrc);
        as_lds[wave][3][lane] = make_int2(__float_as_int(a4.w), psrc);

        // ---- phase B: 2 edge-slots x 32 feature-chunks, unroll-4 ----
        const int half = lane >> 5;
        const int fl = lane & 31;
        const int h = fl >> 3;
        float acc8[8];
        #pragma unroll
        for (int q = 0; q < 8; q++) acc8[q] = 0.f;
        int i = r0;
        for (; i + 7 < r1; i += 8) {
            int j0 = (i - r0) + half;
            int2 e0 = as_lds[wave][h][j0 + 0];
            int2 e1 = as_lds[wave][h][j0 + 2];
            int2 e2 = as_lds[wave][h][j0 + 4];
            int2 e3 = as_lds[wave][h][j0 + 6];
            float a0 = __int_as_float(e0.x), a1 = __int_as_float(e1.x);
            float a2 = __int_as_float(e2.x), a3 = __int_as_float(e3.x);
            h8 f0 = *(const h8*)(feat + (size_t)e0.y * 256 + fl * 8);
            h8 f1 = *(const h8*)(feat + (size_t)e1.y * 256 + fl * 8);
            h8 f2 = *(const h8*)(feat + (size_t)e2.y * 256 + fl * 8);
            h8 f3 = *(const h8*)(feat + (size_t)e3.y * 256 + fl * 8);
            #pragma unroll
            for (int q = 0; q < 8; q++) acc8[q] = fmaf(a0, (float)f0[q], acc8[q]);
            #pragma unroll
            for (int q = 0; q < 8; q++) acc8[q] = fmaf(a1, (float)f1[q], acc8[q]);
            #pragma unroll
            for (int q = 0; q < 8; q++) acc8[q] = fmaf(a2, (float)f2[q], acc8[q]);
            #pragma unroll
            for (int q = 0; q < 8; q++) acc8[q] = fmaf(a3, (float)f3[q], acc8[q]);
        }
        for (; i + 3 < r1; i += 4) {
            int j0 = (i - r0) + half;
            int2 e0 = as_lds[wave][h][j0 + 0];
            int2 e1 = as_lds[wave][h][j0 + 2];
            float a0 = __int_as_float(e0.x), a1 = __int_as_float(e1.x);
            h8 f0 = *(const h8*)(feat + (size_t)e0.y * 256 + fl * 8);
            h8 f1 = *(const h8*)(feat + (size_t)e1.y * 256 + fl * 8);
            #pragma unroll
            for (int q = 0; q < 8; q++) acc8[q] = fmaf(a0, (float)f0[q], acc8[q]);
            #pragma unroll
            for (int q = 0; q < 8; q++) acc8[q] = fmaf(a1, (float)f1[q], acc8[q]);
        }
        for (; i + 1 < r1; i += 2) {
            int j0 = (i - r0) + half;
            int2 e0 = as_lds[wave][h][j0];
            float a0 = __int_as_float(e0.x);
            h8 f0 = *(const h8*)(feat + (size_t)e0.y * 256 + fl * 8);
            #pragma unroll
            for (int q = 0; q < 8; q++) acc8[q] = fmaf(a0, (float)f0[q], acc8[q]);
        }
        if (i < r1) {
            int j0 = i - r0;
            int2 e0 = as_lds[wave][h][j0];
            float a0 = (half == 0) ? __int_as_float(e0.x) : 0.f;
            h8 f0 = *(const h8*)(feat + (size_t)e0.y * 256 + fl * 8);
            #pragma unroll
            for (int q = 0; q < 8; q++) acc8[q] = fmaf(a0, (float)f0[q], acc8[q]);
        }
        #pragma unroll
        for (int q = 0; q < 8; q++) acc8[q] += __shfl_xor(acc8[q], 32);

        if (half == 0) {
            if (HAS_RES) {
                h8 rv = *(const h8*)(resh + (size_t)n * 256 + fl * 8);
                #pragma unroll
                for (int q = 0; q < 8; q++) acc8[q] += (float)rv[q];
            }
            #pragma unroll
            for (int q = 0; q < 8; q++) acc8[q] = elu_fast(acc8[q]);
            h8 o;
            #pragma unroll
            for (int q = 0; q < 8; q++) o[q] = (_Float16)acc8[q];
            *(h8*)(outh + (size_t)n * 256 + fl * 8) = o;
        }
        return;
    }

    // ---------------- fallback: deg > 64 (two-pass, rare) ----------------
    float4 m4 = {-INFINITY, -INFINITY, -INFINITY, -INFINITY};
    for (int base = r0; base < r1; base += 64) {
        int idx = base + lane;
        if (idx < r1) {
            int p = pk[idx];
            float4 e4 = *(const float4*)(el + (p & 0xFFFF) * 4);
            float4 c4 = *(const float4*)(es + (p >> 16) * 4);
            float v;
            v = e4.x + er4.x + c4.x; v = v > 0.f ? v : SLOPE * v; m4.x = fmaxf(m4.x, v);
            v = e4.y + er4.y + c4.y; v = v > 0.f ? v : SLOPE * v; m4.y = fmaxf(m4.y, v);
            v = e4.z + er4.z + c4.z; v = v > 0.f ? v : SLOPE * v; m4.z = fmaxf(m4.z, v);
            v = e4.w + er4.w + c4.w; v = v > 0.f ? v : SLOPE * v; m4.w = fmaxf(m4.w, v);
        }
    }
    #pragma unroll
    for (int off = 1; off < 64; off <<= 1) {
        m4.x = fmaxf(m4.x, __shfl_xor(m4.x, off));
        m4.y = fmaxf(m4.y, __shfl_xor(m4.y, off));
        m4.z = fmaxf(m4.z, __shfl_xor(m4.z, off));
        m4.w = fmaxf(m4.w, __shfl_xor(m4.w, off));
    }
    float4 s4 = {0.f, 0.f, 0.f, 0.f};
    for (int base = r0; base < r1; base += 64) {
        int idx = base + lane;
        if (idx < r1) {
            int p = pk[idx];
            float4 e4 = *(const float4*)(el + (p & 0xFFFF) * 4);
            float4 c4 = *(const float4*)(es + (p >> 16) * 4);
            float4 exv;
            float v;
            v = e4.x + er4.x + c4.x; v = v > 0.f ? v : SLOPE * v; exv.x = __expf(v - m4.x);
            v = e4.y + er4.y + c4.y; v = v > 0.f ? v : SLOPE * v; exv.y = __expf(v - m4.y);
            v = e4.z + er4.z + c4.z; v = v > 0.f ? v : SLOPE * v; exv.z = __expf(v - m4.z);
            v = e4.w + er4.w + c4.w; v = v > 0.f ? v : SLOPE * v; exv.w = __expf(v - m4.w);
            if (base == r0) {
                as_lds[wave][0][lane] = make_int2(__float_as_int(exv.x), p & 0xFFFF);
                as_lds[wave][1][lane] = make_int2(__float_as_int(exv.y), p & 0xFFFF);
                as_lds[wave][2][lane] = make_int2(__float_as_int(exv.z), p & 0xFFFF);
                as_lds[wave][3][lane] = make_int2(__float_as_int(exv.w), p & 0xFFFF);
            }
            s4.x += exv.x; s4.y += exv.y; s4.z += exv.z; s4.w += exv.w;
        }
    }
    #pragma unroll
    for (int off = 1; off < 64; off <<= 1) {
        s4.x += __shfl_xor(s4.x, off);
        s4.y += __shfl_xor(s4.y, off);
        s4.z += __shfl_xor(s4.z, off);
        s4.w += __shfl_xor(s4.w, off);
    }
    float4 inv4;
    inv4.x = 1.f / (s4.x + 1e-9f); inv4.y = 1.f / (s4.y + 1e-9f);
    inv4.z = 1.f / (s4.z + 1e-9f); inv4.w = 1.f / (s4.w + 1e-9f);
    {
        int idx = r0 + lane;
        float4 a;
        a.x = __int_as_float(as_lds[wave][0][lane].x) * inv4.x;
        a.y = __int_as_float(as_lds[wave][1][lane].x) * inv4.y;
        a.z = __int_as_float(as_lds[wave][2][lane].x) * inv4.z;
        a.w = __int_as_float(as_lds[wave][3][lane].x) * inv4.w;
        if (HAS_PREV) {
            h4 pv = *(const h4*)(aprev + (size_t)idx * 4);
            a.x = a.x * (1.f - ALPHA) + ALPHA * (float)pv[0];
            a.y = a.y * (1.f - ALPHA) + ALPHA * (float)pv[1];
            a.z = a.z * (1.f - ALPHA) + ALPHA * (float)pv[2];
            a.w = a.w * (1.f - ALPHA) + ALPHA * (float)pv[3];
        }
        if (WRITE_A) {
            h4 aw;
            aw[0] = (_Float16)a.x; aw[1] = (_Float16)a.y;
            aw[2] = (_Float16)a.z; aw[3] = (_Float16)a.w;
            *(h4*)(awrite + (size_t)idx * 4) = aw;
        }
        as_lds[wave][0][lane].x = __float_as_int(a.x);
        as_lds[wave][1][lane].x = __float_as_int(a.y);
        as_lds[wave][2][lane].x = __float_as_int(a.z);
        as_lds[wave][3][lane].x = __float_as_int(a.w);
    }
    if (WRITE_A) {
        for (int base = r0 + 64; base < r1; base += 64) {
            int idx = base + lane;
            if (idx < r1) {
                int p = pk[idx];
                float4 e4 = *(const float4*)(el + (p & 0xFFFF) * 4);
                float4 c4 = *(const float4*)(es + (p >> 16) * 4);
                float4 a;
                float v;
                v = e4.x + er4.x + c4.x; v = v > 0.f ? v : SLOPE * v; a.x = __expf(v - m4.x) * inv4.x;
                v = e4.y + er4.y + c4.y; v = v > 0.f ? v : SLOPE * v; a.y = __expf(v - m4.y) * inv4.y;
                v = e4.z + er4.z + c4.z; v = v > 0.f ? v : SLOPE * v; a.z = __expf(v - m4.z) * inv4.z;
                v = e4.w + er4.w + c4.w; v = v > 0.f ? v : SLOPE * v; a.w = __expf(v - m4.w) * inv4.w;
                if (HAS_PREV) {
                    h4 pv = *(const h4*)(aprev + (size_t)idx * 4);
                    a.x = a.x * (1.f - ALPHA) + ALPHA * (float)pv[0];
                    a.y = a.y * (1.f - ALPHA) + ALPHA * (float)pv[1];
                    a.z = a.z * (1.f - ALPHA) + ALPHA * (float)pv[2];
                    a.w = a.w * (1.f - ALPHA) + ALPHA * (float)pv[3];
                }
                h4 aw;
                aw[0] = (_Float16)a.x; aw[1] = (_Float16)a.y;
                aw[2] = (_Float16)a.z; aw[3] = (_Float16)a.w;
                *(h4*)(awrite + (size_t)idx * 4) = aw;
            }
        }
    }
    const int h = lane >> 4;
    float4 acc = {0.f, 0.f, 0.f, 0.f};
    const int cap = r0 + 64;
    for (int i = r0; i < cap; i++) {
        int2 e0 = as_lds[wave][h][i - r0];
        h4 f = *(const h4*)(feat + (size_t)e0.y * 256 + lane * 4);
        float av = __int_as_float(e0.x);
        acc.x = fmaf(av, (float)f[0], acc.x);
        acc.y = fmaf(av, (float)f[1], acc.y);
        acc.z = fmaf(av, (float)f[2], acc.z);
        acc.w = fmaf(av, (float)f[3], acc.w);
    }
    {
        float mh = sel4(m4, h), invh = sel4(inv4, h), erh = sel4(er4, h);
        for (int i = cap; i < r1; i++) {
            int p = pk[i];
            int s = p & 0xFFFF, t = p >> 16;
            float v = el[s * 4 + h] + erh + es[t * 4 + h];
            v = v > 0.f ? v : SLOPE * v;
            float a = __expf(v - mh) * invh;
            if (HAS_PREV) a = a * (1.f - ALPHA) + ALPHA * (float)aprev[(size_t)i * 4 + h];
            h4 f = *(const h4*)(feat + (size_t)s * 256 + lane * 4);
            acc.x = fmaf(a, (float)f[0], acc.x);
            acc.y = fmaf(a, (float)f[1], acc.y);
            acc.z = fmaf(a, (float)f[2], acc.z);
            acc.w = fmaf(a, (float)f[3], acc.w);
        }
    }
    if (HAS_RES) {
        h4 rv = *(const h4*)(resh + (size_t)n * 256 + lane * 4);
        acc.x += (float)rv[0]; acc.y += (float)rv[1];
        acc.z += (float)rv[2]; acc.w += (float)rv[3];
    }
    acc.x = elu_fast(acc.x);
    acc.y = elu_fast(acc.y);
    acc.z = elu_fast(acc.z);
    acc.w = elu_fast(acc.w);
    h4 o;
    o[0] = (_Float16)acc.x; o[1] = (_Float16)acc.y;
    o[2] = (_Float16)acc.z; o[3] = (_Float16)acc.w;
    *(h4*)(outh + (size_t)n * 256 + lane * 4) = o;
}

// ---------------- fused GAT layer 2 (H=1, C=16): one wave per node; cpack fp16 ----------------
// phase B: 16 edge-slots x 4 lanes (h4 loads) -> 16 rows in flight; inactive
// edge lanes carry a=0 so no masking is needed (full-exec shfls throughout).

__global__ __launch_bounds__(256) void gat_fused1(const int* __restrict__ rowstart,
                                                  const int* __restrict__ pk,
                                                  const float* __restrict__ el,
                                                  const float* __restrict__ er,
                                                  const float* __restrict__ es,
                                                  const _Float16* __restrict__ cpack,
                                                  float* __restrict__ out, int nN) {
    const int wave = threadIdx.x >> 6;
    const int lane = threadIdx.x & 63;
    int n = blockIdx.x * 4 + wave;
    if (n >= nN) return;
    const int r0 = rowstart[n], r1 = rowstart[n + 1];
    const int deg = r1 - r0;
    const float ern = er[n];

    if (deg <= 64) {
        const int idx = r0 + lane;
        const bool act = idx < r1;
        int p = act ? pk[idx] : 0;
        int psrc = act ? (p & 0xFFFF) : 0;
        float v = -INFINITY;
        if (act) {
            float t = el[psrc] + ern + es[p >> 16];
            v = t > 0.f ? t : SLOPE * t;
        }
        float m = v;
        #pragma unroll
        for (int off = 1; off <= 8; off <<= 1) m = fmaxf(m, __shfl_xor(m, off));
        if (deg > 16) m = fmaxf(m, __shfl_xor(m, 16));
        if (deg > 32) m = fmaxf(m, __shfl_xor(m, 32));
        float ex = act ? __expf(v - m) : 0.f;
        float s = ex;
        #pragma unroll
        for (int off = 1; off <= 8; off <<= 1) s += __shfl_xor(s, off);
        if (deg > 16) s += __shfl_xor(s, 16);
        if (deg > 32) s += __shfl_xor(s, 32);
        float a = ex / (s + 1e-9f);   // inactive lanes: a == 0

        // 16 edge-slots x 4 class-quads
        const int eslot = lane >> 2, fl = lane & 3;
        float4 acc = {0.f, 0.f, 0.f, 0.f};
        for (int i = r0; i < r1; i += 16) {   // wave-uniform; deg<=16 -> 1 iter
            int j = (i - r0) + eslot;          // 0..63 always valid lane index
            int sj = __shfl(psrc, j);
            float aj = __shfl(a, j);
            if (i + eslot >= r1) aj = 0.f;     // beyond-deg slots contribute 0
            h4 f = *(const h4*)(cpack + (size_t)sj * 32 + fl * 4);
            acc.x = fmaf(aj, (float)f[0], acc.x);
            acc.y = fmaf(aj, (float)f[1], acc.y);
            acc.z = fmaf(aj, (float)f[2], acc.z);
            acc.w = fmaf(aj, (float)f[3], acc.w);
        }
        #pragma unroll
        for (int off = 4; off <= 32; off <<= 1) {
            acc.x += __shfl_xor(acc.x, off);
            acc.y += __shfl_xor(acc.y, off);
            acc.z += __shfl_xor(acc.z, off);
            acc.w += __shfl_xor(acc.w, off);
        }
        if (lane < 4) {
            h4 rv = *(const h4*)(cpack + (size_t)n * 32 + 16 + lane * 4);
            float4 o;
            o.x = acc.x + (float)rv[0];
            o.y = acc.y + (float)rv[1];
            o.z = acc.z + (float)rv[2];
            o.w = acc.w + (float)rv[3];
            *(float4*)(out + (size_t)n * 16 + lane * 4) = o;
        }
        return;
    }

    // fallback deg > 64 (rare)
    float m = -INFINITY;
    for (int base = r0; base < r1; base += 64) {
        int idx = base + lane;
        if (idx < r1) {
            int p = pk[idx];
            float v = el[p & 0xFFFF] + ern + es[p >> 16];
            v = v > 0.f ? v : SLOPE * v;
            m = fmaxf(m, v);
        }
    }
    #pragma unroll
    for (int off = 1; off < 64; off <<= 1) m = fmaxf(m, __shfl_xor(m, off));
    float s = 0.f;
    for (int base = r0; base < r1; base += 64) {
        int idx = base + lane;
        if (idx < r1) {
            int p = pk[idx];
            float v = el[p & 0xFFFF] + ern + es[p >> 16];
            v = v > 0.f ? v : SLOPE * v;
            s += __expf(v - m);
        }
    }
    #pragma unroll
    for (int off = 1; off < 64; off <<= 1) s += __shfl_xor(s, off);
    float inv = 1.f / (s + 1e-9f);
    const int eslot = lane >> 2, fl = lane & 3;
    float4 acc = {0.f, 0.f, 0.f, 0.f};
    for (int i = r0; i < r1; i += 16) {   // wave-uniform
        int j = i + eslot;
        bool valid = j < r1;
        int p = valid ? pk[j] : 0;
        float aj = 0.f;
        if (valid) {
            float v = el[p & 0xFFFF] + ern + es[p >> 16];
            v = v > 0.f ? v : SLOPE * v;
            aj = __expf(v - m) * inv;
        }
        h4 f = *(const h4*)(cpack + (size_t)(p & 0xFFFF) * 32 + fl * 4);
        acc.x = fmaf(aj, (float)f[0], acc.x);
        acc.y = fmaf(aj, (float)f[1], acc.y);
        acc.z = fmaf(aj, (float)f[2], acc.z);
        acc.w = fmaf(aj, (float)f[3], acc.w);
    }
    #pragma unroll
    for (int off = 4; off <= 32; off <<= 1) {
        acc.x += __shfl_xor(acc.x, off);
        acc.y += __shfl_xor(acc.y, off);
        acc.z += __shfl_xor(acc.z, off);
        acc.w += __shfl_xor(acc.w, off);
    }
    if (lane < 4) {
        h4 rv = *(const h4*)(cpack + (size_t)n * 32 + 16 + lane * 4);
        float4 o;
        o.x = acc.x + (float)rv[0];
        o.y = acc.y + (float)rv[1];
        o.z = acc.z + (float)rv[2];
        o.w = acc.w + (float)rv[3];
        *(float4*)(out + (size_t)n * 16 + lane * 4) = o;
    }
}

// ---------------- host ----------------

extern "C" void kernel_launch(void* const* d_in, const int* in_sizes, int n_in,
                              void* d_out, int out_size, void* d_ws, size_t ws_size,
                              hipStream_t stream) {
    const float* x0 = (const float*)d_in[0];
    const float* x1 = (const float*)d_in[1];
    const float* x2 = (const float*)d_in[2];
    const int* src  = (const int*)d_in[3];
    const int* dst  = (const int*)d_in[4];
    const int* et   = (const int*)d_in[5];
    const float* W0 = (const float*)d_in[6];  const float* b0 = (const float*)d_in[7];
    const float* W1 = (const float*)d_in[8];  const float* b1 = (const float*)d_in[9];
    const float* W2 = (const float*)d_in[10]; const float* b2 = (const float*)d_in[11];
    const float* Wg0 = (const float*)d_in[12]; const float* etab0 = (const float*)d_in[13];
    const float* We0 = (const float*)d_in[14]; const float* al0 = (const float*)d_in[15];
    const float* ar0 = (const float*)d_in[16]; const float* ae0 = (const float*)d_in[17];
    const float* Wg1 = (const float*)d_in[18]; const float* etab1 = (const float*)d_in[19];
    const float* We1 = (const float*)d_in[20]; const float* al1 = (const float*)d_in[21];
    const float* ar1 = (const float*)d_in[22]; const float* ae1 = (const float*)d_in[23];
    const float* Wg2 = (const float*)d_in[24]; const float* etab2 = (const float*)d_in[25];
    const float* We2 = (const float*)d_in[26]; const float* al2 = (const float*)d_in[27];
    const float* ar2 = (const float*)d_in[28]; const float* ae2 = (const float*)d_in[29];
    const float* resW2 = (const float*)d_in[30];
    float* outp = (float*)d_out;

    char* p = (char*)d_ws;
    auto alloc = [&](size_t bytes) -> void* {
        void* r = (void*)p;
        p += (bytes + 255) & ~(size_t)255;
        return r;
    };
    _Float16* x0h   = (_Float16*)alloc((size_t)N0 * 128 * 2);
    _Float16* x1h   = (_Float16*)alloc((size_t)N1 * 64 * 2);
    _Float16* x2h   = (_Float16*)alloc((size_t)N2 * 32 * 2);
    _Float16* W0h   = (_Float16*)alloc(64 * 128 * 2);
    _Float16* W1h   = (_Float16*)alloc(64 * 64 * 2);
    _Float16* W2h   = (_Float16*)alloc(64 * 32 * 2);
    _Float16* Wg0h  = (_Float16*)alloc(256 * 64 * 2);
    _Float16* Wg1h  = (_Float16*)alloc(256 * 256 * 2);
    _Float16* wpkh  = (_Float16*)alloc(32 * 256 * 2);
    _Float16* h0h   = (_Float16*)alloc((size_t)NN * 64 * 2);
    _Float16* feath = (_Float16*)alloc((size_t)NN * 256 * 2);
    _Float16* bufAh = (_Float16*)alloc((size_t)NN * 256 * 2);
    _Float16* bufBh = (_Float16*)alloc((size_t)NN * 256 * 2);
    _Float16* a0h   = (_Float16*)alloc((size_t)EE * 4 * 2);
    _Float16* cpackh = (_Float16*)alloc((size_t)NN * 32 * 2);
    float* el    = (float*)alloc((size_t)NN * 4 * 4);
    float* er    = (float*)alloc((size_t)NN * 4 * 4);
    float* es    = (float*)alloc(96 * 4);
    int* rowstart = (int*)alloc((size_t)(NN + 1) * 4);
    int* deg      = (int*)alloc((size_t)NN * 4);
    int* cursor   = (int*)alloc((size_t)NN * 4);
    int* bsum     = (int*)alloc(256 * 4);
    int* pk       = (int*)alloc((size_t)EE * 4);

    const int NB = (NN + 255) / 256;        // 196
    const int MB128 = (NN + 127) / 128;     // 391
    const int WB = (NN + 3) / 4;            // 12500
    const int nb0 = (N0 + 127) / 128;       // 157
    const int nb1 = (N1 + 127) / 128;       // 118
    const int nb2 = (N2 + 127) / 128;       // 118
    const int SB = 8 * HSLICE;              // 1024 partitioned hist/scatter blocks

    hipMemsetAsync(deg, 0, (size_t)NN * 4, stream);

    // K1: partitioned hist || es tables || fp32->fp16 converts (vectorized x4)
    {
        int n0c = N0 * 128, n1c = N1 * 64, n2c = N2 * 32;
        int total4 = (n0c + n1c + n2c + 8192 + 4096 + 2048 + 16384 + 65536 + 4096 + 4096) / 4;
        int cvb = (total4 + 255) / 256;
        k1_hist_prep<<<SB + 18 + cvb, 256, 0, stream>>>(
            dst, deg,
            etab0, We0, ae0, etab1, We1, ae1, etab2, We2, ae2, es,
            x0, x0h, n0c, x1, x1h, n1c, x2, x2h, n2c,
            W0, W0h, 8192, W1, W1h, 4096, W2, W2h, 2048,
            Wg0, Wg0h, 16384, Wg1, Wg1h, 65536,
            Wg2, wpkh, 4096, resW2, wpkh + 4096, 4096);
    }

    // K2: block_sum || input projections
    k2_bsum_proj<<<NB + nb0 + nb1 + nb2, 256, 0, stream>>>(
        deg, bsum, NB, x0h, W0h, b0, x1h, W1h, b1, x2h, W2h, b2, h0h, nb0, nb1);

    // K3: scan (rowstart + cursor)
    scan_out2<<<NB, 256, 0, stream>>>(deg, bsum, rowstart, cursor, NN, NB);

    // K4: partitioned scatter || layer-0 GEMM + fused el/er
    k4_scat_gemm0<<<SB + MB128 * 2, 256, 0, stream>>>(
        src, dst, et, cursor, pk,
        h0h, Wg0h, feath, el, er, al0, ar0, MB128);

    // ---- GAT layer 0 edge stage ----
    gat_fused4<true, false, false><<<WB, 256, 0, stream>>>(
        rowstart, pk, el, er, es + 0, feath, nullptr, a0h, nullptr, bufAh, NN);

    // ---- GAT layer 1 ----
    gemm_mfma<8, 1><<<dim3(MB128, 2), 256, 0, stream>>>(bufAh, Wg1h, nullptr, nullptr, feath,
                                                        el, er, al1, ar1, NN, 256, 256);
    gat_fused4<false, true, true><<<WB, 256, 0, stream>>>(
        rowstart, pk, el, er, es + 32, feath, a0h, nullptr, bufAh, bufBh, NN);

    // ---- GAT layer 2 (H=1, C=16, linear residual, no act) ----
    gemm_mfma<2, 2><<<dim3(MB128, 1), 256, 0, stream>>>(bufBh, wpkh, nullptr, nullptr, cpackh,
                                                        el, er, al2, ar2, NN, 32, 256);
    gat_fused1<<<WB, 256, 0, stream>>>(rowstart, pk, el, er, es + 64, cpackh, outp, NN);
}